// Round 1
// baseline (6344.352 us; speedup 1.0000x reference)
//
#include <hip/hip_runtime.h>
#include <hip/hip_bf16.h>

#define H 128
#define ND 100000
#define NS 10000

typedef __attribute__((ext_vector_type(8))) short bf16x8;
typedef __attribute__((ext_vector_type(4))) float f32x4;

__device__ inline ushort f2bf(float f) {
    union { float f; unsigned u; } v; v.f = f;
    unsigned r = v.u + 0x7FFFu + ((v.u >> 16) & 1u);
    return (ushort)(r >> 16);
}

// ---------------- weight prep: fp32 -> bf16, fold root weights & biases ----
__global__ void prep_weights(
    const float* w1ddr, const float* w1ddo, const float* w1sdr, const float* w1sdo,
    const float* w1dsr, const float* w1dso,
    const float* w2ddr, const float* w2ddo, const float* w2sdr, const float* w2sdo,
    const float* w2dsr, const float* w2dso,
    const float* b1dd, const float* b1sd, const float* b1ds,
    const float* b2dd, const float* b2sd, const float* b2ds,
    ushort* Wd1, ushort* Ws1, ushort* Wd2, ushort* Ws2, float* bias)
{
    int i = blockIdx.x * blockDim.x + threadIdx.x;
    if (i < 16384) {
        Wd1[i]           = f2bf(w1ddr[i]);
        Wd1[16384 + i]   = f2bf(w1sdr[i]);
        Wd1[32768 + i]   = f2bf(w1ddo[i] + w1sdo[i]);
        Ws1[i]           = f2bf(w1dsr[i]);
        Ws1[16384 + i]   = f2bf(w1dso[i]);
        Wd2[i]           = f2bf(w2ddr[i]);
        Wd2[16384 + i]   = f2bf(w2sdr[i]);
        Wd2[32768 + i]   = f2bf(w2ddo[i] + w2sdo[i]);
        Ws2[i]           = f2bf(w2dsr[i]);
        Ws2[16384 + i]   = f2bf(w2dso[i]);
    }
    if (i < H) {
        bias[i]         = b1dd[i] + b1sd[i];
        bias[H + i]     = b1ds[i];
        bias[2*H + i]   = b2dd[i] + b2sd[i];
        bias[3*H + i]   = b2ds[i];
    }
}

// ---------------- edge scatter: dst[ed[e]] += src[es[e]] (H floats) --------
__global__ __launch_bounds__(256) void scatter_add(
    const float* __restrict__ src, const int* __restrict__ es,
    const int* __restrict__ ed, int nE, float* dst)
{
    int tid = blockIdx.x * 256 + threadIdx.x;
    int e = tid >> 5;          // 32 threads per edge, float4 each
    if (e >= nE) return;
    int lane = tid & 31;
    int s = es[e], d = ed[e];
    float4 v = reinterpret_cast<const float4*>(src + (size_t)s * H)[lane];
    float* dp = dst + (size_t)d * H + lane * 4;
    atomicAdd(dp + 0, v.x);
    atomicAdd(dp + 1, v.y);
    atomicAdd(dp + 2, v.z);
    atomicAdd(dp + 3, v.w);
}

// ---------------- fused GEMM: out = lrelu(sum_s src_s @ W_s^T + bias) ------
// W layout: [slot][n=128][k=128] bf16 (i.e. already transposed "B^T" form).
// BM=128 rows/block, N=128 (full), K = nsrc*128, MFMA 16x16x32 bf16.
__global__ __launch_bounds__(256) void fused_gemm(
    const float* __restrict__ src0, const float* __restrict__ src1,
    const float* src2, int nsrc,
    const ushort* __restrict__ W, const float* __restrict__ bias,
    float* out, int M)
{
    __shared__ ushort Al[128][40];   // [row][k] bf16, padded to 40 (80B rows)
    __shared__ ushort Bl[128][40];   // [n][k] bf16

    const int t = threadIdx.x;
    const int wave = t >> 6;
    const int lane = t & 63;
    const int l15 = lane & 15;
    const int kreg = lane >> 4;                 // 0..3
    const int block_row = blockIdx.x * 128;

    f32x4 acc[2][8] = {};

    const int quad = t & 7;
    const int rbase = t >> 3;                   // 0..31

    const int nstep = nsrc * 4;
    for (int step = 0; step < nstep; ++step) {
        const float* s = (step < 4) ? src0 : (step < 8) ? src1 : src2;
        const int kc = (step & 3) * 32;
        const int slot = step >> 2;

        __syncthreads();
        // stage A: 128 rows x 32 k, fp32 -> bf16
        #pragma unroll
        for (int it = 0; it < 4; ++it) {
            int row = rbase + it * 32;
            int grow = block_row + row;
            float4 v = make_float4(0.f, 0.f, 0.f, 0.f);
            if (grow < M)
                v = reinterpret_cast<const float4*>(s + (size_t)grow * H + kc)[quad];
            ushort4 b;
            b.x = f2bf(v.x); b.y = f2bf(v.y); b.z = f2bf(v.z); b.w = f2bf(v.w);
            *reinterpret_cast<ushort4*>(&Al[row][quad * 4]) = b;
        }
        // stage B: 128 n x 32 k, bf16 copy (16B chunks)
        #pragma unroll
        for (int c = t; c < 512; c += 256) {
            int row = c >> 2, part = c & 3;
            const ushort* gp = W + slot * 16384 + row * 128 + kc + part * 8;
            uint4 v = *reinterpret_cast<const uint4*>(gp);
            *reinterpret_cast<uint4*>(&Bl[row][part * 8]) = v;
        }
        __syncthreads();

        bf16x8 a[2], b[8];
        #pragma unroll
        for (int m = 0; m < 2; ++m)
            a[m] = *reinterpret_cast<const bf16x8*>(&Al[wave * 32 + m * 16 + l15][kreg * 8]);
        #pragma unroll
        for (int n = 0; n < 8; ++n)
            b[n] = *reinterpret_cast<const bf16x8*>(&Bl[n * 16 + l15][kreg * 8]);
        #pragma unroll
        for (int m = 0; m < 2; ++m)
            #pragma unroll
            for (int n = 0; n < 8; ++n)
                acc[m][n] = __builtin_amdgcn_mfma_f32_16x16x32_bf16(a[m], b[n], acc[m][n], 0, 0, 0);
    }

    // epilogue: bias + leaky-relu, fp32 store
    #pragma unroll
    for (int m = 0; m < 2; ++m) {
        int rb = block_row + wave * 32 + m * 16 + kreg * 4;
        #pragma unroll
        for (int n = 0; n < 8; ++n) {
            int col = n * 16 + l15;
            float bv = bias[col];
            #pragma unroll
            for (int r = 0; r < 4; ++r) {
                int row = rb + r;
                if (row < M) {
                    float v = acc[m][n][r] + bv;
                    v = (v > 0.f) ? v : 0.01f * v;
                    out[(size_t)row * H + col] = v;
                }
            }
        }
    }
}

// ---------------- batchnorm: pass 1 column sums/sumsq ----------------------
__global__ void bn_stats(const float* __restrict__ x, int M, float* stats)
{
    int col = threadIdx.x;                      // 128 threads
    int rows_per = (M + gridDim.x - 1) / gridDim.x;
    int r0 = blockIdx.x * rows_per;
    int r1 = r0 + rows_per; if (r1 > M) r1 = M;
    float s = 0.f, q = 0.f;
    for (int r = r0; r < r1; ++r) {
        float v = x[(size_t)r * H + col];
        s += v; q += v * v;
    }
    if (r0 < M) {
        atomicAdd(&stats[col], s);
        atomicAdd(&stats[H + col], q);
    }
}

// ---------------- batchnorm: pass 2 normalize in place ---------------------
__global__ __launch_bounds__(256) void bn_apply(
    float* x, int M, const float* __restrict__ stats,
    const float* __restrict__ gamma, const float* __restrict__ beta)
{
    size_t i = (size_t)blockIdx.x * 256 + threadIdx.x;
    size_t total = (size_t)M * (H / 4);
    if (i >= total) return;
    int c4 = (int)(i & (H / 4 - 1)) * 4;
    float4 v = reinterpret_cast<float4*>(x)[i];
    float inv_m = 1.0f / (float)M;
    float* vp = &v.x;
    #pragma unroll
    for (int j = 0; j < 4; ++j) {
        int c = c4 + j;
        float mean = stats[c] * inv_m;
        float var = stats[H + c] * inv_m - mean * mean;
        float sc = gamma[c] * rsqrtf(fmaxf(var, 0.f) + 1e-5f);
        vp[j] = (vp[j] - mean) * sc + beta[c];
    }
    reinterpret_cast<float4*>(x)[i] = v;
}

// ---------------- launch ----------------------------------------------------
extern "C" void kernel_launch(void* const* d_in, const int* in_sizes, int n_in,
                              void* d_out, int out_size, void* d_ws, size_t ws_size,
                              hipStream_t stream)
{
    (void)n_in; (void)out_size; (void)ws_size;
    const float* x_drug = (const float*)d_in[0];
    const float* x_se   = (const float*)d_in[1];
    const int* ei_dd = (const int*)d_in[2];
    const int* ei_ds = (const int*)d_in[3];
    const int* ei_sd = (const int*)d_in[4];
    const int EDD = in_sizes[2] / 2;
    const int EDS = in_sizes[3] / 2;
    const int ESD = in_sizes[4] / 2;

    const float* w1_dd_rel  = (const float*)d_in[5];
    const float* b1_dd      = (const float*)d_in[6];
    const float* w1_dd_root = (const float*)d_in[7];
    const float* w1_ds_rel  = (const float*)d_in[8];
    const float* b1_ds      = (const float*)d_in[9];
    const float* w1_ds_root = (const float*)d_in[10];
    const float* w1_sd_rel  = (const float*)d_in[11];
    const float* b1_sd      = (const float*)d_in[12];
    const float* w1_sd_root = (const float*)d_in[13];
    const float* w2_dd_rel  = (const float*)d_in[14];
    const float* b2_dd      = (const float*)d_in[15];
    const float* w2_dd_root = (const float*)d_in[16];
    const float* w2_ds_rel  = (const float*)d_in[17];
    const float* b2_ds      = (const float*)d_in[18];
    const float* w2_ds_root = (const float*)d_in[19];
    const float* w2_sd_rel  = (const float*)d_in[20];
    const float* b2_sd      = (const float*)d_in[21];
    const float* w2_sd_root = (const float*)d_in[22];
    const float* gamma      = (const float*)d_in[23];
    const float* beta       = (const float*)d_in[24];

    // workspace layout (fp32 elements unless noted)
    float* segdd = (float*)d_ws;                       // ND*H
    float* segsd = segdd + (size_t)ND * H;             // ND*H
    float* segds = segsd + (size_t)ND * H;             // NS*H
    float* stats = segds + (size_t)NS * H;             // 512
    float* bias  = stats + 512;                        // 512
    ushort* Wd1 = (ushort*)(bias + 512);               // 3*16384 bf16
    ushort* Ws1 = Wd1 + 3 * 16384;                     // 2*16384
    ushort* Wd2 = Ws1 + 2 * 16384;                     // 3*16384
    ushort* Ws2 = Wd2 + 3 * 16384;                     // 2*16384

    // d1/s1 live in d_out; layer-2 GEMM overwrites in place.
    float* d1 = (float*)d_out;                // ND*H
    float* s1 = d1 + (size_t)ND * H;          // NS*H
    float* d2 = d1;
    float* s2 = s1;

    const size_t seg_bytes = ((size_t)2 * ND * H + (size_t)NS * H) * sizeof(float);

    // zero seg buffers + stats (every call: harness does not re-poison)
    hipMemsetAsync(d_ws, 0, seg_bytes + 512 * sizeof(float), stream);

    prep_weights<<<64, 256, 0, stream>>>(
        w1_dd_rel, w1_dd_root, w1_sd_rel, w1_sd_root, w1_ds_rel, w1_ds_root,
        w2_dd_rel, w2_dd_root, w2_sd_rel, w2_sd_root, w2_ds_rel, w2_ds_root,
        b1_dd, b1_sd, b1_ds, b2_dd, b2_sd, b2_ds,
        Wd1, Ws1, Wd2, Ws2, bias);

    #define SCATTER_GRID(E) (((E) * 32 + 255) / 256)
    // layer 1 scatters
    scatter_add<<<SCATTER_GRID(EDD), 256, 0, stream>>>(x_drug, ei_dd, ei_dd + EDD, EDD, segdd);
    scatter_add<<<SCATTER_GRID(ESD), 256, 0, stream>>>(x_se,   ei_sd, ei_sd + ESD, ESD, segsd);
    scatter_add<<<SCATTER_GRID(EDS), 256, 0, stream>>>(x_drug, ei_ds, ei_ds + EDS, EDS, segds);

    // layer 1 GEMMs
    fused_gemm<<<(ND + 127) / 128, 256, 0, stream>>>(segdd, segsd, x_drug, 3, Wd1, bias, d1, ND);
    fused_gemm<<<(NS + 127) / 128, 256, 0, stream>>>(segds, x_se, nullptr, 2, Ws1, bias + H, s1, NS);

    // re-zero seg buffers for layer 2
    hipMemsetAsync(d_ws, 0, seg_bytes, stream);

    // layer 2 scatters (read d1/s1 from d_out)
    scatter_add<<<SCATTER_GRID(EDD), 256, 0, stream>>>(d1, ei_dd, ei_dd + EDD, EDD, segdd);
    scatter_add<<<SCATTER_GRID(ESD), 256, 0, stream>>>(s1, ei_sd, ei_sd + ESD, ESD, segsd);
    scatter_add<<<SCATTER_GRID(EDS), 256, 0, stream>>>(d1, ei_ds, ei_ds + EDS, EDS, segds);

    // layer 2 GEMMs (in place over d1/s1)
    fused_gemm<<<(ND + 127) / 128, 256, 0, stream>>>(segdd, segsd, d1, 3, Wd2, bias + 2 * H, d2, ND);
    fused_gemm<<<(NS + 127) / 128, 256, 0, stream>>>(segds, s1, nullptr, 2, Ws2, bias + 3 * H, s2, NS);

    // batchnorm per node type (shared gamma/beta)
    bn_stats<<<512, 128, 0, stream>>>(d2, ND, stats);
    bn_stats<<<512, 128, 0, stream>>>(s2, NS, stats + 256);
    bn_apply<<<(ND * (H / 4) + 255) / 256, 256, 0, stream>>>(d2, ND, stats, gamma, beta);
    bn_apply<<<(NS * (H / 4) + 255) / 256, 256, 0, stream>>>(s2, NS, stats + 256, gamma, beta);
}

// Round 2
// 760.769 us; speedup vs baseline: 8.3394x; 8.3394x over previous
//
#include <hip/hip_runtime.h>
#include <hip/hip_bf16.h>

#define H 128
#define ND 100000
#define NS 10000

typedef __attribute__((ext_vector_type(8))) short bf16x8;
typedef __attribute__((ext_vector_type(4))) float f32x4;

__device__ inline ushort f2bf(float f) {
    union { float f; unsigned u; } v; v.f = f;
    unsigned r = v.u + 0x7FFFu + ((v.u >> 16) & 1u);
    return (ushort)(r >> 16);
}

// ---------------- weight prep: fp32 -> bf16, fold root weights & biases ----
__global__ void prep_weights(
    const float* w1ddr, const float* w1ddo, const float* w1sdr, const float* w1sdo,
    const float* w1dsr, const float* w1dso,
    const float* w2ddr, const float* w2ddo, const float* w2sdr, const float* w2sdo,
    const float* w2dsr, const float* w2dso,
    const float* b1dd, const float* b1sd, const float* b1ds,
    const float* b2dd, const float* b2sd, const float* b2ds,
    ushort* Wd1, ushort* Ws1, ushort* Wd2, ushort* Ws2, float* bias)
{
    int i = blockIdx.x * blockDim.x + threadIdx.x;
    if (i < 16384) {
        Wd1[i]           = f2bf(w1ddr[i]);
        Wd1[16384 + i]   = f2bf(w1sdr[i]);
        Wd1[32768 + i]   = f2bf(w1ddo[i] + w1sdo[i]);
        Ws1[i]           = f2bf(w1dsr[i]);
        Ws1[16384 + i]   = f2bf(w1dso[i]);
        Wd2[i]           = f2bf(w2ddr[i]);
        Wd2[16384 + i]   = f2bf(w2sdr[i]);
        Wd2[32768 + i]   = f2bf(w2ddo[i] + w2sdo[i]);
        Ws2[i]           = f2bf(w2dsr[i]);
        Ws2[16384 + i]   = f2bf(w2dso[i]);
    }
    if (i < H) {
        bias[i]         = b1dd[i] + b1sd[i];
        bias[H + i]     = b1ds[i];
        bias[2*H + i]   = b2dd[i] + b2sd[i];
        bias[3*H + i]   = b2ds[i];
    }
}

// ---------------- CSR build ------------------------------------------------
__global__ __launch_bounds__(256) void hist_kernel(
    const int* __restrict__ ed, int E, int* __restrict__ cnt)
{
    int e = blockIdx.x * 256 + threadIdx.x;
    if (e < E) atomicAdd(&cnt[ed[e]], 1);
}

// per-block exclusive scan of 2048 elements, in-place safe; bsum[b] = block total
__global__ __launch_bounds__(256) void scan1(
    const int* __restrict__ cnt, int n, int* __restrict__ out, int* __restrict__ bsum)
{
    __shared__ int sh[256];
    const int t = threadIdx.x;
    const int base = blockIdx.x * 2048 + t * 8;
    int v[8]; int s = 0;
    #pragma unroll
    for (int j = 0; j < 8; ++j) { int i = base + j; v[j] = (i < n) ? cnt[i] : 0; s += v[j]; }
    sh[t] = s; __syncthreads();
    for (int off = 1; off < 256; off <<= 1) {
        int y = (t >= off) ? sh[t - off] : 0;
        __syncthreads();
        sh[t] += y;
        __syncthreads();
    }
    int excl = sh[t] - s;
    #pragma unroll
    for (int j = 0; j < 8; ++j) { int i = base + j; if (i < n) out[i] = excl; excl += v[j]; }
    if (t == 255) bsum[blockIdx.x] = sh[255];
}

// single-wave exclusive scan of block sums (nb <= 64)
__global__ void scan2(int* bsum, int nb)
{
    int t = threadIdx.x;
    int v = (t < nb) ? bsum[t] : 0;
    int x = v;
    for (int off = 1; off < 64; off <<= 1) {
        int y = __shfl_up(x, off);
        if (t >= off) x += y;
    }
    if (t < nb) bsum[t] = x - v;
}

__global__ __launch_bounds__(256) void scan3(
    int* __restrict__ rowptr, int n, const int* __restrict__ bsum,
    int* __restrict__ cursor, int E)
{
    int i = blockIdx.x * 256 + threadIdx.x;
    if (i < n) { int v = rowptr[i] + bsum[i >> 11]; rowptr[i] = v; cursor[i] = v; }
    if (i == 0) rowptr[n] = E;
}

__global__ __launch_bounds__(256) void csr_fill(
    const int* __restrict__ es, const int* __restrict__ ed, int E,
    int* __restrict__ cursor, int* __restrict__ srcidx)
{
    int e = blockIdx.x * 256 + threadIdx.x;
    if (e >= E) return;
    int pos = atomicAdd(&cursor[ed[e]], 1);
    srcidx[pos] = es[e];
}

// ---------------- CSR aggregate: one wave per destination ------------------
// dst[d][:] = sum over sorted sources, written once, as bf16 (RNE).
__global__ __launch_bounds__(256) void csr_aggregate(
    const float* __restrict__ src, const int* __restrict__ rowptr,
    const int* __restrict__ srcidx, ushort* __restrict__ dst, int Ndst)
{
    int d = (blockIdx.x * 256 + threadIdx.x) >> 6;
    if (d >= Ndst) return;
    int lane = threadIdx.x & 63;
    int p0 = rowptr[d], p1 = rowptr[d + 1];
    float ax = 0.f, ay = 0.f;
    int p = p0;
    for (; p + 2 <= p1; p += 2) {
        int s0 = srcidx[p], s1 = srcidx[p + 1];
        float2 v0 = reinterpret_cast<const float2*>(src + (size_t)s0 * H)[lane];
        float2 v1 = reinterpret_cast<const float2*>(src + (size_t)s1 * H)[lane];
        ax += v0.x + v1.x; ay += v0.y + v1.y;
    }
    if (p < p1) {
        int s0 = srcidx[p];
        float2 v0 = reinterpret_cast<const float2*>(src + (size_t)s0 * H)[lane];
        ax += v0.x; ay += v0.y;
    }
    ushort2 o; o.x = f2bf(ax); o.y = f2bf(ay);
    reinterpret_cast<ushort2*>(dst + (size_t)d * H)[lane] = o;
}

// ---------------- fused GEMM: out = lrelu(sum_s src_s @ W_s^T + bias) ------
// W layout: [slot][n=128][k=128] bf16. Sources: bf16 if (MASK>>slot)&1 else fp32.
template<int NSRC, int MASK>
__global__ __launch_bounds__(256) void fused_gemm(
    const void* __restrict__ src0, const void* __restrict__ src1,
    const void* src2,
    const ushort* __restrict__ W, const float* __restrict__ bias,
    float* out, int M)
{
    __shared__ ushort Al[128][40];   // [row][k] bf16, padded
    __shared__ ushort Bl[128][40];   // [n][k] bf16

    const int t = threadIdx.x;
    const int wave = t >> 6;
    const int lane = t & 63;
    const int l15 = lane & 15;
    const int kreg = lane >> 4;
    const int block_row = blockIdx.x * 128;

    f32x4 acc[2][8] = {};

    const int quad = t & 7;
    const int rbase = t >> 3;

    #pragma unroll
    for (int step = 0; step < NSRC * 4; ++step) {
        const int slot = step >> 2;
        const int kc = (step & 3) * 32;
        const void* sv = (slot == 0) ? src0 : (slot == 1) ? src1 : src2;

        __syncthreads();
        if ((MASK >> slot) & 1) {
            // bf16 source: straight 16B copies
            const ushort* sb = (const ushort*)sv;
            #pragma unroll
            for (int it = 0; it < 2; ++it) {
                int c = t + it * 256;
                int row = c >> 2, part = c & 3;
                int grow = block_row + row;
                uint4 v = make_uint4(0, 0, 0, 0);
                if (grow < M)
                    v = *reinterpret_cast<const uint4*>(sb + (size_t)grow * H + kc + part * 8);
                *reinterpret_cast<uint4*>(&Al[row][part * 8]) = v;
            }
        } else {
            // fp32 source: convert to bf16 while staging
            const float* sf = (const float*)sv;
            #pragma unroll
            for (int it = 0; it < 4; ++it) {
                int row = rbase + it * 32;
                int grow = block_row + row;
                float4 v = make_float4(0.f, 0.f, 0.f, 0.f);
                if (grow < M)
                    v = reinterpret_cast<const float4*>(sf + (size_t)grow * H + kc)[quad];
                ushort4 b;
                b.x = f2bf(v.x); b.y = f2bf(v.y); b.z = f2bf(v.z); b.w = f2bf(v.w);
                *reinterpret_cast<ushort4*>(&Al[row][quad * 4]) = b;
            }
        }
        // stage B: 128 n x 32 k bf16
        #pragma unroll
        for (int it = 0; it < 2; ++it) {
            int c = t + it * 256;
            int row = c >> 2, part = c & 3;
            const ushort* gp = W + slot * 16384 + row * 128 + kc + part * 8;
            uint4 v = *reinterpret_cast<const uint4*>(gp);
            *reinterpret_cast<uint4*>(&Bl[row][part * 8]) = v;
        }
        __syncthreads();

        bf16x8 a[2], b[8];
        #pragma unroll
        for (int m = 0; m < 2; ++m)
            a[m] = *reinterpret_cast<const bf16x8*>(&Al[wave * 32 + m * 16 + l15][kreg * 8]);
        #pragma unroll
        for (int n = 0; n < 8; ++n)
            b[n] = *reinterpret_cast<const bf16x8*>(&Bl[n * 16 + l15][kreg * 8]);
        #pragma unroll
        for (int m = 0; m < 2; ++m)
            #pragma unroll
            for (int n = 0; n < 8; ++n)
                acc[m][n] = __builtin_amdgcn_mfma_f32_16x16x32_bf16(a[m], b[n], acc[m][n], 0, 0, 0);
    }

    #pragma unroll
    for (int m = 0; m < 2; ++m) {
        int rb = block_row + wave * 32 + m * 16 + kreg * 4;
        #pragma unroll
        for (int n = 0; n < 8; ++n) {
            int col = n * 16 + l15;
            float bv = bias[col];
            #pragma unroll
            for (int r = 0; r < 4; ++r) {
                int row = rb + r;
                if (row < M) {
                    float v = acc[m][n][r] + bv;
                    v = (v > 0.f) ? v : 0.01f * v;
                    out[(size_t)row * H + col] = v;
                }
            }
        }
    }
}

// ---------------- batchnorm ------------------------------------------------
__global__ void bn_stats(const float* __restrict__ x, int M, float* stats)
{
    int col = threadIdx.x;                      // 128 threads
    int rows_per = (M + gridDim.x - 1) / gridDim.x;
    int r0 = blockIdx.x * rows_per;
    int r1 = r0 + rows_per; if (r1 > M) r1 = M;
    float s = 0.f, q = 0.f;
    for (int r = r0; r < r1; ++r) {
        float v = x[(size_t)r * H + col];
        s += v; q += v * v;
    }
    if (r0 < M) {
        atomicAdd(&stats[col], s);
        atomicAdd(&stats[H + col], q);
    }
}

__global__ __launch_bounds__(256) void bn_apply(
    float* x, int M, const float* __restrict__ stats,
    const float* __restrict__ gamma, const float* __restrict__ beta)
{
    size_t i = (size_t)blockIdx.x * 256 + threadIdx.x;
    size_t total = (size_t)M * (H / 4);
    if (i >= total) return;
    int c4 = (int)(i & (H / 4 - 1)) * 4;
    float4 v = reinterpret_cast<float4*>(x)[i];
    float inv_m = 1.0f / (float)M;
    float* vp = &v.x;
    #pragma unroll
    for (int j = 0; j < 4; ++j) {
        int c = c4 + j;
        float mean = stats[c] * inv_m;
        float var = stats[H + c] * inv_m - mean * mean;
        float sc = gamma[c] * rsqrtf(fmaxf(var, 0.f) + 1e-5f);
        vp[j] = (vp[j] - mean) * sc + beta[c];
    }
    reinterpret_cast<float4*>(x)[i] = v;
}

// ---------------- launch ----------------------------------------------------
extern "C" void kernel_launch(void* const* d_in, const int* in_sizes, int n_in,
                              void* d_out, int out_size, void* d_ws, size_t ws_size,
                              hipStream_t stream)
{
    (void)n_in; (void)out_size; (void)ws_size;
    const float* x_drug = (const float*)d_in[0];
    const float* x_se   = (const float*)d_in[1];
    const int* ei_dd = (const int*)d_in[2];
    const int* ei_ds = (const int*)d_in[3];
    const int* ei_sd = (const int*)d_in[4];
    const int EDD = in_sizes[2] / 2;
    const int EDS = in_sizes[3] / 2;
    const int ESD = in_sizes[4] / 2;

    const float* w1_dd_rel  = (const float*)d_in[5];
    const float* b1_dd      = (const float*)d_in[6];
    const float* w1_dd_root = (const float*)d_in[7];
    const float* w1_ds_rel  = (const float*)d_in[8];
    const float* b1_ds      = (const float*)d_in[9];
    const float* w1_ds_root = (const float*)d_in[10];
    const float* w1_sd_rel  = (const float*)d_in[11];
    const float* b1_sd      = (const float*)d_in[12];
    const float* w1_sd_root = (const float*)d_in[13];
    const float* w2_dd_rel  = (const float*)d_in[14];
    const float* b2_dd      = (const float*)d_in[15];
    const float* w2_dd_root = (const float*)d_in[16];
    const float* w2_ds_rel  = (const float*)d_in[17];
    const float* b2_ds      = (const float*)d_in[18];
    const float* w2_ds_root = (const float*)d_in[19];
    const float* w2_sd_rel  = (const float*)d_in[20];
    const float* b2_sd      = (const float*)d_in[21];
    const float* w2_sd_root = (const float*)d_in[22];
    const float* gamma      = (const float*)d_in[23];
    const float* beta       = (const float*)d_in[24];

    // ---------------- workspace layout ----------------
    ushort* segdd = (ushort*)d_ws;                     // ND*H bf16
    ushort* segsd = segdd + (size_t)ND * H;            // ND*H
    ushort* segds = segsd + (size_t)ND * H;            // NS*H
    ushort* Wd1 = segds + (size_t)NS * H;              // 3*16384
    ushort* Ws1 = Wd1 + 3 * 16384;                     // 2*16384
    ushort* Wd2 = Ws1 + 2 * 16384;                     // 3*16384
    ushort* Ws2 = Wd2 + 3 * 16384;                     // 2*16384
    float* bias  = (float*)(Ws2 + 2 * 16384);          // 512
    float* stats = bias + 512;                         // 512
    int* rp_dd = (int*)(stats + 512);                  // ND+1
    int* rp_sd = rp_dd + (ND + 1);                     // ND+1
    int* rp_ds = rp_sd + (ND + 1);                     // NS+1
    int* cur_dd = rp_ds + (NS + 1);                    // ND
    int* cur_sd = cur_dd + ND;                         // ND
    int* cur_ds = cur_sd + ND;                         // NS
    int* si_dd = cur_ds + NS;                          // EDD
    int* si_sd = si_dd + EDD;                          // ESD
    int* si_ds = si_sd + ESD;                          // EDS
    int* bs_dd = si_ds + EDS;                          // 64
    int* bs_sd = bs_dd + 64;                           // 64
    int* bs_ds = bs_sd + 64;                           // 64

    float* d1 = (float*)d_out;                // ND*H
    float* s1 = d1 + (size_t)ND * H;          // NS*H
    float* d2 = d1;
    float* s2 = s1;

    // zero stats + rowptr arrays (contiguous)
    hipMemsetAsync(stats, 0, (512 + (size_t)2 * (ND + 1) + (NS + 1)) * sizeof(int), stream);

    prep_weights<<<64, 256, 0, stream>>>(
        w1_dd_rel, w1_dd_root, w1_sd_rel, w1_sd_root, w1_ds_rel, w1_ds_root,
        w2_dd_rel, w2_dd_root, w2_sd_rel, w2_sd_root, w2_ds_rel, w2_ds_root,
        b1_dd, b1_sd, b1_ds, b2_dd, b2_sd, b2_ds,
        Wd1, Ws1, Wd2, Ws2, bias);

    // ---- CSR build (once per relation; reused by both layers) ----
    const int nbDD = (ND + 2047) / 2048, nbDS = (NS + 2047) / 2048;
    hist_kernel<<<(EDD + 255) / 256, 256, 0, stream>>>(ei_dd + EDD, EDD, rp_dd);
    hist_kernel<<<(ESD + 255) / 256, 256, 0, stream>>>(ei_sd + ESD, ESD, rp_sd);
    hist_kernel<<<(EDS + 255) / 256, 256, 0, stream>>>(ei_ds + EDS, EDS, rp_ds);

    scan1<<<nbDD, 256, 0, stream>>>(rp_dd, ND, rp_dd, bs_dd);
    scan1<<<nbDD, 256, 0, stream>>>(rp_sd, ND, rp_sd, bs_sd);
    scan1<<<nbDS, 256, 0, stream>>>(rp_ds, NS, rp_ds, bs_ds);
    scan2<<<1, 64, 0, stream>>>(bs_dd, nbDD);
    scan2<<<1, 64, 0, stream>>>(bs_sd, nbDD);
    scan2<<<1, 64, 0, stream>>>(bs_ds, nbDS);
    scan3<<<(ND + 255) / 256, 256, 0, stream>>>(rp_dd, ND, bs_dd, cur_dd, EDD);
    scan3<<<(ND + 255) / 256, 256, 0, stream>>>(rp_sd, ND, bs_sd, cur_sd, ESD);
    scan3<<<(NS + 255) / 256, 256, 0, stream>>>(rp_ds, NS, bs_ds, cur_ds, EDS);

    csr_fill<<<(EDD + 255) / 256, 256, 0, stream>>>(ei_dd, ei_dd + EDD, EDD, cur_dd, si_dd);
    csr_fill<<<(ESD + 255) / 256, 256, 0, stream>>>(ei_sd, ei_sd + ESD, ESD, cur_sd, si_sd);
    csr_fill<<<(EDS + 255) / 256, 256, 0, stream>>>(ei_ds, ei_ds + EDS, EDS, cur_ds, si_ds);

    #define AGG_GRID(N) (((N) + 3) / 4)
    // ---- layer 1 ----
    csr_aggregate<<<AGG_GRID(ND), 256, 0, stream>>>(x_drug, rp_dd, si_dd, segdd, ND);
    csr_aggregate<<<AGG_GRID(ND), 256, 0, stream>>>(x_se,   rp_sd, si_sd, segsd, ND);
    csr_aggregate<<<AGG_GRID(NS), 256, 0, stream>>>(x_drug, rp_ds, si_ds, segds, NS);

    fused_gemm<3, 3><<<(ND + 127) / 128, 256, 0, stream>>>(segdd, segsd, x_drug, Wd1, bias, d1, ND);
    fused_gemm<2, 1><<<(NS + 127) / 128, 256, 0, stream>>>(segds, x_se, nullptr, Ws1, bias + H, s1, NS);

    // ---- layer 2 (reuse CSR; sources are d1/s1) ----
    csr_aggregate<<<AGG_GRID(ND), 256, 0, stream>>>(d1, rp_dd, si_dd, segdd, ND);
    csr_aggregate<<<AGG_GRID(ND), 256, 0, stream>>>(s1, rp_sd, si_sd, segsd, ND);
    csr_aggregate<<<AGG_GRID(NS), 256, 0, stream>>>(d1, rp_ds, si_ds, segds, NS);

    fused_gemm<3, 3><<<(ND + 127) / 128, 256, 0, stream>>>(segdd, segsd, d1, Wd2, bias + 2 * H, d2, ND);
    fused_gemm<2, 1><<<(NS + 127) / 128, 256, 0, stream>>>(segds, s1, nullptr, Ws2, bias + 3 * H, s2, NS);

    // ---- batchnorm ----
    bn_stats<<<512, 128, 0, stream>>>(d2, ND, stats);
    bn_stats<<<512, 128, 0, stream>>>(s2, NS, stats + 256);
    bn_apply<<<(ND * (H / 4) + 255) / 256, 256, 0, stream>>>(d2, ND, stats, gamma, beta);
    bn_apply<<<(NS * (H / 4) + 255) / 256, 256, 0, stream>>>(s2, NS, stats + 256, gamma, beta);
}

// Round 3
// 661.536 us; speedup vs baseline: 9.5903x; 1.1500x over previous
//
#include <hip/hip_runtime.h>
#include <hip/hip_bf16.h>

#define H 128
#define ND 100000
#define NS 10000

typedef __attribute__((ext_vector_type(8))) _Float16 f16x8;
typedef __attribute__((ext_vector_type(4))) float f32x4;

__device__ inline ushort f2h(float f) {
    union { _Float16 h; ushort u; } c; c.h = (_Float16)f; return c.u;
}
__device__ inline float h2f(ushort u) {
    union { ushort u; _Float16 h; } c; c.u = u; return (float)c.h;
}

// ---------------- fp32 -> fp16 table convert -------------------------------
__global__ __launch_bounds__(256) void f2h_kernel(
    const float* __restrict__ in, ushort* __restrict__ out, int n4)
{
    int i = blockIdx.x * 256 + threadIdx.x;
    if (i >= n4) return;
    float4 v = reinterpret_cast<const float4*>(in)[i];
    ushort4 o;
    o.x = f2h(v.x); o.y = f2h(v.y); o.z = f2h(v.z); o.w = f2h(v.w);
    reinterpret_cast<ushort4*>(out)[i] = o;
}

// ---------------- weight prep: fp32 -> fp16, fold root weights & biases ----
__global__ void prep_weights(
    const float* w1ddr, const float* w1ddo, const float* w1sdr, const float* w1sdo,
    const float* w1dsr, const float* w1dso,
    const float* w2ddr, const float* w2ddo, const float* w2sdr, const float* w2sdo,
    const float* w2dsr, const float* w2dso,
    const float* b1dd, const float* b1sd, const float* b1ds,
    const float* b2dd, const float* b2sd, const float* b2ds,
    ushort* Wd1, ushort* Ws1, ushort* Wd2, ushort* Ws2, float* bias)
{
    int i = blockIdx.x * blockDim.x + threadIdx.x;
    if (i < 16384) {
        Wd1[i]           = f2h(w1ddr[i]);
        Wd1[16384 + i]   = f2h(w1sdr[i]);
        Wd1[32768 + i]   = f2h(w1ddo[i] + w1sdo[i]);
        Ws1[i]           = f2h(w1dsr[i]);
        Ws1[16384 + i]   = f2h(w1dso[i]);
        Wd2[i]           = f2h(w2ddr[i]);
        Wd2[16384 + i]   = f2h(w2sdr[i]);
        Wd2[32768 + i]   = f2h(w2ddo[i] + w2sdo[i]);
        Ws2[i]           = f2h(w2dsr[i]);
        Ws2[16384 + i]   = f2h(w2dso[i]);
    }
    if (i < H) {
        bias[i]         = b1dd[i] + b1sd[i];
        bias[H + i]     = b1ds[i];
        bias[2*H + i]   = b2dd[i] + b2sd[i];
        bias[3*H + i]   = b2ds[i];
    }
}

// ---------------- CSR build ------------------------------------------------
__global__ __launch_bounds__(256) void hist_kernel(
    const int* __restrict__ ed, int E, int* __restrict__ cnt)
{
    int e = blockIdx.x * 256 + threadIdx.x;
    if (e < E) atomicAdd(&cnt[ed[e]], 1);
}

__global__ __launch_bounds__(256) void scan1(
    const int* __restrict__ cnt, int n, int* __restrict__ out, int* __restrict__ bsum)
{
    __shared__ int sh[256];
    const int t = threadIdx.x;
    const int base = blockIdx.x * 2048 + t * 8;
    int v[8]; int s = 0;
    #pragma unroll
    for (int j = 0; j < 8; ++j) { int i = base + j; v[j] = (i < n) ? cnt[i] : 0; s += v[j]; }
    sh[t] = s; __syncthreads();
    for (int off = 1; off < 256; off <<= 1) {
        int y = (t >= off) ? sh[t - off] : 0;
        __syncthreads();
        sh[t] += y;
        __syncthreads();
    }
    int excl = sh[t] - s;
    #pragma unroll
    for (int j = 0; j < 8; ++j) { int i = base + j; if (i < n) out[i] = excl; excl += v[j]; }
    if (t == 255) bsum[blockIdx.x] = sh[255];
}

__global__ void scan2(int* bsum, int nb)
{
    int t = threadIdx.x;
    int v = (t < nb) ? bsum[t] : 0;
    int x = v;
    for (int off = 1; off < 64; off <<= 1) {
        int y = __shfl_up(x, off);
        if (t >= off) x += y;
    }
    if (t < nb) bsum[t] = x - v;
}

__global__ __launch_bounds__(256) void scan3(
    int* __restrict__ rowptr, int n, const int* __restrict__ bsum,
    int* __restrict__ cursor, int E)
{
    int i = blockIdx.x * 256 + threadIdx.x;
    if (i < n) { int v = rowptr[i] + bsum[i >> 11]; rowptr[i] = v; cursor[i] = v; }
    if (i == 0) rowptr[n] = E;
}

__global__ __launch_bounds__(256) void csr_fill(
    const int* __restrict__ es, const int* __restrict__ ed, int E,
    int* __restrict__ cursor, int* __restrict__ srcidx)
{
    int e = blockIdx.x * 256 + threadIdx.x;
    if (e >= E) return;
    int pos = atomicAdd(&cursor[ed[e]], 1);
    srcidx[pos] = es[e];
}

// ---------------- CSR aggregate: one wave per destination, fp16 in/out -----
__global__ __launch_bounds__(256) void csr_aggregate(
    const ushort* __restrict__ src, const int* __restrict__ rowptr,
    const int* __restrict__ srcidx, ushort* __restrict__ dst, int Ndst)
{
    int d = blockIdx.x * 4 + (threadIdx.x >> 6);
    if (d >= Ndst) return;
    int lane = threadIdx.x & 63;
    int p0 = rowptr[d], p1 = rowptr[d + 1];
    float ax = 0.f, ay = 0.f;
    int p = p0;
    for (; p + 4 <= p1; p += 4) {
        int s0 = srcidx[p], s1 = srcidx[p + 1], s2 = srcidx[p + 2], s3 = srcidx[p + 3];
        uint v0 = reinterpret_cast<const uint*>(src + (size_t)s0 * H)[lane];
        uint v1 = reinterpret_cast<const uint*>(src + (size_t)s1 * H)[lane];
        uint v2 = reinterpret_cast<const uint*>(src + (size_t)s2 * H)[lane];
        uint v3 = reinterpret_cast<const uint*>(src + (size_t)s3 * H)[lane];
        ax += h2f((ushort)(v0 & 0xffff)) + h2f((ushort)(v1 & 0xffff))
            + h2f((ushort)(v2 & 0xffff)) + h2f((ushort)(v3 & 0xffff));
        ay += h2f((ushort)(v0 >> 16)) + h2f((ushort)(v1 >> 16))
            + h2f((ushort)(v2 >> 16)) + h2f((ushort)(v3 >> 16));
    }
    for (; p < p1; ++p) {
        int s0 = srcidx[p];
        uint v0 = reinterpret_cast<const uint*>(src + (size_t)s0 * H)[lane];
        ax += h2f((ushort)(v0 & 0xffff));
        ay += h2f((ushort)(v0 >> 16));
    }
    uint o = (uint)f2h(ax) | ((uint)f2h(ay) << 16);
    reinterpret_cast<uint*>(dst + (size_t)d * H)[lane] = o;
}

// ---------------- fused GEMM: out = lrelu(sum_s src_s @ W_s^T + bias) ------
template<int NSRC, bool OUTF32>
__global__ __launch_bounds__(256) void fused_gemm(
    const ushort* __restrict__ src0, const ushort* __restrict__ src1,
    const ushort* __restrict__ src2,
    const ushort* __restrict__ W, const float* __restrict__ bias,
    void* __restrict__ outv, int M)
{
    __shared__ ushort Al[128][40];   // [row][k] fp16, padded
    __shared__ ushort Bl[128][40];   // [n][k] fp16

    const int t = threadIdx.x;
    const int wave = t >> 6;
    const int lane = t & 63;
    const int l15 = lane & 15;
    const int kreg = lane >> 4;
    const int block_row = blockIdx.x * 128;

    f32x4 acc[2][8] = {};

    #pragma unroll
    for (int step = 0; step < NSRC * 4; ++step) {
        const int slot = step >> 2;
        const int kc = (step & 3) * 32;
        const ushort* sb = (slot == 0) ? src0 : (slot == 1) ? src1 : src2;

        __syncthreads();
        #pragma unroll
        for (int it = 0; it < 2; ++it) {
            int c = t + it * 256;
            int row = c >> 2, part = c & 3;
            int grow = block_row + row;
            uint4 v = make_uint4(0, 0, 0, 0);
            if (grow < M)
                v = *reinterpret_cast<const uint4*>(sb + (size_t)grow * H + kc + part * 8);
            *reinterpret_cast<uint4*>(&Al[row][part * 8]) = v;
        }
        #pragma unroll
        for (int it = 0; it < 2; ++it) {
            int c = t + it * 256;
            int row = c >> 2, part = c & 3;
            const ushort* gp = W + slot * 16384 + row * 128 + kc + part * 8;
            uint4 v = *reinterpret_cast<const uint4*>(gp);
            *reinterpret_cast<uint4*>(&Bl[row][part * 8]) = v;
        }
        __syncthreads();

        f16x8 a[2], b[8];
        #pragma unroll
        for (int m = 0; m < 2; ++m)
            a[m] = *reinterpret_cast<const f16x8*>(&Al[wave * 32 + m * 16 + l15][kreg * 8]);
        #pragma unroll
        for (int n = 0; n < 8; ++n)
            b[n] = *reinterpret_cast<const f16x8*>(&Bl[n * 16 + l15][kreg * 8]);
        #pragma unroll
        for (int m = 0; m < 2; ++m)
            #pragma unroll
            for (int n = 0; n < 8; ++n)
                acc[m][n] = __builtin_amdgcn_mfma_f32_16x16x32_f16(a[m], b[n], acc[m][n], 0, 0, 0);
    }

    #pragma unroll
    for (int m = 0; m < 2; ++m) {
        int rb = block_row + wave * 32 + m * 16 + kreg * 4;
        #pragma unroll
        for (int n = 0; n < 8; ++n) {
            int col = n * 16 + l15;
            float bv = bias[col];
            #pragma unroll
            for (int r = 0; r < 4; ++r) {
                int row = rb + r;
                if (row < M) {
                    float v = acc[m][n][r] + bv;
                    v = (v > 0.f) ? v : 0.01f * v;
                    if (OUTF32)
                        ((float*)outv)[(size_t)row * H + col] = v;
                    else
                        ((ushort*)outv)[(size_t)row * H + col] = f2h(v);
                }
            }
        }
    }
}

// ---------------- batchnorm ------------------------------------------------
__global__ void bn_stats(const float* __restrict__ x, int M, float* stats)
{
    int col = threadIdx.x;                      // 128 threads
    int rows_per = (M + gridDim.x - 1) / gridDim.x;
    int r0 = blockIdx.x * rows_per;
    int r1 = r0 + rows_per; if (r1 > M) r1 = M;
    float s = 0.f, q = 0.f;
    for (int r = r0; r < r1; ++r) {
        float v = x[(size_t)r * H + col];
        s += v; q += v * v;
    }
    if (r0 < M) {
        atomicAdd(&stats[col], s);
        atomicAdd(&stats[H + col], q);
    }
}

__global__ __launch_bounds__(256) void bn_apply(
    float* x, int M, const float* __restrict__ stats,
    const float* __restrict__ gamma, const float* __restrict__ beta)
{
    size_t i = (size_t)blockIdx.x * 256 + threadIdx.x;
    size_t total = (size_t)M * (H / 4);
    if (i >= total) return;
    int c4 = (int)(i & (H / 4 - 1)) * 4;
    float4 v = reinterpret_cast<float4*>(x)[i];
    float inv_m = 1.0f / (float)M;
    float* vp = &v.x;
    #pragma unroll
    for (int j = 0; j < 4; ++j) {
        int c = c4 + j;
        float mean = stats[c] * inv_m;
        float var = stats[H + c] * inv_m - mean * mean;
        float sc = gamma[c] * rsqrtf(fmaxf(var, 0.f) + 1e-5f);
        vp[j] = (vp[j] - mean) * sc + beta[c];
    }
    reinterpret_cast<float4*>(x)[i] = v;
}

// ---------------- launch ----------------------------------------------------
extern "C" void kernel_launch(void* const* d_in, const int* in_sizes, int n_in,
                              void* d_out, int out_size, void* d_ws, size_t ws_size,
                              hipStream_t stream)
{
    (void)n_in; (void)out_size; (void)ws_size;
    const float* x_drug = (const float*)d_in[0];
    const float* x_se   = (const float*)d_in[1];
    const int* ei_dd = (const int*)d_in[2];
    const int* ei_ds = (const int*)d_in[3];
    const int* ei_sd = (const int*)d_in[4];
    const int EDD = in_sizes[2] / 2;
    const int EDS = in_sizes[3] / 2;
    const int ESD = in_sizes[4] / 2;

    const float* w1_dd_rel  = (const float*)d_in[5];
    const float* b1_dd      = (const float*)d_in[6];
    const float* w1_dd_root = (const float*)d_in[7];
    const float* w1_ds_rel  = (const float*)d_in[8];
    const float* b1_ds      = (const float*)d_in[9];
    const float* w1_ds_root = (const float*)d_in[10];
    const float* w1_sd_rel  = (const float*)d_in[11];
    const float* b1_sd      = (const float*)d_in[12];
    const float* w1_sd_root = (const float*)d_in[13];
    const float* w2_dd_rel  = (const float*)d_in[14];
    const float* b2_dd      = (const float*)d_in[15];
    const float* w2_dd_root = (const float*)d_in[16];
    const float* w2_ds_rel  = (const float*)d_in[17];
    const float* b2_ds      = (const float*)d_in[18];
    const float* w2_ds_root = (const float*)d_in[19];
    const float* w2_sd_rel  = (const float*)d_in[20];
    const float* b2_sd      = (const float*)d_in[21];
    const float* w2_sd_root = (const float*)d_in[22];
    const float* gamma      = (const float*)d_in[23];
    const float* beta       = (const float*)d_in[24];

    // ---------------- workspace layout ----------------
    ushort* xd_h  = (ushort*)d_ws;                     // ND*H fp16 (becomes d1h in place)
    ushort* xs_h  = xd_h + (size_t)ND * H;             // NS*H fp16 (becomes s1h)
    ushort* segdd = xs_h + (size_t)NS * H;             // ND*H
    ushort* segsd = segdd + (size_t)ND * H;            // ND*H
    ushort* segds = segsd + (size_t)ND * H;            // NS*H
    ushort* Wd1 = segds + (size_t)NS * H;              // 3*16384
    ushort* Ws1 = Wd1 + 3 * 16384;                     // 2*16384
    ushort* Wd2 = Ws1 + 2 * 16384;                     // 3*16384
    ushort* Ws2 = Wd2 + 3 * 16384;                     // 2*16384
    float* bias  = (float*)(Ws2 + 2 * 16384);          // 512
    float* stats = bias + 512;                         // 512
    int* rp_dd = (int*)(stats + 512);                  // ND+1
    int* rp_sd = rp_dd + (ND + 1);                     // ND+1
    int* rp_ds = rp_sd + (ND + 1);                     // NS+1
    int* cur_dd = rp_ds + (NS + 1);                    // ND
    int* cur_sd = cur_dd + ND;                         // ND
    int* cur_ds = cur_sd + ND;                         // NS
    int* si_dd = cur_ds + NS;                          // EDD
    int* si_sd = si_dd + EDD;                          // ESD
    int* si_ds = si_sd + ESD;                          // EDS
    int* bs_dd = si_ds + EDS;                          // 64
    int* bs_sd = bs_dd + 64;                           // 64
    int* bs_ds = bs_sd + 64;                           // 64

    ushort* d1h = xd_h;
    ushort* s1h = xs_h;

    float* d2 = (float*)d_out;                // ND*H
    float* s2 = d2 + (size_t)ND * H;          // NS*H

    hipMemsetAsync(stats, 0, (512 + (size_t)2 * (ND + 1) + (NS + 1)) * sizeof(int), stream);

    prep_weights<<<64, 256, 0, stream>>>(
        w1_dd_rel, w1_dd_root, w1_sd_rel, w1_sd_root, w1_ds_rel, w1_ds_root,
        w2_dd_rel, w2_dd_root, w2_sd_rel, w2_sd_root, w2_ds_rel, w2_ds_root,
        b1_dd, b1_sd, b1_ds, b2_dd, b2_sd, b2_ds,
        Wd1, Ws1, Wd2, Ws2, bias);

    f2h_kernel<<<(ND * H / 4 + 255) / 256, 256, 0, stream>>>(x_drug, xd_h, ND * H / 4);
    f2h_kernel<<<(NS * H / 4 + 255) / 256, 256, 0, stream>>>(x_se,   xs_h, NS * H / 4);

    // ---- CSR build (once per relation; reused by both layers) ----
    const int nbDD = (ND + 2047) / 2048, nbDS = (NS + 2047) / 2048;
    hist_kernel<<<(EDD + 255) / 256, 256, 0, stream>>>(ei_dd + EDD, EDD, rp_dd);
    hist_kernel<<<(ESD + 255) / 256, 256, 0, stream>>>(ei_sd + ESD, ESD, rp_sd);
    hist_kernel<<<(EDS + 255) / 256, 256, 0, stream>>>(ei_ds + EDS, EDS, rp_ds);

    scan1<<<nbDD, 256, 0, stream>>>(rp_dd, ND, rp_dd, bs_dd);
    scan1<<<nbDD, 256, 0, stream>>>(rp_sd, ND, rp_sd, bs_sd);
    scan1<<<nbDS, 256, 0, stream>>>(rp_ds, NS, rp_ds, bs_ds);
    scan2<<<1, 64, 0, stream>>>(bs_dd, nbDD);
    scan2<<<1, 64, 0, stream>>>(bs_sd, nbDD);
    scan2<<<1, 64, 0, stream>>>(bs_ds, nbDS);
    scan3<<<(ND + 255) / 256, 256, 0, stream>>>(rp_dd, ND, bs_dd, cur_dd, EDD);
    scan3<<<(ND + 255) / 256, 256, 0, stream>>>(rp_sd, ND, bs_sd, cur_sd, ESD);
    scan3<<<(NS + 255) / 256, 256, 0, stream>>>(rp_ds, NS, bs_ds, cur_ds, EDS);

    csr_fill<<<(EDD + 255) / 256, 256, 0, stream>>>(ei_dd, ei_dd + EDD, EDD, cur_dd, si_dd);
    csr_fill<<<(ESD + 255) / 256, 256, 0, stream>>>(ei_sd, ei_sd + ESD, ESD, cur_sd, si_sd);
    csr_fill<<<(EDS + 255) / 256, 256, 0, stream>>>(ei_ds, ei_ds + EDS, EDS, cur_ds, si_ds);

    #define AGG_GRID(N) (((N) + 3) / 4)
    // ---- layer 1 ----
    csr_aggregate<<<AGG_GRID(ND), 256, 0, stream>>>(xd_h, rp_dd, si_dd, segdd, ND);
    csr_aggregate<<<AGG_GRID(ND), 256, 0, stream>>>(xs_h, rp_sd, si_sd, segsd, ND);
    csr_aggregate<<<AGG_GRID(NS), 256, 0, stream>>>(xd_h, rp_ds, si_ds, segds, NS);

    fused_gemm<3, false><<<(ND + 127) / 128, 256, 0, stream>>>(segdd, segsd, xd_h, Wd1, bias, d1h, ND);
    fused_gemm<2, false><<<(NS + 127) / 128, 256, 0, stream>>>(segds, xs_h, nullptr, Ws1, bias + H, s1h, NS);

    // ---- layer 2 (reuse CSR; sources are d1h/s1h) ----
    csr_aggregate<<<AGG_GRID(ND), 256, 0, stream>>>(d1h, rp_dd, si_dd, segdd, ND);
    csr_aggregate<<<AGG_GRID(ND), 256, 0, stream>>>(s1h, rp_sd, si_sd, segsd, ND);
    csr_aggregate<<<AGG_GRID(NS), 256, 0, stream>>>(d1h, rp_ds, si_ds, segds, NS);

    fused_gemm<3, true><<<(ND + 127) / 128, 256, 0, stream>>>(segdd, segsd, d1h, Wd2, bias + 2 * H, d2, ND);
    fused_gemm<2, true><<<(NS + 127) / 128, 256, 0, stream>>>(segds, s1h, nullptr, Ws2, bias + 3 * H, s2, NS);

    // ---- batchnorm ----
    bn_stats<<<512, 128, 0, stream>>>(d2, ND, stats);
    bn_stats<<<512, 128, 0, stream>>>(s2, NS, stats + 256);
    bn_apply<<<(ND * (H / 4) + 255) / 256, 256, 0, stream>>>(d2, ND, stats, gamma, beta);
    bn_apply<<<(NS * (H / 4) + 255) / 256, 256, 0, stream>>>(s2, NS, stats + 256, gamma, beta);
}

// Round 4
// 660.630 us; speedup vs baseline: 9.6035x; 1.0014x over previous
//
#include <hip/hip_runtime.h>
#include <hip/hip_bf16.h>

#define H 128
#define ND 100000
#define NS 10000
#define NB_D 1024   // bn partial blocks for drug table
#define NB_S 128    // bn partial blocks for se table

typedef __attribute__((ext_vector_type(8))) _Float16 f16x8;
typedef __attribute__((ext_vector_type(4))) float f32x4;

__device__ inline ushort f2h(float f) {
    union { _Float16 h; ushort u; } c; c.h = (_Float16)f; return c.u;
}
__device__ inline float h2f(ushort u) {
    union { ushort u; _Float16 h; } c; c.u = u; return (float)c.h;
}

// ---------------- fp32 -> fp16 table convert -------------------------------
__global__ __launch_bounds__(256) void f2h_kernel(
    const float* __restrict__ in, ushort* __restrict__ out, int n4)
{
    int i = blockIdx.x * 256 + threadIdx.x;
    if (i >= n4) return;
    float4 v = reinterpret_cast<const float4*>(in)[i];
    ushort4 o;
    o.x = f2h(v.x); o.y = f2h(v.y); o.z = f2h(v.z); o.w = f2h(v.w);
    reinterpret_cast<ushort4*>(out)[i] = o;
}

// ---------------- weight prep: fp32 -> fp16, fold root weights & biases ----
__global__ void prep_weights(
    const float* w1ddr, const float* w1ddo, const float* w1sdr, const float* w1sdo,
    const float* w1dsr, const float* w1dso,
    const float* w2ddr, const float* w2ddo, const float* w2sdr, const float* w2sdo,
    const float* w2dsr, const float* w2dso,
    const float* b1dd, const float* b1sd, const float* b1ds,
    const float* b2dd, const float* b2sd, const float* b2ds,
    ushort* Wd1, ushort* Ws1, ushort* Wd2, ushort* Ws2, float* bias)
{
    int i = blockIdx.x * blockDim.x + threadIdx.x;
    if (i < 16384) {
        Wd1[i]           = f2h(w1ddr[i]);
        Wd1[16384 + i]   = f2h(w1sdr[i]);
        Wd1[32768 + i]   = f2h(w1ddo[i] + w1sdo[i]);
        Ws1[i]           = f2h(w1dsr[i]);
        Ws1[16384 + i]   = f2h(w1dso[i]);
        Wd2[i]           = f2h(w2ddr[i]);
        Wd2[16384 + i]   = f2h(w2sdr[i]);
        Wd2[32768 + i]   = f2h(w2ddo[i] + w2sdo[i]);
        Ws2[i]           = f2h(w2dsr[i]);
        Ws2[16384 + i]   = f2h(w2dso[i]);
    }
    if (i < H) {
        bias[i]         = b1dd[i] + b1sd[i];
        bias[H + i]     = b1ds[i];
        bias[2*H + i]   = b2dd[i] + b2sd[i];
        bias[3*H + i]   = b2ds[i];
    }
}

// ---------------- CSR build ------------------------------------------------
__global__ __launch_bounds__(256) void hist_kernel(
    const int* __restrict__ ed, int E, int* __restrict__ cnt)
{
    int e = blockIdx.x * 256 + threadIdx.x;
    if (e < E) atomicAdd(&cnt[ed[e]], 1);
}

__global__ __launch_bounds__(256) void scan1(
    const int* __restrict__ cnt, int n, int* __restrict__ out, int* __restrict__ bsum)
{
    __shared__ int sh[256];
    const int t = threadIdx.x;
    const int base = blockIdx.x * 2048 + t * 8;
    int v[8]; int s = 0;
    #pragma unroll
    for (int j = 0; j < 8; ++j) { int i = base + j; v[j] = (i < n) ? cnt[i] : 0; s += v[j]; }
    sh[t] = s; __syncthreads();
    for (int off = 1; off < 256; off <<= 1) {
        int y = (t >= off) ? sh[t - off] : 0;
        __syncthreads();
        sh[t] += y;
        __syncthreads();
    }
    int excl = sh[t] - s;
    #pragma unroll
    for (int j = 0; j < 8; ++j) { int i = base + j; if (i < n) out[i] = excl; excl += v[j]; }
    if (t == 255) bsum[blockIdx.x] = sh[255];
}

__global__ void scan2(int* bsum, int nb)
{
    int t = threadIdx.x;
    int v = (t < nb) ? bsum[t] : 0;
    int x = v;
    for (int off = 1; off < 64; off <<= 1) {
        int y = __shfl_up(x, off);
        if (t >= off) x += y;
    }
    if (t < nb) bsum[t] = x - v;
}

__global__ __launch_bounds__(256) void scan3(
    int* __restrict__ rowptr, int n, const int* __restrict__ bsum,
    int* __restrict__ cursor, int E)
{
    int i = blockIdx.x * 256 + threadIdx.x;
    if (i < n) { int v = rowptr[i] + bsum[i >> 11]; rowptr[i] = v; cursor[i] = v; }
    if (i == 0) rowptr[n] = E;
}

__global__ __launch_bounds__(256) void csr_fill(
    const int* __restrict__ es, const int* __restrict__ ed, int E,
    int* __restrict__ cursor, int* __restrict__ srcidx)
{
    int e = blockIdx.x * 256 + threadIdx.x;
    if (e >= E) return;
    int pos = atomicAdd(&cursor[ed[e]], 1);
    srcidx[pos] = es[e];
}

// ---------------- CSR aggregate: one wave per dest, half-wave per source ---
// lanes: half = lane>>5 picks source within a pair; c = lane&31 covers 8 B.
__global__ __launch_bounds__(256) void csr_aggregate(
    const ushort* __restrict__ src, const int* __restrict__ rowptr,
    const int* __restrict__ srcidx, ushort* __restrict__ dst, int Ndst)
{
    int d = blockIdx.x * 4 + (threadIdx.x >> 6);
    if (d >= Ndst) return;
    int lane = threadIdx.x & 63;
    int half = lane >> 5;
    int c = lane & 31;
    int p0 = rowptr[d], p1 = rowptr[d + 1];
    float a0 = 0.f, a1 = 0.f, a2 = 0.f, a3 = 0.f;
    int p = p0;
    for (; p + 4 <= p1; p += 4) {
        int sA = srcidx[p + half];
        int sB = srcidx[p + 2 + half];
        uint2 vA = *reinterpret_cast<const uint2*>(src + (size_t)sA * H + c * 4);
        uint2 vB = *reinterpret_cast<const uint2*>(src + (size_t)sB * H + c * 4);
        a0 += h2f((ushort)(vA.x & 0xffff)) + h2f((ushort)(vB.x & 0xffff));
        a1 += h2f((ushort)(vA.x >> 16))    + h2f((ushort)(vB.x >> 16));
        a2 += h2f((ushort)(vA.y & 0xffff)) + h2f((ushort)(vB.y & 0xffff));
        a3 += h2f((ushort)(vA.y >> 16))    + h2f((ushort)(vB.y >> 16));
    }
    if (p + 2 <= p1) {
        int sA = srcidx[p + half];
        uint2 vA = *reinterpret_cast<const uint2*>(src + (size_t)sA * H + c * 4);
        a0 += h2f((ushort)(vA.x & 0xffff));
        a1 += h2f((ushort)(vA.x >> 16));
        a2 += h2f((ushort)(vA.y & 0xffff));
        a3 += h2f((ushort)(vA.y >> 16));
        p += 2;
    }
    if (p < p1 && half == 0) {
        int sA = srcidx[p];
        uint2 vA = *reinterpret_cast<const uint2*>(src + (size_t)sA * H + c * 4);
        a0 += h2f((ushort)(vA.x & 0xffff));
        a1 += h2f((ushort)(vA.x >> 16));
        a2 += h2f((ushort)(vA.y & 0xffff));
        a3 += h2f((ushort)(vA.y >> 16));
    }
    a0 += __shfl_xor(a0, 32);
    a1 += __shfl_xor(a1, 32);
    a2 += __shfl_xor(a2, 32);
    a3 += __shfl_xor(a3, 32);
    if (half == 0) {
        uint2 o;
        o.x = (uint)f2h(a0) | ((uint)f2h(a1) << 16);
        o.y = (uint)f2h(a2) | ((uint)f2h(a3) << 16);
        *reinterpret_cast<uint2*>(dst + (size_t)d * H + c * 4) = o;
    }
}

// ---------------- fused GEMM: out = lrelu(sum_s src_s @ W_s^T + bias) ------
template<int NSRC, bool OUTF32>
__global__ __launch_bounds__(256) void fused_gemm(
    const ushort* __restrict__ src0, const ushort* __restrict__ src1,
    const ushort* __restrict__ src2,
    const ushort* __restrict__ W, const float* __restrict__ bias,
    void* __restrict__ outv, int M)
{
    __shared__ ushort Al[128][40];   // [row][k] fp16, padded
    __shared__ ushort Bl[128][40];   // [n][k] fp16

    const int t = threadIdx.x;
    const int wave = t >> 6;
    const int lane = t & 63;
    const int l15 = lane & 15;
    const int kreg = lane >> 4;
    const int block_row = blockIdx.x * 128;

    f32x4 acc[2][8] = {};

    #pragma unroll
    for (int step = 0; step < NSRC * 4; ++step) {
        const int slot = step >> 2;
        const int kc = (step & 3) * 32;
        const ushort* sb = (slot == 0) ? src0 : (slot == 1) ? src1 : src2;

        __syncthreads();
        #pragma unroll
        for (int it = 0; it < 2; ++it) {
            int c = t + it * 256;
            int row = c >> 2, part = c & 3;
            int grow = block_row + row;
            uint4 v = make_uint4(0, 0, 0, 0);
            if (grow < M)
                v = *reinterpret_cast<const uint4*>(sb + (size_t)grow * H + kc + part * 8);
            *reinterpret_cast<uint4*>(&Al[row][part * 8]) = v;
        }
        #pragma unroll
        for (int it = 0; it < 2; ++it) {
            int c = t + it * 256;
            int row = c >> 2, part = c & 3;
            const ushort* gp = W + slot * 16384 + row * 128 + kc + part * 8;
            uint4 v = *reinterpret_cast<const uint4*>(gp);
            *reinterpret_cast<uint4*>(&Bl[row][part * 8]) = v;
        }
        __syncthreads();

        f16x8 a[2], b[8];
        #pragma unroll
        for (int m = 0; m < 2; ++m)
            a[m] = *reinterpret_cast<const f16x8*>(&Al[wave * 32 + m * 16 + l15][kreg * 8]);
        #pragma unroll
        for (int n = 0; n < 8; ++n)
            b[n] = *reinterpret_cast<const f16x8*>(&Bl[n * 16 + l15][kreg * 8]);
        #pragma unroll
        for (int m = 0; m < 2; ++m)
            #pragma unroll
            for (int n = 0; n < 8; ++n)
                acc[m][n] = __builtin_amdgcn_mfma_f32_16x16x32_f16(a[m], b[n], acc[m][n], 0, 0, 0);
    }

    #pragma unroll
    for (int m = 0; m < 2; ++m) {
        int rb = block_row + wave * 32 + m * 16 + kreg * 4;
        #pragma unroll
        for (int n = 0; n < 8; ++n) {
            int col = n * 16 + l15;
            float bv = bias[col];
            #pragma unroll
            for (int r = 0; r < 4; ++r) {
                int row = rb + r;
                if (row < M) {
                    float v = acc[m][n][r] + bv;
                    v = (v > 0.f) ? v : 0.01f * v;
                    if (OUTF32)
                        ((float*)outv)[(size_t)row * H + col] = v;
                    else
                        ((ushort*)outv)[(size_t)row * H + col] = f2h(v);
                }
            }
        }
    }
}

// ---------------- batchnorm stage 1: per-block column partials --------------
// grid-stride float4 loads; partial[block][0..127]=sum, [128..255]=sumsq
__global__ __launch_bounds__(256) void bn_partial(
    const float* __restrict__ x, int total4, float* __restrict__ partial)
{
    __shared__ float shs[8][128], shq[8][128];
    const int t = threadIdx.x;
    float s4[4] = {}, q4[4] = {};
    const int stride = gridDim.x * 256;
    for (int i = blockIdx.x * 256 + t; i < total4; i += stride) {
        float4 v = reinterpret_cast<const float4*>(x)[i];
        const float* vp = &v.x;
        #pragma unroll
        for (int j = 0; j < 4; ++j) { s4[j] += vp[j]; q4[j] += vp[j] * vp[j]; }
    }
    const int g = t >> 5, cg = (t & 31) * 4;
    #pragma unroll
    for (int j = 0; j < 4; ++j) { shs[g][cg + j] = s4[j]; shq[g][cg + j] = q4[j]; }
    __syncthreads();
    float acc = 0.f;
    if (t < 128) {
        #pragma unroll
        for (int k = 0; k < 8; ++k) acc += shs[k][t];
    } else {
        #pragma unroll
        for (int k = 0; k < 8; ++k) acc += shq[k][t - 128];
    }
    partial[blockIdx.x * 256 + t] = acc;
}

// ---------------- batchnorm stage 2: fold partials -> stats -----------------
__global__ void bn_finalize(
    const float* __restrict__ pd, const float* __restrict__ ps,
    float* __restrict__ stats)
{
    int t = threadIdx.x;   // 256
    float a = 0.f, b = 0.f;
    for (int k = 0; k < NB_D; k += 2) {
        a += pd[k * 256 + t];
        b += pd[(k + 1) * 256 + t];
    }
    stats[t] = a + b;
    float c = 0.f, d = 0.f;
    for (int k = 0; k < NB_S; k += 2) {
        c += ps[k * 256 + t];
        d += ps[(k + 1) * 256 + t];
    }
    stats[256 + t] = c + d;
}

// ---------------- batchnorm apply -------------------------------------------
__global__ __launch_bounds__(256) void bn_apply(
    float* x, int M, const float* __restrict__ stats,
    const float* __restrict__ gamma, const float* __restrict__ beta)
{
    size_t i = (size_t)blockIdx.x * 256 + threadIdx.x;
    size_t total = (size_t)M * (H / 4);
    if (i >= total) return;
    int c4 = (int)(i & (H / 4 - 1)) * 4;
    float4 v = reinterpret_cast<float4*>(x)[i];
    float inv_m = 1.0f / (float)M;
    float* vp = &v.x;
    #pragma unroll
    for (int j = 0; j < 4; ++j) {
        int c = c4 + j;
        float mean = stats[c] * inv_m;
        float var = stats[H + c] * inv_m - mean * mean;
        float sc = gamma[c] * rsqrtf(fmaxf(var, 0.f) + 1e-5f);
        vp[j] = (vp[j] - mean) * sc + beta[c];
    }
    reinterpret_cast<float4*>(x)[i] = v;
}

// ---------------- launch ----------------------------------------------------
extern "C" void kernel_launch(void* const* d_in, const int* in_sizes, int n_in,
                              void* d_out, int out_size, void* d_ws, size_t ws_size,
                              hipStream_t stream)
{
    (void)n_in; (void)out_size; (void)ws_size;
    const float* x_drug = (const float*)d_in[0];
    const float* x_se   = (const float*)d_in[1];
    const int* ei_dd = (const int*)d_in[2];
    const int* ei_ds = (const int*)d_in[3];
    const int* ei_sd = (const int*)d_in[4];
    const int EDD = in_sizes[2] / 2;
    const int EDS = in_sizes[3] / 2;
    const int ESD = in_sizes[4] / 2;

    const float* w1_dd_rel  = (const float*)d_in[5];
    const float* b1_dd      = (const float*)d_in[6];
    const float* w1_dd_root = (const float*)d_in[7];
    const float* w1_ds_rel  = (const float*)d_in[8];
    const float* b1_ds      = (const float*)d_in[9];
    const float* w1_ds_root = (const float*)d_in[10];
    const float* w1_sd_rel  = (const float*)d_in[11];
    const float* b1_sd      = (const float*)d_in[12];
    const float* w1_sd_root = (const float*)d_in[13];
    const float* w2_dd_rel  = (const float*)d_in[14];
    const float* b2_dd      = (const float*)d_in[15];
    const float* w2_dd_root = (const float*)d_in[16];
    const float* w2_ds_rel  = (const float*)d_in[17];
    const float* b2_ds      = (const float*)d_in[18];
    const float* w2_ds_root = (const float*)d_in[19];
    const float* w2_sd_rel  = (const float*)d_in[20];
    const float* b2_sd      = (const float*)d_in[21];
    const float* w2_sd_root = (const float*)d_in[22];
    const float* gamma      = (const float*)d_in[23];
    const float* beta       = (const float*)d_in[24];

    // ---------------- workspace layout ----------------
    ushort* xd_h  = (ushort*)d_ws;                     // ND*H fp16 (becomes d1h in place)
    ushort* xs_h  = xd_h + (size_t)ND * H;             // NS*H fp16 (becomes s1h)
    ushort* segdd = xs_h + (size_t)NS * H;             // ND*H
    ushort* segsd = segdd + (size_t)ND * H;            // ND*H
    ushort* segds = segsd + (size_t)ND * H;            // NS*H
    ushort* Wd1 = segds + (size_t)NS * H;              // 3*16384
    ushort* Ws1 = Wd1 + 3 * 16384;                     // 2*16384
    ushort* Wd2 = Ws1 + 2 * 16384;                     // 3*16384
    ushort* Ws2 = Wd2 + 3 * 16384;                     // 2*16384
    float* bias  = (float*)(Ws2 + 2 * 16384);          // 512
    float* stats = bias + 512;                         // 512
    float* pd    = stats + 512;                        // NB_D*256
    float* ps    = pd + NB_D * 256;                    // NB_S*256
    int* rp_dd = (int*)(ps + NB_S * 256);              // ND+1
    int* rp_sd = rp_dd + (ND + 1);                     // ND+1
    int* rp_ds = rp_sd + (ND + 1);                     // NS+1
    int* cur_dd = rp_ds + (NS + 1);                    // ND
    int* cur_sd = cur_dd + ND;                         // ND
    int* cur_ds = cur_sd + ND;                         // NS
    int* si_dd = cur_ds + NS;                          // EDD
    int* si_sd = si_dd + EDD;                          // ESD
    int* si_ds = si_sd + ESD;                          // EDS
    int* bs_dd = si_ds + EDS;                          // 64
    int* bs_sd = bs_dd + 64;                           // 64
    int* bs_ds = bs_sd + 64;                           // 64

    ushort* d1h = xd_h;
    ushort* s1h = xs_h;

    float* d2 = (float*)d_out;                // ND*H
    float* s2 = d2 + (size_t)ND * H;          // NS*H

    // zero the histogram/rowptr region only (no atomics elsewhere now)
    hipMemsetAsync(rp_dd, 0, ((size_t)2 * (ND + 1) + (NS + 1)) * sizeof(int), stream);

    prep_weights<<<64, 256, 0, stream>>>(
        w1_dd_rel, w1_dd_root, w1_sd_rel, w1_sd_root, w1_ds_rel, w1_ds_root,
        w2_dd_rel, w2_dd_root, w2_sd_rel, w2_sd_root, w2_ds_rel, w2_ds_root,
        b1_dd, b1_sd, b1_ds, b2_dd, b2_sd, b2_ds,
        Wd1, Ws1, Wd2, Ws2, bias);

    f2h_kernel<<<(ND * H / 4 + 255) / 256, 256, 0, stream>>>(x_drug, xd_h, ND * H / 4);
    f2h_kernel<<<(NS * H / 4 + 255) / 256, 256, 0, stream>>>(x_se,   xs_h, NS * H / 4);

    // ---- CSR build (once per relation; reused by both layers) ----
    const int nbDD = (ND + 2047) / 2048, nbDS = (NS + 2047) / 2048;
    hist_kernel<<<(EDD + 255) / 256, 256, 0, stream>>>(ei_dd + EDD, EDD, rp_dd);
    hist_kernel<<<(ESD + 255) / 256, 256, 0, stream>>>(ei_sd + ESD, ESD, rp_sd);
    hist_kernel<<<(EDS + 255) / 256, 256, 0, stream>>>(ei_ds + EDS, EDS, rp_ds);

    scan1<<<nbDD, 256, 0, stream>>>(rp_dd, ND, rp_dd, bs_dd);
    scan1<<<nbDD, 256, 0, stream>>>(rp_sd, ND, rp_sd, bs_sd);
    scan1<<<nbDS, 256, 0, stream>>>(rp_ds, NS, rp_ds, bs_ds);
    scan2<<<1, 64, 0, stream>>>(bs_dd, nbDD);
    scan2<<<1, 64, 0, stream>>>(bs_sd, nbDD);
    scan2<<<1, 64, 0, stream>>>(bs_ds, nbDS);
    scan3<<<(ND + 255) / 256, 256, 0, stream>>>(rp_dd, ND, bs_dd, cur_dd, EDD);
    scan3<<<(ND + 255) / 256, 256, 0, stream>>>(rp_sd, ND, bs_sd, cur_sd, ESD);
    scan3<<<(NS + 255) / 256, 256, 0, stream>>>(rp_ds, NS, bs_ds, cur_ds, EDS);

    csr_fill<<<(EDD + 255) / 256, 256, 0, stream>>>(ei_dd, ei_dd + EDD, EDD, cur_dd, si_dd);
    csr_fill<<<(ESD + 255) / 256, 256, 0, stream>>>(ei_sd, ei_sd + ESD, ESD, cur_sd, si_sd);
    csr_fill<<<(EDS + 255) / 256, 256, 0, stream>>>(ei_ds, ei_ds + EDS, EDS, cur_ds, si_ds);

    #define AGG_GRID(N) (((N) + 3) / 4)
    // ---- layer 1 ----
    csr_aggregate<<<AGG_GRID(ND), 256, 0, stream>>>(xd_h, rp_dd, si_dd, segdd, ND);
    csr_aggregate<<<AGG_GRID(ND), 256, 0, stream>>>(xs_h, rp_sd, si_sd, segsd, ND);
    csr_aggregate<<<AGG_GRID(NS), 256, 0, stream>>>(xd_h, rp_ds, si_ds, segds, NS);

    fused_gemm<3, false><<<(ND + 127) / 128, 256, 0, stream>>>(segdd, segsd, xd_h, Wd1, bias, d1h, ND);
    fused_gemm<2, false><<<(NS + 127) / 128, 256, 0, stream>>>(segds, xs_h, nullptr, Ws1, bias + H, s1h, NS);

    // ---- layer 2 (reuse CSR; sources are d1h/s1h) ----
    csr_aggregate<<<AGG_GRID(ND), 256, 0, stream>>>(d1h, rp_dd, si_dd, segdd, ND);
    csr_aggregate<<<AGG_GRID(ND), 256, 0, stream>>>(s1h, rp_sd, si_sd, segsd, ND);
    csr_aggregate<<<AGG_GRID(NS), 256, 0, stream>>>(d1h, rp_ds, si_ds, segds, NS);

    fused_gemm<3, true><<<(ND + 127) / 128, 256, 0, stream>>>(segdd, segsd, d1h, Wd2, bias + 2 * H, d2, ND);
    fused_gemm<2, true><<<(NS + 127) / 128, 256, 0, stream>>>(segds, s1h, nullptr, Ws2, bias + 3 * H, s2, NS);

    // ---- batchnorm: partial -> finalize -> apply ----
    bn_partial<<<NB_D, 256, 0, stream>>>(d2, ND * (H / 4), pd);
    bn_partial<<<NB_S, 256, 0, stream>>>(s2, NS * (H / 4), ps);
    bn_finalize<<<1, 256, 0, stream>>>(pd, ps, stats);
    bn_apply<<<(ND * (H / 4) + 255) / 256, 256, 0, stream>>>(d2, ND, stats, gamma, beta);
    bn_apply<<<(NS * (H / 4) + 255) / 256, 256, 0, stream>>>(s2, NS, stats + 256, gamma, beta);
}

// Round 5
// 627.361 us; speedup vs baseline: 10.1128x; 1.0530x over previous
//
#include <hip/hip_runtime.h>
#include <hip/hip_bf16.h>

#define H 128
#define ND 100000
#define NS 10000
#define NB_D 1024   // bn partial blocks for drug table
#define NB_S 128    // bn partial blocks for se table

typedef __attribute__((ext_vector_type(8))) _Float16 f16x8;
typedef __attribute__((ext_vector_type(4))) float f32x4;

__device__ inline ushort f2h(float f) {
    union { _Float16 h; ushort u; } c; c.h = (_Float16)f; return c.u;
}
__device__ inline float h2f(ushort u) {
    union { ushort u; _Float16 h; } c; c.u = u; return (float)c.h;
}

// ---------------- fp32 -> fp16 table convert -------------------------------
__global__ __launch_bounds__(256) void f2h_kernel(
    const float* __restrict__ in, ushort* __restrict__ out, int n4)
{
    int i = blockIdx.x * 256 + threadIdx.x;
    if (i >= n4) return;
    float4 v = reinterpret_cast<const float4*>(in)[i];
    ushort4 o;
    o.x = f2h(v.x); o.y = f2h(v.y); o.z = f2h(v.z); o.w = f2h(v.w);
    reinterpret_cast<ushort4*>(out)[i] = o;
}

// ---------------- weight prep: fp32 -> fp16, fold root weights & biases ----
__global__ void prep_weights(
    const float* w1ddr, const float* w1ddo, const float* w1sdr, const float* w1sdo,
    const float* w1dsr, const float* w1dso,
    const float* w2ddr, const float* w2ddo, const float* w2sdr, const float* w2sdo,
    const float* w2dsr, const float* w2dso,
    const float* b1dd, const float* b1sd, const float* b1ds,
    const float* b2dd, const float* b2sd, const float* b2ds,
    ushort* Wd1, ushort* Ws1, ushort* Wd2, ushort* Ws2, float* bias)
{
    int i = blockIdx.x * blockDim.x + threadIdx.x;
    if (i < 16384) {
        Wd1[i]           = f2h(w1ddr[i]);
        Wd1[16384 + i]   = f2h(w1sdr[i]);
        Wd1[32768 + i]   = f2h(w1ddo[i] + w1sdo[i]);
        Ws1[i]           = f2h(w1dsr[i]);
        Ws1[16384 + i]   = f2h(w1dso[i]);
        Wd2[i]           = f2h(w2ddr[i]);
        Wd2[16384 + i]   = f2h(w2sdr[i]);
        Wd2[32768 + i]   = f2h(w2ddo[i] + w2sdo[i]);
        Ws2[i]           = f2h(w2dsr[i]);
        Ws2[16384 + i]   = f2h(w2dso[i]);
    }
    if (i < H) {
        bias[i]         = b1dd[i] + b1sd[i];
        bias[H + i]     = b1ds[i];
        bias[2*H + i]   = b2dd[i] + b2sd[i];
        bias[3*H + i]   = b2ds[i];
    }
}

// ---------------- CSR build ------------------------------------------------
__global__ __launch_bounds__(256) void hist_kernel(
    const int* __restrict__ ed, int E, int* __restrict__ cnt)
{
    int e = blockIdx.x * 256 + threadIdx.x;
    if (e < E) atomicAdd(&cnt[ed[e]], 1);
}

__global__ __launch_bounds__(256) void scan1(
    const int* __restrict__ cnt, int n, int* __restrict__ out, int* __restrict__ bsum)
{
    __shared__ int sh[256];
    const int t = threadIdx.x;
    const int base = blockIdx.x * 2048 + t * 8;
    int v[8]; int s = 0;
    #pragma unroll
    for (int j = 0; j < 8; ++j) { int i = base + j; v[j] = (i < n) ? cnt[i] : 0; s += v[j]; }
    sh[t] = s; __syncthreads();
    for (int off = 1; off < 256; off <<= 1) {
        int y = (t >= off) ? sh[t - off] : 0;
        __syncthreads();
        sh[t] += y;
        __syncthreads();
    }
    int excl = sh[t] - s;
    #pragma unroll
    for (int j = 0; j < 8; ++j) { int i = base + j; if (i < n) out[i] = excl; excl += v[j]; }
    if (t == 255) bsum[blockIdx.x] = sh[255];
}

__global__ void scan2(int* bsum, int nb)
{
    int t = threadIdx.x;
    int v = (t < nb) ? bsum[t] : 0;
    int x = v;
    for (int off = 1; off < 64; off <<= 1) {
        int y = __shfl_up(x, off);
        if (t >= off) x += y;
    }
    if (t < nb) bsum[t] = x - v;
}

__global__ __launch_bounds__(256) void scan3(
    int* __restrict__ rowptr, int n, const int* __restrict__ bsum,
    int* __restrict__ cursor, int E)
{
    int i = blockIdx.x * 256 + threadIdx.x;
    if (i < n) { int v = rowptr[i] + bsum[i >> 11]; rowptr[i] = v; cursor[i] = v; }
    if (i == 0) rowptr[n] = E;
}

__global__ __launch_bounds__(256) void csr_fill(
    const int* __restrict__ es, const int* __restrict__ ed, int E,
    int* __restrict__ cursor, int* __restrict__ srcidx)
{
    int e = blockIdx.x * 256 + threadIdx.x;
    if (e >= E) return;
    int pos = atomicAdd(&cursor[ed[e]], 1);
    srcidx[pos] = es[e];
}

// ---------------- CSR aggregate: one wave per dest, half-wave per source ---
__global__ __launch_bounds__(256) void csr_aggregate(
    const ushort* __restrict__ src, const int* __restrict__ rowptr,
    const int* __restrict__ srcidx, ushort* __restrict__ dst, int Ndst)
{
    int d = blockIdx.x * 4 + (threadIdx.x >> 6);
    if (d >= Ndst) return;
    int lane = threadIdx.x & 63;
    int half = lane >> 5;
    int c = lane & 31;
    int p0 = rowptr[d], p1 = rowptr[d + 1];
    float a0 = 0.f, a1 = 0.f, a2 = 0.f, a3 = 0.f;
    int p = p0;
    for (; p + 4 <= p1; p += 4) {
        int sA = srcidx[p + half];
        int sB = srcidx[p + 2 + half];
        uint2 vA = *reinterpret_cast<const uint2*>(src + (size_t)sA * H + c * 4);
        uint2 vB = *reinterpret_cast<const uint2*>(src + (size_t)sB * H + c * 4);
        a0 += h2f((ushort)(vA.x & 0xffff)) + h2f((ushort)(vB.x & 0xffff));
        a1 += h2f((ushort)(vA.x >> 16))    + h2f((ushort)(vB.x >> 16));
        a2 += h2f((ushort)(vA.y & 0xffff)) + h2f((ushort)(vB.y & 0xffff));
        a3 += h2f((ushort)(vA.y >> 16))    + h2f((ushort)(vB.y >> 16));
    }
    if (p + 2 <= p1) {
        int sA = srcidx[p + half];
        uint2 vA = *reinterpret_cast<const uint2*>(src + (size_t)sA * H + c * 4);
        a0 += h2f((ushort)(vA.x & 0xffff));
        a1 += h2f((ushort)(vA.x >> 16));
        a2 += h2f((ushort)(vA.y & 0xffff));
        a3 += h2f((ushort)(vA.y >> 16));
        p += 2;
    }
    if (p < p1 && half == 0) {
        int sA = srcidx[p];
        uint2 vA = *reinterpret_cast<const uint2*>(src + (size_t)sA * H + c * 4);
        a0 += h2f((ushort)(vA.x & 0xffff));
        a1 += h2f((ushort)(vA.x >> 16));
        a2 += h2f((ushort)(vA.y & 0xffff));
        a3 += h2f((ushort)(vA.y >> 16));
    }
    a0 += __shfl_xor(a0, 32);
    a1 += __shfl_xor(a1, 32);
    a2 += __shfl_xor(a2, 32);
    a3 += __shfl_xor(a3, 32);
    if (half == 0) {
        uint2 o;
        o.x = (uint)f2h(a0) | ((uint)f2h(a1) << 16);
        o.y = (uint)f2h(a2) | ((uint)f2h(a3) << 16);
        *reinterpret_cast<uint2*>(dst + (size_t)d * H + c * 4) = o;
    }
}

// ---------------- fused GEMM: out = lrelu(sum_s src_s @ W_s^T + bias) ------
template<int NSRC, bool OUTF32>
__global__ __launch_bounds__(256) void fused_gemm(
    const ushort* __restrict__ src0, const ushort* __restrict__ src1,
    const ushort* __restrict__ src2,
    const ushort* __restrict__ W, const float* __restrict__ bias,
    void* __restrict__ outv, int M)
{
    __shared__ ushort Al[128][40];   // [row][k] fp16, padded
    __shared__ ushort Bl[128][40];   // [n][k] fp16

    const int t = threadIdx.x;
    const int wave = t >> 6;
    const int lane = t & 63;
    const int l15 = lane & 15;
    const int kreg = lane >> 4;
    const int block_row = blockIdx.x * 128;

    f32x4 acc[2][8] = {};

    #pragma unroll
    for (int step = 0; step < NSRC * 4; ++step) {
        const int slot = step >> 2;
        const int kc = (step & 3) * 32;
        const ushort* sb = (slot == 0) ? src0 : (slot == 1) ? src1 : src2;

        __syncthreads();
        #pragma unroll
        for (int it = 0; it < 2; ++it) {
            int c = t + it * 256;
            int row = c >> 2, part = c & 3;
            int grow = block_row + row;
            uint4 v = make_uint4(0, 0, 0, 0);
            if (grow < M)
                v = *reinterpret_cast<const uint4*>(sb + (size_t)grow * H + kc + part * 8);
            *reinterpret_cast<uint4*>(&Al[row][part * 8]) = v;
        }
        #pragma unroll
        for (int it = 0; it < 2; ++it) {
            int c = t + it * 256;
            int row = c >> 2, part = c & 3;
            const ushort* gp = W + slot * 16384 + row * 128 + kc + part * 8;
            uint4 v = *reinterpret_cast<const uint4*>(gp);
            *reinterpret_cast<uint4*>(&Bl[row][part * 8]) = v;
        }
        __syncthreads();

        f16x8 a[2], b[8];
        #pragma unroll
        for (int m = 0; m < 2; ++m)
            a[m] = *reinterpret_cast<const f16x8*>(&Al[wave * 32 + m * 16 + l15][kreg * 8]);
        #pragma unroll
        for (int n = 0; n < 8; ++n)
            b[n] = *reinterpret_cast<const f16x8*>(&Bl[n * 16 + l15][kreg * 8]);
        #pragma unroll
        for (int m = 0; m < 2; ++m)
            #pragma unroll
            for (int n = 0; n < 8; ++n)
                acc[m][n] = __builtin_amdgcn_mfma_f32_16x16x32_f16(a[m], b[n], acc[m][n], 0, 0, 0);
    }

    #pragma unroll
    for (int m = 0; m < 2; ++m) {
        int rb = block_row + wave * 32 + m * 16 + kreg * 4;
        #pragma unroll
        for (int n = 0; n < 8; ++n) {
            int col = n * 16 + l15;
            float bv = bias[col];
            #pragma unroll
            for (int r = 0; r < 4; ++r) {
                int row = rb + r;
                if (row < M) {
                    float v = acc[m][n][r] + bv;
                    v = (v > 0.f) ? v : 0.01f * v;
                    if (OUTF32)
                        ((float*)outv)[(size_t)row * H + col] = v;
                    else
                        ((ushort*)outv)[(size_t)row * H + col] = f2h(v);
                }
            }
        }
    }
}

// ---------------- batchnorm stage 1: per-block column partials --------------
__global__ __launch_bounds__(256) void bn_partial(
    const float* __restrict__ x, int total4, float* __restrict__ partial)
{
    __shared__ float shs[8][128], shq[8][128];
    const int t = threadIdx.x;
    float s4[4] = {}, q4[4] = {};
    const int stride = gridDim.x * 256;
    for (int i = blockIdx.x * 256 + t; i < total4; i += stride) {
        float4 v = reinterpret_cast<const float4*>(x)[i];
        const float* vp = &v.x;
        #pragma unroll
        for (int j = 0; j < 4; ++j) { s4[j] += vp[j]; q4[j] += vp[j] * vp[j]; }
    }
    const int g = t >> 5, cg = (t & 31) * 4;
    #pragma unroll
    for (int j = 0; j < 4; ++j) { shs[g][cg + j] = s4[j]; shq[g][cg + j] = q4[j]; }
    __syncthreads();
    float acc = 0.f;
    if (t < 128) {
        #pragma unroll
        for (int k = 0; k < 8; ++k) acc += shs[k][t];
    } else {
        #pragma unroll
        for (int k = 0; k < 8; ++k) acc += shq[k][t - 128];
    }
    partial[blockIdx.x * 256 + t] = acc;
}

// ---------------- batchnorm stage 2: parallel fold + atomic -----------------
// grid.x blocks each reduce a k-slice of partial[nb][256]; atomicAdd into
// stats[soff + t] (stats zeroed by the launch memset).
__global__ __launch_bounds__(256) void bn_finalize(
    const float* __restrict__ partial, int nb, float* __restrict__ stats)
{
    const int t = threadIdx.x;
    int per = (nb + gridDim.x - 1) / gridDim.x;
    int k0 = blockIdx.x * per;
    int k1 = min(k0 + per, nb);
    if (k0 >= nb) return;
    float acc = 0.f;
    for (int k = k0; k < k1; ++k) acc += partial[k * 256 + t];
    atomicAdd(&stats[t], acc);
}

// ---------------- batchnorm apply: both tables in one launch ----------------
__global__ __launch_bounds__(256) void bn_apply_all(
    float* __restrict__ d2, float* __restrict__ s2,
    const float* __restrict__ stats,
    const float* __restrict__ gamma, const float* __restrict__ beta)
{
    size_t i = (size_t)blockIdx.x * 256 + threadIdx.x;
    const size_t totD = (size_t)ND * (H / 4);
    const size_t totAll = totD + (size_t)NS * (H / 4);
    if (i >= totAll) return;
    float* x;
    const float* st;
    float inv_m;
    size_t j;
    if (i < totD) { x = d2; st = stats;       inv_m = 1.0f / ND; j = i; }
    else          { x = s2; st = stats + 256; inv_m = 1.0f / NS; j = i - totD; }
    int c4 = (int)(j & (H / 4 - 1)) * 4;
    float4 v = reinterpret_cast<float4*>(x)[j];
    float* vp = &v.x;
    #pragma unroll
    for (int k = 0; k < 4; ++k) {
        int c = c4 + k;
        float mean = st[c] * inv_m;
        float var = st[H + c] * inv_m - mean * mean;
        float sc = gamma[c] * rsqrtf(fmaxf(var, 0.f) + 1e-5f);
        vp[k] = (vp[k] - mean) * sc + beta[c];
    }
    reinterpret_cast<float4*>(x)[j] = v;
}

// ---------------- launch ----------------------------------------------------
extern "C" void kernel_launch(void* const* d_in, const int* in_sizes, int n_in,
                              void* d_out, int out_size, void* d_ws, size_t ws_size,
                              hipStream_t stream)
{
    (void)n_in; (void)out_size; (void)ws_size;
    const float* x_drug = (const float*)d_in[0];
    const float* x_se   = (const float*)d_in[1];
    const int* ei_dd = (const int*)d_in[2];
    const int* ei_ds = (const int*)d_in[3];
    const int* ei_sd = (const int*)d_in[4];
    const int EDD = in_sizes[2] / 2;
    const int EDS = in_sizes[3] / 2;
    const int ESD = in_sizes[4] / 2;

    const float* w1_dd_rel  = (const float*)d_in[5];
    const float* b1_dd      = (const float*)d_in[6];
    const float* w1_dd_root = (const float*)d_in[7];
    const float* w1_ds_rel  = (const float*)d_in[8];
    const float* b1_ds      = (const float*)d_in[9];
    const float* w1_ds_root = (const float*)d_in[10];
    const float* w1_sd_rel  = (const float*)d_in[11];
    const float* b1_sd      = (const float*)d_in[12];
    const float* w1_sd_root = (const float*)d_in[13];
    const float* w2_dd_rel  = (const float*)d_in[14];
    const float* b2_dd      = (const float*)d_in[15];
    const float* w2_dd_root = (const float*)d_in[16];
    const float* w2_ds_rel  = (const float*)d_in[17];
    const float* b2_ds      = (const float*)d_in[18];
    const float* w2_ds_root = (const float*)d_in[19];
    const float* w2_sd_rel  = (const float*)d_in[20];
    const float* b2_sd      = (const float*)d_in[21];
    const float* w2_sd_root = (const float*)d_in[22];
    const float* gamma      = (const float*)d_in[23];
    const float* beta       = (const float*)d_in[24];

    // ---------------- workspace layout ----------------
    ushort* xd_h  = (ushort*)d_ws;                     // ND*H fp16 (becomes d1h in place)
    ushort* xs_h  = xd_h + (size_t)ND * H;             // NS*H fp16 (becomes s1h)
    ushort* segdd = xs_h + (size_t)NS * H;             // ND*H
    ushort* segsd = segdd + (size_t)ND * H;            // ND*H
    ushort* segds = segsd + (size_t)ND * H;            // NS*H
    ushort* Wd1 = segds + (size_t)NS * H;              // 3*16384
    ushort* Ws1 = Wd1 + 3 * 16384;                     // 2*16384
    ushort* Wd2 = Ws1 + 2 * 16384;                     // 3*16384
    ushort* Ws2 = Wd2 + 3 * 16384;                     // 2*16384
    float* bias  = (float*)(Ws2 + 2 * 16384);          // 512
    float* pd    = bias + 512;                         // NB_D*256
    float* ps    = pd + NB_D * 256;                    // NB_S*256
    float* stats = ps + NB_S * 256;                    // 512 (zeroed w/ rowptrs)
    int* rp_dd = (int*)(stats + 512);                  // ND+1
    int* rp_sd = rp_dd + (ND + 1);                     // ND+1
    int* rp_ds = rp_sd + (ND + 1);                     // NS+1
    int* cur_dd = rp_ds + (NS + 1);                    // ND
    int* cur_sd = cur_dd + ND;                         // ND
    int* cur_ds = cur_sd + ND;                         // NS
    int* si_dd = cur_ds + NS;                          // EDD
    int* si_sd = si_dd + EDD;                          // ESD
    int* si_ds = si_sd + ESD;                          // EDS
    int* bs_dd = si_ds + EDS;                          // 64
    int* bs_sd = bs_dd + 64;                           // 64
    int* bs_ds = bs_sd + 64;                           // 64

    ushort* d1h = xd_h;
    ushort* s1h = xs_h;

    float* d2 = (float*)d_out;                // ND*H
    float* s2 = d2 + (size_t)ND * H;          // NS*H

    // zero stats + histogram/rowptr region (contiguous)
    hipMemsetAsync(stats, 0, (512 + (size_t)2 * (ND + 1) + (NS + 1)) * sizeof(int), stream);

    prep_weights<<<64, 256, 0, stream>>>(
        w1_dd_rel, w1_dd_root, w1_sd_rel, w1_sd_root, w1_ds_rel, w1_ds_root,
        w2_dd_rel, w2_dd_root, w2_sd_rel, w2_sd_root, w2_ds_rel, w2_ds_root,
        b1_dd, b1_sd, b1_ds, b2_dd, b2_sd, b2_ds,
        Wd1, Ws1, Wd2, Ws2, bias);

    f2h_kernel<<<(ND * H / 4 + 255) / 256, 256, 0, stream>>>(x_drug, xd_h, ND * H / 4);
    f2h_kernel<<<(NS * H / 4 + 255) / 256, 256, 0, stream>>>(x_se,   xs_h, NS * H / 4);

    // ---- CSR build (once per relation; reused by both layers) ----
    const int nbDD = (ND + 2047) / 2048, nbDS = (NS + 2047) / 2048;
    hist_kernel<<<(EDD + 255) / 256, 256, 0, stream>>>(ei_dd + EDD, EDD, rp_dd);
    hist_kernel<<<(ESD + 255) / 256, 256, 0, stream>>>(ei_sd + ESD, ESD, rp_sd);
    hist_kernel<<<(EDS + 255) / 256, 256, 0, stream>>>(ei_ds + EDS, EDS, rp_ds);

    scan1<<<nbDD, 256, 0, stream>>>(rp_dd, ND, rp_dd, bs_dd);
    scan1<<<nbDD, 256, 0, stream>>>(rp_sd, ND, rp_sd, bs_sd);
    scan1<<<nbDS, 256, 0, stream>>>(rp_ds, NS, rp_ds, bs_ds);
    scan2<<<1, 64, 0, stream>>>(bs_dd, nbDD);
    scan2<<<1, 64, 0, stream>>>(bs_sd, nbDD);
    scan2<<<1, 64, 0, stream>>>(bs_ds, nbDS);
    scan3<<<(ND + 255) / 256, 256, 0, stream>>>(rp_dd, ND, bs_dd, cur_dd, EDD);
    scan3<<<(ND + 255) / 256, 256, 0, stream>>>(rp_sd, ND, bs_sd, cur_sd, ESD);
    scan3<<<(NS + 255) / 256, 256, 0, stream>>>(rp_ds, NS, bs_ds, cur_ds, EDS);

    csr_fill<<<(EDD + 255) / 256, 256, 0, stream>>>(ei_dd, ei_dd + EDD, EDD, cur_dd, si_dd);
    csr_fill<<<(ESD + 255) / 256, 256, 0, stream>>>(ei_sd, ei_sd + ESD, ESD, cur_sd, si_sd);
    csr_fill<<<(EDS + 255) / 256, 256, 0, stream>>>(ei_ds, ei_ds + EDS, EDS, cur_ds, si_ds);

    #define AGG_GRID(N) (((N) + 3) / 4)
    // ---- layer 1 ----
    csr_aggregate<<<AGG_GRID(ND), 256, 0, stream>>>(xd_h, rp_dd, si_dd, segdd, ND);
    csr_aggregate<<<AGG_GRID(ND), 256, 0, stream>>>(xs_h, rp_sd, si_sd, segsd, ND);
    csr_aggregate<<<AGG_GRID(NS), 256, 0, stream>>>(xd_h, rp_ds, si_ds, segds, NS);

    fused_gemm<3, false><<<(ND + 127) / 128, 256, 0, stream>>>(segdd, segsd, xd_h, Wd1, bias, d1h, ND);
    fused_gemm<2, false><<<(NS + 127) / 128, 256, 0, stream>>>(segds, xs_h, nullptr, Ws1, bias + H, s1h, NS);

    // ---- layer 2 (reuse CSR; sources are d1h/s1h) ----
    csr_aggregate<<<AGG_GRID(ND), 256, 0, stream>>>(d1h, rp_dd, si_dd, segdd, ND);
    csr_aggregate<<<AGG_GRID(ND), 256, 0, stream>>>(s1h, rp_sd, si_sd, segsd, ND);
    csr_aggregate<<<AGG_GRID(NS), 256, 0, stream>>>(d1h, rp_ds, si_ds, segds, NS);

    fused_gemm<3, true><<<(ND + 127) / 128, 256, 0, stream>>>(segdd, segsd, d1h, Wd2, bias + 2 * H, d2, ND);
    fused_gemm<2, true><<<(NS + 127) / 128, 256, 0, stream>>>(segds, s1h, nullptr, Ws2, bias + 3 * H, s2, NS);

    // ---- batchnorm: partial -> parallel finalize -> fused apply ----
    bn_partial<<<NB_D, 256, 0, stream>>>(d2, ND * (H / 4), pd);
    bn_partial<<<NB_S, 256, 0, stream>>>(s2, NS * (H / 4), ps);
    bn_finalize<<<32, 256, 0, stream>>>(pd, NB_D, stats);
    bn_finalize<<<8,  256, 0, stream>>>(ps, NB_S, stats + 256);
    bn_apply_all<<<((ND + NS) * (H / 4) + 255) / 256, 256, 0, stream>>>(d2, s2, stats, gamma, beta);
}

// Round 7
// 608.765 us; speedup vs baseline: 10.4217x; 1.0305x over previous
//
#include <hip/hip_runtime.h>
#include <hip/hip_bf16.h>

#define H 128
#define ND 100000
#define NS 10000

typedef __attribute__((ext_vector_type(8))) _Float16 f16x8;
typedef __attribute__((ext_vector_type(4))) float f32x4;

__device__ inline ushort f2h(float f) {
    union { _Float16 h; ushort u; } c; c.h = (_Float16)f; return c.u;
}
__device__ inline float h2f(ushort u) {
    union { ushort u; _Float16 h; } c; c.u = u; return (float)c.h;
}

// ---------------- fp32 -> fp16 convert, both tables, one launch -------------
__global__ __launch_bounds__(256) void f2h_all(
    const float* __restrict__ xd, const float* __restrict__ xs,
    ushort* __restrict__ od, ushort* __restrict__ os)
{
    int i = blockIdx.x * 256 + threadIdx.x;
    const int nD = ND * H / 4;
    const int nT = (ND + NS) * H / 4;
    if (i >= nT) return;
    const float* in; ushort* out; int j;
    if (i < nD) { in = xd; out = od; j = i; }
    else        { in = xs; out = os; j = i - nD; }
    float4 v = reinterpret_cast<const float4*>(in)[j];
    ushort4 o;
    o.x = f2h(v.x); o.y = f2h(v.y); o.z = f2h(v.z); o.w = f2h(v.w);
    reinterpret_cast<ushort4*>(out)[j] = o;
}

// ---------------- weight prep: fp32 -> fp16, fold root weights & biases ----
__global__ void prep_weights(
    const float* w1ddr, const float* w1ddo, const float* w1sdr, const float* w1sdo,
    const float* w1dsr, const float* w1dso,
    const float* w2ddr, const float* w2ddo, const float* w2sdr, const float* w2sdo,
    const float* w2dsr, const float* w2dso,
    const float* b1dd, const float* b1sd, const float* b1ds,
    const float* b2dd, const float* b2sd, const float* b2ds,
    ushort* Wd1, ushort* Ws1, ushort* Wd2, ushort* Ws2, float* bias)
{
    int i = blockIdx.x * blockDim.x + threadIdx.x;
    if (i < 16384) {
        Wd1[i]           = f2h(w1ddr[i]);
        Wd1[16384 + i]   = f2h(w1sdr[i]);
        Wd1[32768 + i]   = f2h(w1ddo[i] + w1sdo[i]);
        Ws1[i]           = f2h(w1dsr[i]);
        Ws1[16384 + i]   = f2h(w1dso[i]);
        Wd2[i]           = f2h(w2ddr[i]);
        Wd2[16384 + i]   = f2h(w2sdr[i]);
        Wd2[32768 + i]   = f2h(w2ddo[i] + w2sdo[i]);
        Ws2[i]           = f2h(w2dsr[i]);
        Ws2[16384 + i]   = f2h(w2dso[i]);
    }
    if (i < H) {
        bias[i]         = b1dd[i] + b1sd[i];
        bias[H + i]     = b1ds[i];
        bias[2*H + i]   = b2dd[i] + b2sd[i];
        bias[3*H + i]   = b2ds[i];
    }
}

// ---------------- histogram (padded counters, stride 16 ints), 3 rels ------
__global__ __launch_bounds__(256) void hist3(
    const int* __restrict__ e1, int E1, int* __restrict__ c1,
    const int* __restrict__ e2, int E2, int* __restrict__ c2,
    const int* __restrict__ e3, int E3, int* __restrict__ c3,
    int g1, int g2)
{
    int b = blockIdx.x;
    const int* ed; int* cnt; int E;
    if (b < g1)           { ed = e1; cnt = c1; E = E1; }
    else if (b < g1 + g2) { ed = e2; cnt = c2; E = E2; b -= g1; }
    else                  { ed = e3; cnt = c3; E = E3; b -= g1 + g2; }
    int e = b * 256 + threadIdx.x;
    if (e < E) atomicAdd(&cnt[ed[e] * 16], 1);
}

// ---------------- scan stage 1: padded counts -> rowptr partials ------------
__global__ __launch_bounds__(256) void scan1_3(
    const int* __restrict__ c1, int n1, int* __restrict__ r1, int* __restrict__ b1,
    const int* __restrict__ c2, int n2, int* __restrict__ r2, int* __restrict__ b2,
    const int* __restrict__ c3, int n3, int* __restrict__ r3, int* __restrict__ b3,
    int g1, int g2)
{
    int blk = blockIdx.x;
    const int* cnt; int n; int* rp; int* bs;
    if (blk < g1)           { cnt = c1; n = n1; rp = r1; bs = b1; }
    else if (blk < g1 + g2) { cnt = c2; n = n2; rp = r2; bs = b2; blk -= g1; }
    else                    { cnt = c3; n = n3; rp = r3; bs = b3; blk -= g1 + g2; }
    __shared__ int sh[256];
    const int t = threadIdx.x;
    const int base = blk * 2048 + t * 8;
    int v[8]; int s = 0;
    #pragma unroll
    for (int j = 0; j < 8; ++j) {
        int i = base + j;
        v[j] = (i < n) ? cnt[i * 16] : 0; s += v[j];
    }
    sh[t] = s; __syncthreads();
    for (int off = 1; off < 256; off <<= 1) {
        int y = (t >= off) ? sh[t - off] : 0;
        __syncthreads();
        sh[t] += y;
        __syncthreads();
    }
    int excl = sh[t] - s;
    #pragma unroll
    for (int j = 0; j < 8; ++j) { int i = base + j; if (i < n) rp[i] = excl; excl += v[j]; }
    if (t == 255) bs[blk] = sh[255];
}

// ---------------- scan stage 2: block sums (<=64 each), 3 rels --------------
__global__ void scan2_3(int* b1, int nb1, int* b2, int nb2, int* b3, int nb3)
{
    int* bs; int nb;
    if (blockIdx.x == 0)      { bs = b1; nb = nb1; }
    else if (blockIdx.x == 1) { bs = b2; nb = nb2; }
    else                      { bs = b3; nb = nb3; }
    int t = threadIdx.x;
    int v = (t < nb) ? bs[t] : 0;
    int x = v;
    for (int off = 1; off < 64; off <<= 1) {
        int y = __shfl_up(x, off);
        if (t >= off) x += y;
    }
    if (t < nb) bs[t] = x - v;
}

// ---------------- scan stage 3: add block offsets, init padded cursors ------
__global__ __launch_bounds__(256) void scan3_3(
    int* __restrict__ r1, int n1, const int* __restrict__ b1, int* __restrict__ c1, int E1,
    int* __restrict__ r2, int n2, const int* __restrict__ b2, int* __restrict__ c2, int E2,
    int* __restrict__ r3, int n3, const int* __restrict__ b3, int* __restrict__ c3, int E3,
    int g1, int g2)
{
    int blk = blockIdx.x;
    int* rp; int n; const int* bs; int* cur; int E;
    if (blk < g1)           { rp = r1; n = n1; bs = b1; cur = c1; E = E1; }
    else if (blk < g1 + g2) { rp = r2; n = n2; bs = b2; cur = c2; E = E2; blk -= g1; }
    else                    { rp = r3; n = n3; bs = b3; cur = c3; E = E3; blk -= g1 + g2; }
    int i = blk * 256 + threadIdx.x;
    if (i < n) {
        int v = rp[i] + bs[i >> 11];
        rp[i] = v;
        cur[i * 16] = v;
    }
    if (i == 0) rp[n] = E;
}

// ---------------- CSR fill (padded cursors), 3 rels -------------------------
__global__ __launch_bounds__(256) void fill3(
    const int* __restrict__ s1, const int* __restrict__ d1, int E1, int* __restrict__ c1, int* __restrict__ o1,
    const int* __restrict__ s2, const int* __restrict__ d2, int E2, int* __restrict__ c2, int* __restrict__ o2,
    const int* __restrict__ s3, const int* __restrict__ d3, int E3, int* __restrict__ c3, int* __restrict__ o3,
    int g1, int g2)
{
    int b = blockIdx.x;
    const int *es, *ed; int *cur, *si; int E;
    if (b < g1)           { es = s1; ed = d1; cur = c1; si = o1; E = E1; }
    else if (b < g1 + g2) { es = s2; ed = d2; cur = c2; si = o2; E = E2; b -= g1; }
    else                  { es = s3; ed = d3; cur = c3; si = o3; E = E3; b -= g1 + g2; }
    int e = b * 256 + threadIdx.x;
    if (e >= E) return;
    int pos = atomicAdd(&cur[ed[e] * 16], 1);
    si[pos] = es[e];
}

// ---------------- CSR aggregate, 3 relations in one launch ------------------
__global__ __launch_bounds__(256) void agg3(
    const ushort* __restrict__ dtab, const ushort* __restrict__ stab,
    const int* __restrict__ rpdd, const int* __restrict__ sidd, ushort* __restrict__ segdd,
    const int* __restrict__ rpsd, const int* __restrict__ sisd, ushort* __restrict__ segsd,
    const int* __restrict__ rpds, const int* __restrict__ sids, ushort* __restrict__ segds,
    int gA)
{
    int b = blockIdx.x;
    const ushort* src; const int* rp; const int* si; ushort* dst; int Ndst;
    if (b < gA)          { src = dtab; rp = rpdd; si = sidd; dst = segdd; Ndst = ND; }
    else if (b < 2 * gA) { src = stab; rp = rpsd; si = sisd; dst = segsd; Ndst = ND; b -= gA; }
    else                 { src = dtab; rp = rpds; si = sids; dst = segds; Ndst = NS; b -= 2 * gA; }
    int d = b * 4 + (threadIdx.x >> 6);
    if (d >= Ndst) return;
    int lane = threadIdx.x & 63;
    int half = lane >> 5;
    int c = lane & 31;
    int p0 = rp[d], p1 = rp[d + 1];
    float a0 = 0.f, a1 = 0.f, a2 = 0.f, a3 = 0.f;
    int p = p0;
    for (; p + 4 <= p1; p += 4) {
        int sA = si[p + half];
        int sB = si[p + 2 + half];
        uint2 vA = *reinterpret_cast<const uint2*>(src + (size_t)sA * H + c * 4);
        uint2 vB = *reinterpret_cast<const uint2*>(src + (size_t)sB * H + c * 4);
        a0 += h2f((ushort)(vA.x & 0xffff)) + h2f((ushort)(vB.x & 0xffff));
        a1 += h2f((ushort)(vA.x >> 16))    + h2f((ushort)(vB.x >> 16));
        a2 += h2f((ushort)(vA.y & 0xffff)) + h2f((ushort)(vB.y & 0xffff));
        a3 += h2f((ushort)(vA.y >> 16))    + h2f((ushort)(vB.y >> 16));
    }
    if (p + 2 <= p1) {
        int sA = si[p + half];
        uint2 vA = *reinterpret_cast<const uint2*>(src + (size_t)sA * H + c * 4);
        a0 += h2f((ushort)(vA.x & 0xffff));
        a1 += h2f((ushort)(vA.x >> 16));
        a2 += h2f((ushort)(vA.y & 0xffff));
        a3 += h2f((ushort)(vA.y >> 16));
        p += 2;
    }
    if (p < p1 && half == 0) {
        int sA = si[p];
        uint2 vA = *reinterpret_cast<const uint2*>(src + (size_t)sA * H + c * 4);
        a0 += h2f((ushort)(vA.x & 0xffff));
        a1 += h2f((ushort)(vA.x >> 16));
        a2 += h2f((ushort)(vA.y & 0xffff));
        a3 += h2f((ushort)(vA.y >> 16));
    }
    a0 += __shfl_xor(a0, 32);
    a1 += __shfl_xor(a1, 32);
    a2 += __shfl_xor(a2, 32);
    a3 += __shfl_xor(a3, 32);
    if (half == 0) {
        uint2 o;
        o.x = (uint)f2h(a0) | ((uint)f2h(a1) << 16);
        o.y = (uint)f2h(a2) | ((uint)f2h(a3) << 16);
        *reinterpret_cast<uint2*>(dst + (size_t)d * H + c * 4) = o;
    }
}

// ---------------- fused GEMM layer: drug + SE in one dispatch, BM=64 --------
// sm copy layout (512 floats per copy, 8 copies):
//   [0:128) drug sum | [128:256) drug sumsq | [256:384) SE sum | [384:512) SE sumsq
template<bool OUTF32>
__global__ __launch_bounds__(256) void gemm_layer(
    const ushort* __restrict__ segdd, const ushort* __restrict__ segsd,
    const ushort* __restrict__ rootd, const ushort* __restrict__ Wd,
    const float* __restrict__ biasd, void* __restrict__ outd,
    const ushort* __restrict__ segds, const ushort* __restrict__ roots,
    const ushort* __restrict__ Ws, const float* __restrict__ biass,
    void* __restrict__ outs, float* __restrict__ sm, int GD)
{
    __shared__ union {
        struct { ushort Al[64][40]; ushort Bl[128][40]; } s;  // 15.4 KB
        float red[2][16][128];                                 // 16 KB
    } u;

    int b = blockIdx.x;
    const ushort *src0, *src1, *src2, *W; const float* bias; void* out;
    int M, nsrc, soff;
    if (b < GD) {
        src0 = segdd; src1 = segsd; src2 = rootd; W = Wd; bias = biasd;
        out = outd; M = ND; nsrc = 3; soff = 0;
    } else {
        b -= GD;
        src0 = segds; src1 = roots; src2 = nullptr; W = Ws; bias = biass;
        out = outs; M = NS; nsrc = 2; soff = 256;   // FIX: was 512 (overflowed copy)
    }

    const int t = threadIdx.x;
    const int wave = t >> 6;
    const int lane = t & 63;
    const int l15 = lane & 15;
    const int kreg = lane >> 4;
    const int block_row = b * 64;

    f32x4 acc[8] = {};

    for (int slot = 0; slot < nsrc; ++slot) {
        const ushort* sb = (slot == 0) ? src0 : (slot == 1) ? src1 : src2;
        #pragma unroll
        for (int kk = 0; kk < 4; ++kk) {
            const int kc = kk * 32;
            __syncthreads();
            // stage A: 64 rows x 32 k fp16, 1 uint4/thread
            {
                int row = t >> 2, part = t & 3;
                int grow = block_row + row;
                uint4 v = make_uint4(0, 0, 0, 0);
                if (grow < M)
                    v = *reinterpret_cast<const uint4*>(sb + (size_t)grow * H + kc + part * 8);
                *reinterpret_cast<uint4*>(&u.s.Al[row][part * 8]) = v;
            }
            // stage B: 128 n x 32 k fp16, 2 uint4/thread (L2-hot weights)
            #pragma unroll
            for (int it = 0; it < 2; ++it) {
                int c = t + it * 256;
                int row = c >> 2, part = c & 3;
                uint4 v = *reinterpret_cast<const uint4*>(W + slot * 16384 + row * 128 + kc + part * 8);
                *reinterpret_cast<uint4*>(&u.s.Bl[row][part * 8]) = v;
            }
            __syncthreads();

            f16x8 a = *reinterpret_cast<const f16x8*>(&u.s.Al[wave * 16 + l15][kreg * 8]);
            #pragma unroll
            for (int n = 0; n < 8; ++n) {
                f16x8 bb = *reinterpret_cast<const f16x8*>(&u.s.Bl[n * 16 + l15][kreg * 8]);
                acc[n] = __builtin_amdgcn_mfma_f32_16x16x32_f16(a, bb, acc[n], 0, 0, 0);
            }
        }
    }

    // epilogue: bias + leaky-relu + store (+ BN partials for layer 2)
    float psum[8], psq[8];
    const int rb = block_row + wave * 16 + kreg * 4;
    #pragma unroll
    for (int n = 0; n < 8; ++n) {
        int col = n * 16 + l15;
        float bv = bias[col];
        float s = 0.f, q = 0.f;
        #pragma unroll
        for (int r = 0; r < 4; ++r) {
            int row = rb + r;
            if (row < M) {
                float v = acc[n][r] + bv;
                v = (v > 0.f) ? v : 0.01f * v;
                if (OUTF32) ((float*)out)[(size_t)row * H + col] = v;
                else        ((ushort*)out)[(size_t)row * H + col] = f2h(v);
                s += v; q += v * v;
            }
        }
        psum[n] = s; psq[n] = q;
    }

    if (OUTF32) {
        __syncthreads();   // Al/Bl reads done; reuse LDS as red[][][]
        const int w4k = wave * 4 + kreg;
        #pragma unroll
        for (int n = 0; n < 8; ++n) {
            int col = n * 16 + l15;
            u.red[0][w4k][col] = psum[n];
            u.red[1][w4k][col] = psq[n];
        }
        __syncthreads();
        if (t < 128) {
            float a = 0.f, q = 0.f;
            #pragma unroll
            for (int k = 0; k < 16; ++k) { a += u.red[0][k][t]; q += u.red[1][k][t]; }
            // 8-way spread copies to cut same-address contention
            float* dstp = sm + (blockIdx.x & 7) * 512 + soff;
            atomicAdd(&dstp[t], a);
            atomicAdd(&dstp[H + t], q);
        }
    }
}

// ---------------- fold 8 stats copies -> stats ------------------------------
__global__ void bn_fold(const float* __restrict__ sm, float* __restrict__ stats)
{
    int t = blockIdx.x * 256 + threadIdx.x;   // 0..511
    float s = 0.f;
    #pragma unroll
    for (int k = 0; k < 8; ++k) s += sm[k * 512 + t];
    stats[t] = s;
}

// ---------------- batchnorm apply: both tables in one launch ----------------
__global__ __launch_bounds__(256) void bn_apply_all(
    float* __restrict__ d2, float* __restrict__ s2,
    const float* __restrict__ stats,
    const float* __restrict__ gamma, const float* __restrict__ beta)
{
    size_t i = (size_t)blockIdx.x * 256 + threadIdx.x;
    const size_t totD = (size_t)ND * (H / 4);
    const size_t totAll = totD + (size_t)NS * (H / 4);
    if (i >= totAll) return;
    float* x;
    const float* st;
    float inv_m;
    size_t j;
    if (i < totD) { x = d2; st = stats;       inv_m = 1.0f / ND; j = i; }
    else          { x = s2; st = stats + 256; inv_m = 1.0f / NS; j = i - totD; }
    int c4 = (int)(j & (H / 4 - 1)) * 4;
    float4 v = reinterpret_cast<float4*>(x)[j];
    float* vp = &v.x;
    #pragma unroll
    for (int k = 0; k < 4; ++k) {
        int c = c4 + k;
        float mean = st[c] * inv_m;
        float var = st[H + c] * inv_m - mean * mean;
        float sc = gamma[c] * rsqrtf(fmaxf(var, 0.f) + 1e-5f);
        vp[k] = (vp[k] - mean) * sc + beta[c];
    }
    reinterpret_cast<float4*>(x)[j] = v;
}

// ---------------- launch ----------------------------------------------------
extern "C" void kernel_launch(void* const* d_in, const int* in_sizes, int n_in,
                              void* d_out, int out_size, void* d_ws, size_t ws_size,
                              hipStream_t stream)
{
    (void)n_in; (void)out_size; (void)ws_size;
    const float* x_drug = (const float*)d_in[0];
    const float* x_se   = (const float*)d_in[1];
    const int* ei_dd = (const int*)d_in[2];
    const int* ei_ds = (const int*)d_in[3];
    const int* ei_sd = (const int*)d_in[4];
    const int EDD = in_sizes[2] / 2;
    const int EDS = in_sizes[3] / 2;
    const int ESD = in_sizes[4] / 2;

    const float* w1_dd_rel  = (const float*)d_in[5];
    const float* b1_dd      = (const float*)d_in[6];
    const float* w1_dd_root = (const float*)d_in[7];
    const float* w1_ds_rel  = (const float*)d_in[8];
    const float* b1_ds      = (const float*)d_in[9];
    const float* w1_ds_root = (const float*)d_in[10];
    const float* w1_sd_rel  = (const float*)d_in[11];
    const float* b1_sd      = (const float*)d_in[12];
    const float* w1_sd_root = (const float*)d_in[13];
    const float* w2_dd_rel  = (const float*)d_in[14];
    const float* b2_dd      = (const float*)d_in[15];
    const float* w2_dd_root = (const float*)d_in[16];
    const float* w2_ds_rel  = (const float*)d_in[17];
    const float* b2_ds      = (const float*)d_in[18];
    const float* w2_ds_root = (const float*)d_in[19];
    const float* w2_sd_rel  = (const float*)d_in[20];
    const float* b2_sd      = (const float*)d_in[21];
    const float* w2_sd_root = (const float*)d_in[22];
    const float* gamma      = (const float*)d_in[23];
    const float* beta       = (const float*)d_in[24];

    // ---------------- workspace layout ----------------
    ushort* xd_h  = (ushort*)d_ws;                     // ND*H fp16 (becomes d1h in place)
    ushort* xs_h  = xd_h + (size_t)ND * H;             // NS*H fp16 (becomes s1h)
    ushort* segdd = xs_h + (size_t)NS * H;             // ND*H
    ushort* segsd = segdd + (size_t)ND * H;            // ND*H
    ushort* segds = segsd + (size_t)ND * H;            // NS*H
    ushort* Wd1 = segds + (size_t)NS * H;              // 3*16384
    ushort* Ws1 = Wd1 + 3 * 16384;                     // 2*16384
    ushort* Wd2 = Ws1 + 2 * 16384;                     // 3*16384
    ushort* Ws2 = Wd2 + 3 * 16384;                     // 2*16384
    float* bias  = (float*)(Ws2 + 2 * 16384);          // 512
    float* stats = bias + 512;                         // 512
    float* sm    = stats + 512;                        // 8*512 spread stats (memset start)
    int* cur_dd  = (int*)(sm + 8 * 512);               // ND*16 (padded hist+cursor)
    int* cur_sd  = cur_dd + (size_t)ND * 16;           // ND*16
    int* cur_ds  = cur_sd + (size_t)ND * 16;           // NS*16 (memset end)
    int* rp_dd = cur_ds + (size_t)NS * 16;             // ND+1
    int* rp_sd = rp_dd + (ND + 1);                     // ND+1
    int* rp_ds = rp_sd + (ND + 1);                     // NS+1
    int* si_dd = rp_ds + (NS + 1);                     // EDD
    int* si_sd = si_dd + EDD;                          // ESD
    int* si_ds = si_sd + ESD;                          // EDS
    int* bs_dd = si_ds + EDS;                          // 64
    int* bs_sd = bs_dd + 64;                           // 64
    int* bs_ds = bs_sd + 64;                           // 64

    ushort* d1h = xd_h;
    ushort* s1h = xs_h;

    float* d2 = (float*)d_out;                // ND*H
    float* s2 = d2 + (size_t)ND * H;          // NS*H

    // zero sm + padded hist/cursor arrays (contiguous region)
    hipMemsetAsync(sm, 0,
        ((size_t)8 * 512 + (size_t)(2 * ND + NS) * 16) * sizeof(int), stream);

    prep_weights<<<64, 256, 0, stream>>>(
        w1_dd_rel, w1_dd_root, w1_sd_rel, w1_sd_root, w1_ds_rel, w1_ds_root,
        w2_dd_rel, w2_dd_root, w2_sd_rel, w2_sd_root, w2_ds_rel, w2_ds_root,
        b1_dd, b1_sd, b1_ds, b2_dd, b2_sd, b2_ds,
        Wd1, Ws1, Wd2, Ws2, bias);

    f2h_all<<<((ND + NS) * H / 4 + 255) / 256, 256, 0, stream>>>(x_drug, x_se, xd_h, xs_h);

    // ---- CSR build (merged 3-relation dispatches) ----
    const int gDD = (EDD + 255) / 256, gSD = (ESD + 255) / 256, gDS = (EDS + 255) / 256;
    hist3<<<gDD + gSD + gDS, 256, 0, stream>>>(
        ei_dd + EDD, EDD, cur_dd,
        ei_sd + ESD, ESD, cur_sd,
        ei_ds + EDS, EDS, cur_ds, gDD, gSD);

    const int nbDD = (ND + 2047) / 2048, nbDS = (NS + 2047) / 2048;
    scan1_3<<<2 * nbDD + nbDS, 256, 0, stream>>>(
        cur_dd, ND, rp_dd, bs_dd,
        cur_sd, ND, rp_sd, bs_sd,
        cur_ds, NS, rp_ds, bs_ds, nbDD, nbDD);
    scan2_3<<<3, 64, 0, stream>>>(bs_dd, nbDD, bs_sd, nbDD, bs_ds, nbDS);
    const int g3D = (ND + 255) / 256, g3S = (NS + 255) / 256;
    scan3_3<<<2 * g3D + g3S, 256, 0, stream>>>(
        rp_dd, ND, bs_dd, cur_dd, EDD,
        rp_sd, ND, bs_sd, cur_sd, ESD,
        rp_ds, NS, bs_ds, cur_ds, EDS, g3D, g3D);

    fill3<<<gDD + gSD + gDS, 256, 0, stream>>>(
        ei_dd, ei_dd + EDD, EDD, cur_dd, si_dd,
        ei_sd, ei_sd + ESD, ESD, cur_sd, si_sd,
        ei_ds, ei_ds + EDS, EDS, cur_ds, si_ds, gDD, gSD);

    const int gA = (ND + 3) / 4, gB = (NS + 3) / 4;
    const int GD = (ND + 63) / 64, GS = (NS + 63) / 64;

    // ---- layer 1 ----
    agg3<<<2 * gA + gB, 256, 0, stream>>>(
        xd_h, xs_h,
        rp_dd, si_dd, segdd,
        rp_sd, si_sd, segsd,
        rp_ds, si_ds, segds, gA);
    gemm_layer<false><<<GD + GS, 256, 0, stream>>>(
        segdd, segsd, xd_h, Wd1, bias, d1h,
        segds, xs_h, Ws1, bias + H, s1h, sm, GD);

    // ---- layer 2 ----
    agg3<<<2 * gA + gB, 256, 0, stream>>>(
        d1h, s1h,
        rp_dd, si_dd, segdd,
        rp_sd, si_sd, segsd,
        rp_ds, si_ds, segds, gA);
    gemm_layer<true><<<GD + GS, 256, 0, stream>>>(
        segdd, segsd, d1h, Wd2, bias + 2 * H, d2,
        segds, s1h, Ws2, bias + 3 * H, s2, sm, GD);

    // ---- batchnorm: fold spread stats, then apply ----
    bn_fold<<<2, 256, 0, stream>>>(sm, stats);
    bn_apply_all<<<((ND + NS) * (H / 4) + 255) / 256, 256, 0, stream>>>(d2, s2, stats, gamma, beta);
}

// Round 8
// 526.493 us; speedup vs baseline: 12.0502x; 1.1563x over previous
//
#include <hip/hip_runtime.h>
#include <hip/hip_bf16.h>

#define H 128
#define ND 100000
#define NS 10000

typedef __attribute__((ext_vector_type(8))) _Float16 f16x8;
typedef __attribute__((ext_vector_type(4))) float f32x4;

__device__ inline ushort f2h(float f) {
    union { _Float16 h; ushort u; } c; c.h = (_Float16)f; return c.u;
}
__device__ inline float h2f(ushort u) {
    union { ushort u; _Float16 h; } c; c.u = u; return (float)c.h;
}

// ---------------- fp32 -> fp16 convert, both tables, one launch -------------
__global__ __launch_bounds__(256) void f2h_all(
    const float* __restrict__ xd, const float* __restrict__ xs,
    ushort* __restrict__ od, ushort* __restrict__ os)
{
    int i = blockIdx.x * 256 + threadIdx.x;
    const int nD = ND * H / 4;
    const int nT = (ND + NS) * H / 4;
    if (i >= nT) return;
    const float* in; ushort* out; int j;
    if (i < nD) { in = xd; out = od; j = i; }
    else        { in = xs; out = os; j = i - nD; }
    float4 v = reinterpret_cast<const float4*>(in)[j];
    ushort4 o;
    o.x = f2h(v.x); o.y = f2h(v.y); o.z = f2h(v.z); o.w = f2h(v.w);
    reinterpret_cast<ushort4*>(out)[j] = o;
}

// ---------------- weight prep: fp32 -> fp16, fold root weights & biases ----
__global__ void prep_weights(
    const float* w1ddr, const float* w1ddo, const float* w1sdr, const float* w1sdo,
    const float* w1dsr, const float* w1dso,
    const float* w2ddr, const float* w2ddo, const float* w2sdr, const float* w2sdo,
    const float* w2dsr, const float* w2dso,
    const float* b1dd, const float* b1sd, const float* b1ds,
    const float* b2dd, const float* b2sd, const float* b2ds,
    ushort* Wd1, ushort* Ws1, ushort* Wd2, ushort* Ws2, float* bias)
{
    int i = blockIdx.x * blockDim.x + threadIdx.x;
    if (i < 16384) {
        Wd1[i]           = f2h(w1ddr[i]);
        Wd1[16384 + i]   = f2h(w1sdr[i]);
        Wd1[32768 + i]   = f2h(w1ddo[i] + w1sdo[i]);
        Ws1[i]           = f2h(w1dsr[i]);
        Ws1[16384 + i]   = f2h(w1dso[i]);
        Wd2[i]           = f2h(w2ddr[i]);
        Wd2[16384 + i]   = f2h(w2sdr[i]);
        Wd2[32768 + i]   = f2h(w2ddo[i] + w2sdo[i]);
        Ws2[i]           = f2h(w2dsr[i]);
        Ws2[16384 + i]   = f2h(w2dso[i]);
    }
    if (i < H) {
        bias[i]         = b1dd[i] + b1sd[i];
        bias[H + i]     = b1ds[i];
        bias[2*H + i]   = b2dd[i] + b2sd[i];
        bias[3*H + i]   = b2ds[i];
    }
}

// ---------------- histogram, 3 rels -----------------------------------------
__global__ __launch_bounds__(256) void hist3(
    const int* __restrict__ e1, int E1, int* __restrict__ c1,
    const int* __restrict__ e2, int E2, int* __restrict__ c2,
    const int* __restrict__ e3, int E3, int* __restrict__ c3,
    int g1, int g2)
{
    int b = blockIdx.x;
    const int* ed; int* cnt; int E;
    if (b < g1)           { ed = e1; cnt = c1; E = E1; }
    else if (b < g1 + g2) { ed = e2; cnt = c2; E = E2; b -= g1; }
    else                  { ed = e3; cnt = c3; E = E3; b -= g1 + g2; }
    int e = b * 256 + threadIdx.x;
    if (e < E) atomicAdd(&cnt[ed[e]], 1);
}

// ---------------- scan stage 1 ----------------------------------------------
__global__ __launch_bounds__(256) void scan1_3(
    const int* __restrict__ c1, int n1, int* __restrict__ r1, int* __restrict__ b1,
    const int* __restrict__ c2, int n2, int* __restrict__ r2, int* __restrict__ b2,
    const int* __restrict__ c3, int n3, int* __restrict__ r3, int* __restrict__ b3,
    int g1, int g2)
{
    int blk = blockIdx.x;
    const int* cnt; int n; int* rp; int* bs;
    if (blk < g1)           { cnt = c1; n = n1; rp = r1; bs = b1; }
    else if (blk < g1 + g2) { cnt = c2; n = n2; rp = r2; bs = b2; blk -= g1; }
    else                    { cnt = c3; n = n3; rp = r3; bs = b3; blk -= g1 + g2; }
    __shared__ int sh[256];
    const int t = threadIdx.x;
    const int base = blk * 2048 + t * 8;
    int v[8]; int s = 0;
    #pragma unroll
    for (int j = 0; j < 8; ++j) { int i = base + j; v[j] = (i < n) ? cnt[i] : 0; s += v[j]; }
    sh[t] = s; __syncthreads();
    for (int off = 1; off < 256; off <<= 1) {
        int y = (t >= off) ? sh[t - off] : 0;
        __syncthreads();
        sh[t] += y;
        __syncthreads();
    }
    int excl = sh[t] - s;
    #pragma unroll
    for (int j = 0; j < 8; ++j) { int i = base + j; if (i < n) rp[i] = excl; excl += v[j]; }
    if (t == 255) bs[blk] = sh[255];
}

// ---------------- scan stage 2 ----------------------------------------------
__global__ void scan2_3(int* b1, int nb1, int* b2, int nb2, int* b3, int nb3)
{
    int* bs; int nb;
    if (blockIdx.x == 0)      { bs = b1; nb = nb1; }
    else if (blockIdx.x == 1) { bs = b2; nb = nb2; }
    else                      { bs = b3; nb = nb3; }
    int t = threadIdx.x;
    int v = (t < nb) ? bs[t] : 0;
    int x = v;
    for (int off = 1; off < 64; off <<= 1) {
        int y = __shfl_up(x, off);
        if (t >= off) x += y;
    }
    if (t < nb) bs[t] = x - v;
}

// ---------------- scan stage 3: add offsets, init cursors -------------------
__global__ __launch_bounds__(256) void scan3_3(
    int* __restrict__ r1, int n1, const int* __restrict__ b1, int* __restrict__ c1, int E1,
    int* __restrict__ r2, int n2, const int* __restrict__ b2, int* __restrict__ c2, int E2,
    int* __restrict__ r3, int n3, const int* __restrict__ b3, int* __restrict__ c3, int E3,
    int g1, int g2)
{
    int blk = blockIdx.x;
    int* rp; int n; const int* bs; int* cur; int E;
    if (blk < g1)           { rp = r1; n = n1; bs = b1; cur = c1; E = E1; }
    else if (blk < g1 + g2) { rp = r2; n = n2; bs = b2; cur = c2; E = E2; blk -= g1; }
    else                    { rp = r3; n = n3; bs = b3; cur = c3; E = E3; blk -= g1 + g2; }
    int i = blk * 256 + threadIdx.x;
    if (i < n) {
        int v = rp[i] + bs[i >> 11];
        rp[i] = v;
        cur[i] = v;
    }
    if (i == 0) rp[n] = E;
}

// ---------------- CSR fill, 3 rels, 8 dest-range passes ---------------------
// Pass p only processes edges whose dst falls in [p*n/8,(p+1)*n/8): si writes
// are confined to a contiguous ~E/8 window -> partial lines merge in cache.
__global__ __launch_bounds__(256) void fill3(
    const int* __restrict__ s1, const int* __restrict__ d1, int E1, int n1, int* __restrict__ c1, int* __restrict__ o1,
    const int* __restrict__ s2, const int* __restrict__ d2, int E2, int n2, int* __restrict__ c2, int* __restrict__ o2,
    const int* __restrict__ s3, const int* __restrict__ d3, int E3, int n3, int* __restrict__ c3, int* __restrict__ o3,
    int g1, int g2)
{
    int b = blockIdx.x;
    const int *es, *ed; int *cur, *si; int E, n;
    if (b < g1)           { es = s1; ed = d1; cur = c1; si = o1; E = E1; n = n1; }
    else if (b < g1 + g2) { es = s2; ed = d2; cur = c2; si = o2; E = E2; n = n2; b -= g1; }
    else                  { es = s3; ed = d3; cur = c3; si = o3; E = E3; n = n3; b -= g1 + g2; }
    int e = b * 256 + threadIdx.x;
    if (e >= E) return;
    int dst = ed[e];
    int src = es[e];
    const int step = n >> 3;   // n divisible by 8 (100000/8, 10000/8)
    #pragma unroll 1
    for (int pass = 0; pass < 8; ++pass) {
        int lo = pass * step;
        if (dst >= lo && dst < lo + step) {
            int pos = atomicAdd(&cur[dst], 1);
            si[pos] = src;
        }
    }
}

// ---------------- CSR aggregate: half-wave per dest, 4-deep unroll ----------
__global__ __launch_bounds__(256) void agg3(
    const ushort* __restrict__ dtab, const ushort* __restrict__ stab,
    const int* __restrict__ rpdd, const int* __restrict__ sidd, ushort* __restrict__ segdd,
    const int* __restrict__ rpsd, const int* __restrict__ sisd, ushort* __restrict__ segsd,
    const int* __restrict__ rpds, const int* __restrict__ sids, ushort* __restrict__ segds,
    int gA)
{
    int b = blockIdx.x;
    const ushort* src; const int* rp; const int* si; ushort* dst; int Ndst;
    if (b < gA)          { src = dtab; rp = rpdd; si = sidd; dst = segdd; Ndst = ND; }
    else if (b < 2 * gA) { src = stab; rp = rpsd; si = sisd; dst = segsd; Ndst = ND; b -= gA; }
    else                 { src = dtab; rp = rpds; si = sids; dst = segds; Ndst = NS; b -= 2 * gA; }
    int d = b * 8 + (threadIdx.x >> 5);   // 8 half-waves per block
    if (d >= Ndst) return;
    int c = threadIdx.x & 31;             // 8B per lane covers the 256B row
    int p0 = rp[d], p1 = rp[d + 1];
    float a0 = 0.f, a1 = 0.f, a2 = 0.f, a3 = 0.f;
    int p = p0;
    for (; p + 4 <= p1; p += 4) {
        int s0 = si[p], s1 = si[p + 1], s2 = si[p + 2], s3 = si[p + 3];
        uint2 v0 = *reinterpret_cast<const uint2*>(src + (size_t)s0 * H + c * 4);
        uint2 v1 = *reinterpret_cast<const uint2*>(src + (size_t)s1 * H + c * 4);
        uint2 v2 = *reinterpret_cast<const uint2*>(src + (size_t)s2 * H + c * 4);
        uint2 v3 = *reinterpret_cast<const uint2*>(src + (size_t)s3 * H + c * 4);
        a0 += h2f((ushort)(v0.x & 0xffff)) + h2f((ushort)(v1.x & 0xffff))
            + h2f((ushort)(v2.x & 0xffff)) + h2f((ushort)(v3.x & 0xffff));
        a1 += h2f((ushort)(v0.x >> 16))    + h2f((ushort)(v1.x >> 16))
            + h2f((ushort)(v2.x >> 16))    + h2f((ushort)(v3.x >> 16));
        a2 += h2f((ushort)(v0.y & 0xffff)) + h2f((ushort)(v1.y & 0xffff))
            + h2f((ushort)(v2.y & 0xffff)) + h2f((ushort)(v3.y & 0xffff));
        a3 += h2f((ushort)(v0.y >> 16))    + h2f((ushort)(v1.y >> 16))
            + h2f((ushort)(v2.y >> 16))    + h2f((ushort)(v3.y >> 16));
    }
    for (; p < p1; ++p) {
        int s0 = si[p];
        uint2 v0 = *reinterpret_cast<const uint2*>(src + (size_t)s0 * H + c * 4);
        a0 += h2f((ushort)(v0.x & 0xffff));
        a1 += h2f((ushort)(v0.x >> 16));
        a2 += h2f((ushort)(v0.y & 0xffff));
        a3 += h2f((ushort)(v0.y >> 16));
    }
    uint2 o;
    o.x = (uint)f2h(a0) | ((uint)f2h(a1) << 16);
    o.y = (uint)f2h(a2) | ((uint)f2h(a3) << 16);
    *reinterpret_cast<uint2*>(dst + (size_t)d * H + c * 4) = o;
}

// ---------------- fused GEMM layer: drug + SE in one dispatch, BM=64 --------
// sm copy layout (512 floats per copy, 8 copies):
//   [0:128) drug sum | [128:256) drug sumsq | [256:384) SE sum | [384:512) SE sumsq
template<bool OUTF32>
__global__ __launch_bounds__(256) void gemm_layer(
    const ushort* __restrict__ segdd, const ushort* __restrict__ segsd,
    const ushort* __restrict__ rootd, const ushort* __restrict__ Wd,
    const float* __restrict__ biasd, void* __restrict__ outd,
    const ushort* __restrict__ segds, const ushort* __restrict__ roots,
    const ushort* __restrict__ Ws, const float* __restrict__ biass,
    void* __restrict__ outs, float* __restrict__ sm, int GD)
{
    __shared__ union {
        struct { ushort Al[64][40]; ushort Bl[128][40]; } s;  // 15.4 KB
        float red[2][16][128];                                 // 16 KB
    } u;

    int b = blockIdx.x;
    const ushort *src0, *src1, *src2, *W; const float* bias; void* out;
    int M, nsrc, soff;
    if (b < GD) {
        src0 = segdd; src1 = segsd; src2 = rootd; W = Wd; bias = biasd;
        out = outd; M = ND; nsrc = 3; soff = 0;
    } else {
        b -= GD;
        src0 = segds; src1 = roots; src2 = nullptr; W = Ws; bias = biass;
        out = outs; M = NS; nsrc = 2; soff = 256;
    }

    const int t = threadIdx.x;
    const int wave = t >> 6;
    const int lane = t & 63;
    const int l15 = lane & 15;
    const int kreg = lane >> 4;
    const int block_row = b * 64;

    f32x4 acc[8] = {};

    for (int slot = 0; slot < nsrc; ++slot) {
        const ushort* sb = (slot == 0) ? src0 : (slot == 1) ? src1 : src2;
        #pragma unroll
        for (int kk = 0; kk < 4; ++kk) {
            const int kc = kk * 32;
            __syncthreads();
            {
                int row = t >> 2, part = t & 3;
                int grow = block_row + row;
                uint4 v = make_uint4(0, 0, 0, 0);
                if (grow < M)
                    v = *reinterpret_cast<const uint4*>(sb + (size_t)grow * H + kc + part * 8);
                *reinterpret_cast<uint4*>(&u.s.Al[row][part * 8]) = v;
            }
            #pragma unroll
            for (int it = 0; it < 2; ++it) {
                int c = t + it * 256;
                int row = c >> 2, part = c & 3;
                uint4 v = *reinterpret_cast<const uint4*>(W + slot * 16384 + row * 128 + kc + part * 8);
                *reinterpret_cast<uint4*>(&u.s.Bl[row][part * 8]) = v;
            }
            __syncthreads();

            f16x8 a = *reinterpret_cast<const f16x8*>(&u.s.Al[wave * 16 + l15][kreg * 8]);
            #pragma unroll
            for (int n = 0; n < 8; ++n) {
                f16x8 bb = *reinterpret_cast<const f16x8*>(&u.s.Bl[n * 16 + l15][kreg * 8]);
                acc[n] = __builtin_amdgcn_mfma_f32_16x16x32_f16(a, bb, acc[n], 0, 0, 0);
            }
        }
    }

    float psum[8], psq[8];
    const int rb = block_row + wave * 16 + kreg * 4;
    #pragma unroll
    for (int n = 0; n < 8; ++n) {
        int col = n * 16 + l15;
        float bv = bias[col];
        float s = 0.f, q = 0.f;
        #pragma unroll
        for (int r = 0; r < 4; ++r) {
            int row = rb + r;
            if (row < M) {
                float v = acc[n][r] + bv;
                v = (v > 0.f) ? v : 0.01f * v;
                if (OUTF32) ((float*)out)[(size_t)row * H + col] = v;
                else        ((ushort*)out)[(size_t)row * H + col] = f2h(v);
                s += v; q += v * v;
            }
        }
        psum[n] = s; psq[n] = q;
    }

    if (OUTF32) {
        __syncthreads();
        const int w4k = wave * 4 + kreg;
        #pragma unroll
        for (int n = 0; n < 8; ++n) {
            int col = n * 16 + l15;
            u.red[0][w4k][col] = psum[n];
            u.red[1][w4k][col] = psq[n];
        }
        __syncthreads();
        if (t < 128) {
            float a = 0.f, q = 0.f;
            #pragma unroll
            for (int k = 0; k < 16; ++k) { a += u.red[0][k][t]; q += u.red[1][k][t]; }
            float* dstp = sm + (blockIdx.x & 7) * 512 + soff;
            atomicAdd(&dstp[t], a);
            atomicAdd(&dstp[H + t], q);
        }
    }
}

// ---------------- fold 8 stats copies -> stats ------------------------------
__global__ void bn_fold(const float* __restrict__ sm, float* __restrict__ stats)
{
    int t = blockIdx.x * 256 + threadIdx.x;   // 0..511
    float s = 0.f;
    #pragma unroll
    for (int k = 0; k < 8; ++k) s += sm[k * 512 + t];
    stats[t] = s;
}

// ---------------- batchnorm apply: both tables in one launch ----------------
__global__ __launch_bounds__(256) void bn_apply_all(
    float* __restrict__ d2, float* __restrict__ s2,
    const float* __restrict__ stats,
    const float* __restrict__ gamma, const float* __restrict__ beta)
{
    size_t i = (size_t)blockIdx.x * 256 + threadIdx.x;
    const size_t totD = (size_t)ND * (H / 4);
    const size_t totAll = totD + (size_t)NS * (H / 4);
    if (i >= totAll) return;
    float* x;
    const float* st;
    float inv_m;
    size_t j;
    if (i < totD) { x = d2; st = stats;       inv_m = 1.0f / ND; j = i; }
    else          { x = s2; st = stats + 256; inv_m = 1.0f / NS; j = i - totD; }
    int c4 = (int)(j & (H / 4 - 1)) * 4;
    float4 v = reinterpret_cast<float4*>(x)[j];
    float* vp = &v.x;
    #pragma unroll
    for (int k = 0; k < 4; ++k) {
        int c = c4 + k;
        float mean = st[c] * inv_m;
        float var = st[H + c] * inv_m - mean * mean;
        float sc = gamma[c] * rsqrtf(fmaxf(var, 0.f) + 1e-5f);
        vp[k] = (vp[k] - mean) * sc + beta[c];
    }
    reinterpret_cast<float4*>(x)[j] = v;
}

// ---------------- launch ----------------------------------------------------
extern "C" void kernel_launch(void* const* d_in, const int* in_sizes, int n_in,
                              void* d_out, int out_size, void* d_ws, size_t ws_size,
                              hipStream_t stream)
{
    (void)n_in; (void)out_size; (void)ws_size;
    const float* x_drug = (const float*)d_in[0];
    const float* x_se   = (const float*)d_in[1];
    const int* ei_dd = (const int*)d_in[2];
    const int* ei_ds = (const int*)d_in[3];
    const int* ei_sd = (const int*)d_in[4];
    const int EDD = in_sizes[2] / 2;
    const int EDS = in_sizes[3] / 2;
    const int ESD = in_sizes[4] / 2;

    const float* w1_dd_rel  = (const float*)d_in[5];
    const float* b1_dd      = (const float*)d_in[6];
    const float* w1_dd_root = (const float*)d_in[7];
    const float* w1_ds_rel  = (const float*)d_in[8];
    const float* b1_ds      = (const float*)d_in[9];
    const float* w1_ds_root = (const float*)d_in[10];
    const float* w1_sd_rel  = (const float*)d_in[11];
    const float* b1_sd      = (const float*)d_in[12];
    const float* w1_sd_root = (const float*)d_in[13];
    const float* w2_dd_rel  = (const float*)d_in[14];
    const float* b2_dd      = (const float*)d_in[15];
    const float* w2_dd_root = (const float*)d_in[16];
    const float* w2_ds_rel  = (const float*)d_in[17];
    const float* b2_ds      = (const float*)d_in[18];
    const float* w2_ds_root = (const float*)d_in[19];
    const float* w2_sd_rel  = (const float*)d_in[20];
    const float* b2_sd      = (const float*)d_in[21];
    const float* w2_sd_root = (const float*)d_in[22];
    const float* gamma      = (const float*)d_in[23];
    const float* beta       = (const float*)d_in[24];

    // ---------------- workspace layout ----------------
    ushort* xd_h  = (ushort*)d_ws;                     // ND*H fp16 (becomes d1h in place)
    ushort* xs_h  = xd_h + (size_t)ND * H;             // NS*H fp16 (becomes s1h)
    ushort* segdd = xs_h + (size_t)NS * H;             // ND*H
    ushort* segsd = segdd + (size_t)ND * H;            // ND*H
    ushort* segds = segsd + (size_t)ND * H;            // NS*H
    ushort* Wd1 = segds + (size_t)NS * H;              // 3*16384
    ushort* Ws1 = Wd1 + 3 * 16384;                     // 2*16384
    ushort* Wd2 = Ws1 + 2 * 16384;                     // 3*16384
    ushort* Ws2 = Wd2 + 3 * 16384;                     // 2*16384
    float* bias  = (float*)(Ws2 + 2 * 16384);          // 512
    float* stats = bias + 512;                         // 512
    float* sm    = stats + 512;                        // 8*512 spread stats (memset start)
    int* cur_dd  = (int*)(sm + 8 * 512);               // ND (hist+cursor)
    int* cur_sd  = cur_dd + ND;                        // ND
    int* cur_ds  = cur_sd + ND;                        // NS (memset end)
    int* rp_dd = cur_ds + NS;                          // ND+1
    int* rp_sd = rp_dd + (ND + 1);                     // ND+1
    int* rp_ds = rp_sd + (ND + 1);                     // NS+1
    int* si_dd = rp_ds + (NS + 1);                     // EDD
    int* si_sd = si_dd + EDD;                          // ESD
    int* si_ds = si_sd + ESD;                          // EDS
    int* bs_dd = si_ds + EDS;                          // 64
    int* bs_sd = bs_dd + 64;                           // 64
    int* bs_ds = bs_sd + 64;                           // 64

    ushort* d1h = xd_h;
    ushort* s1h = xs_h;

    float* d2 = (float*)d_out;                // ND*H
    float* s2 = d2 + (size_t)ND * H;          // NS*H

    // zero sm + hist/cursor arrays (contiguous region)
    hipMemsetAsync(sm, 0, ((size_t)8 * 512 + (size_t)(2 * ND + NS)) * sizeof(int), stream);

    prep_weights<<<64, 256, 0, stream>>>(
        w1_dd_rel, w1_dd_root, w1_sd_rel, w1_sd_root, w1_ds_rel, w1_ds_root,
        w2_dd_rel, w2_dd_root, w2_sd_rel, w2_sd_root, w2_ds_rel, w2_ds_root,
        b1_dd, b1_sd, b1_ds, b2_dd, b2_sd, b2_ds,
        Wd1, Ws1, Wd2, Ws2, bias);

    f2h_all<<<((ND + NS) * H / 4 + 255) / 256, 256, 0, stream>>>(x_drug, x_se, xd_h, xs_h);

    // ---- CSR build (merged 3-relation dispatches) ----
    const int gDD = (EDD + 255) / 256, gSD = (ESD + 255) / 256, gDS = (EDS + 255) / 256;
    hist3<<<gDD + gSD + gDS, 256, 0, stream>>>(
        ei_dd + EDD, EDD, cur_dd,
        ei_sd + ESD, ESD, cur_sd,
        ei_ds + EDS, EDS, cur_ds, gDD, gSD);

    const int nbDD = (ND + 2047) / 2048, nbDS = (NS + 2047) / 2048;
    scan1_3<<<2 * nbDD + nbDS, 256, 0, stream>>>(
        cur_dd, ND, rp_dd, bs_dd,
        cur_sd, ND, rp_sd, bs_sd,
        cur_ds, NS, rp_ds, bs_ds, nbDD, nbDD);
    scan2_3<<<3, 64, 0, stream>>>(bs_dd, nbDD, bs_sd, nbDD, bs_ds, nbDS);
    const int g3D = (ND + 255) / 256, g3S = (NS + 255) / 256;
    scan3_3<<<2 * g3D + g3S, 256, 0, stream>>>(
        rp_dd, ND, bs_dd, cur_dd, EDD,
        rp_sd, ND, bs_sd, cur_sd, ESD,
        rp_ds, NS, bs_ds, cur_ds, EDS, g3D, g3D);

    fill3<<<gDD + gSD + gDS, 256, 0, stream>>>(
        ei_dd, ei_dd + EDD, EDD, ND, cur_dd, si_dd,
        ei_sd, ei_sd + ESD, ESD, ND, cur_sd, si_sd,
        ei_ds, ei_ds + EDS, EDS, NS, cur_ds, si_ds, gDD, gSD);

    const int gA = (ND + 7) / 8, gB = (NS + 7) / 8;
    const int GD = (ND + 63) / 64, GS = (NS + 63) / 64;

    // ---- layer 1 ----
    agg3<<<2 * gA + gB, 256, 0, stream>>>(
        xd_h, xs_h,
        rp_dd, si_dd, segdd,
        rp_sd, si_sd, segsd,
        rp_ds, si_ds, segds, gA);
    gemm_layer<false><<<GD + GS, 256, 0, stream>>>(
        segdd, segsd, xd_h, Wd1, bias, d1h,
        segds, xs_h, Ws1, bias + H, s1h, sm, GD);

    // ---- layer 2 ----
    agg3<<<2 * gA + gB, 256, 0, stream>>>(
        d1h, s1h,
        rp_dd, si_dd, segdd,
        rp_sd, si_sd, segsd,
        rp_ds, si_ds, segds, gA);
    gemm_layer<true><<<GD + GS, 256, 0, stream>>>(
        segdd, segsd, d1h, Wd2, bias + 2 * H, d2,
        segds, s1h, Ws2, bias + 3 * H, s2, sm, GD);

    // ---- batchnorm: fold spread stats, then apply ----
    bn_fold<<<2, 256, 0, stream>>>(sm, stats);
    bn_apply_all<<<((ND + NS) * (H / 4) + 255) / 256, 256, 0, stream>>>(d2, s2, stats, gamma, beta);
}

// Round 9
// 520.253 us; speedup vs baseline: 12.1947x; 1.0120x over previous
//
#include <hip/hip_runtime.h>
#include <hip/hip_bf16.h>

#define H 128
#define ND 100000
#define NS 10000

typedef __attribute__((ext_vector_type(8))) _Float16 f16x8;
typedef __attribute__((ext_vector_type(4))) float f32x4;

__device__ inline ushort f2h(float f) {
    union { _Float16 h; ushort u; } c; c.h = (_Float16)f; return c.u;
}
__device__ inline float h2f(ushort u) {
    union { ushort u; _Float16 h; } c; c.u = u; return (float)c.h;
}

// ---------------- fp32 -> fp16 convert, both tables, one launch -------------
__global__ __launch_bounds__(256) void f2h_all(
    const float* __restrict__ xd, const float* __restrict__ xs,
    ushort* __restrict__ od, ushort* __restrict__ os)
{
    int i = blockIdx.x * 256 + threadIdx.x;
    const int nD = ND * H / 4;
    const int nT = (ND + NS) * H / 4;
    if (i >= nT) return;
    const float* in; ushort* out; int j;
    if (i < nD) { in = xd; out = od; j = i; }
    else        { in = xs; out = os; j = i - nD; }
    float4 v = reinterpret_cast<const float4*>(in)[j];
    ushort4 o;
    o.x = f2h(v.x); o.y = f2h(v.y); o.z = f2h(v.z); o.w = f2h(v.w);
    reinterpret_cast<ushort4*>(out)[j] = o;
}

// ---------------- weight prep: fp32 -> fp16, fold root weights & biases ----
__global__ void prep_weights(
    const float* w1ddr, const float* w1ddo, const float* w1sdr, const float* w1sdo,
    const float* w1dsr, const float* w1dso,
    const float* w2ddr, const float* w2ddo, const float* w2sdr, const float* w2sdo,
    const float* w2dsr, const float* w2dso,
    const float* b1dd, const float* b1sd, const float* b1ds,
    const float* b2dd, const float* b2sd, const float* b2ds,
    ushort* Wd1, ushort* Ws1, ushort* Wd2, ushort* Ws2, float* bias)
{
    int i = blockIdx.x * blockDim.x + threadIdx.x;
    if (i < 16384) {
        Wd1[i]           = f2h(w1ddr[i]);
        Wd1[16384 + i]   = f2h(w1sdr[i]);
        Wd1[32768 + i]   = f2h(w1ddo[i] + w1sdo[i]);
        Ws1[i]           = f2h(w1dsr[i]);
        Ws1[16384 + i]   = f2h(w1dso[i]);
        Wd2[i]           = f2h(w2ddr[i]);
        Wd2[16384 + i]   = f2h(w2sdr[i]);
        Wd2[32768 + i]   = f2h(w2ddo[i] + w2sdo[i]);
        Ws2[i]           = f2h(w2dsr[i]);
        Ws2[16384 + i]   = f2h(w2dso[i]);
    }
    if (i < H) {
        bias[i]         = b1dd[i] + b1sd[i];
        bias[H + i]     = b1ds[i];
        bias[2*H + i]   = b2dd[i] + b2sd[i];
        bias[3*H + i]   = b2ds[i];
    }
}

// ---------------- histogram, XCD-partitioned dst windows --------------------
// pass = blockIdx & 7 == XCD id (round-robin dispatch heuristic): all atomics
// on dst-window p issue from XCD p only -> counter lines live in one L2.
__global__ __launch_bounds__(256) void hist3(
    const int* __restrict__ e1, int E1, int n1, int* __restrict__ c1,
    const int* __restrict__ e2, int E2, int n2, int* __restrict__ c2,
    const int* __restrict__ e3, int E3, int n3, int* __restrict__ c3,
    int g1, int g2)
{
    int pass = blockIdx.x & 7;
    int b = blockIdx.x >> 3;
    const int* ed; int* cnt; int E, n;
    if (b < g1)           { ed = e1; cnt = c1; E = E1; n = n1; }
    else if (b < g1 + g2) { ed = e2; cnt = c2; E = E2; n = n2; b -= g1; }
    else                  { ed = e3; cnt = c3; E = E3; n = n3; b -= g1 + g2; }
    int e = b * 256 + threadIdx.x;
    if (e >= E) return;
    int dst = ed[e];
    int lo = pass * (n >> 3);
    if (dst >= lo && dst < lo + (n >> 3))
        atomicAdd(&cnt[dst], 1);
}

// ---------------- scan stage 1 ----------------------------------------------
__global__ __launch_bounds__(256) void scan1_3(
    const int* __restrict__ c1, int n1, int* __restrict__ r1, int* __restrict__ b1,
    const int* __restrict__ c2, int n2, int* __restrict__ r2, int* __restrict__ b2,
    const int* __restrict__ c3, int n3, int* __restrict__ r3, int* __restrict__ b3,
    int g1, int g2)
{
    int blk = blockIdx.x;
    const int* cnt; int n; int* rp; int* bs;
    if (blk < g1)           { cnt = c1; n = n1; rp = r1; bs = b1; }
    else if (blk < g1 + g2) { cnt = c2; n = n2; rp = r2; bs = b2; blk -= g1; }
    else                    { cnt = c3; n = n3; rp = r3; bs = b3; blk -= g1 + g2; }
    __shared__ int sh[256];
    const int t = threadIdx.x;
    const int base = blk * 2048 + t * 8;
    int v[8]; int s = 0;
    #pragma unroll
    for (int j = 0; j < 8; ++j) { int i = base + j; v[j] = (i < n) ? cnt[i] : 0; s += v[j]; }
    sh[t] = s; __syncthreads();
    for (int off = 1; off < 256; off <<= 1) {
        int y = (t >= off) ? sh[t - off] : 0;
        __syncthreads();
        sh[t] += y;
        __syncthreads();
    }
    int excl = sh[t] - s;
    #pragma unroll
    for (int j = 0; j < 8; ++j) { int i = base + j; if (i < n) rp[i] = excl; excl += v[j]; }
    if (t == 255) bs[blk] = sh[255];
}

// ---------------- scan stage 2 ----------------------------------------------
__global__ void scan2_3(int* b1, int nb1, int* b2, int nb2, int* b3, int nb3)
{
    int* bs; int nb;
    if (blockIdx.x == 0)      { bs = b1; nb = nb1; }
    else if (blockIdx.x == 1) { bs = b2; nb = nb2; }
    else                      { bs = b3; nb = nb3; }
    int t = threadIdx.x;
    int v = (t < nb) ? bs[t] : 0;
    int x = v;
    for (int off = 1; off < 64; off <<= 1) {
        int y = __shfl_up(x, off);
        if (t >= off) x += y;
    }
    if (t < nb) bs[t] = x - v;
}

// ---------------- scan stage 3: add offsets, init cursors -------------------
__global__ __launch_bounds__(256) void scan3_3(
    int* __restrict__ r1, int n1, const int* __restrict__ b1, int* __restrict__ c1, int E1,
    int* __restrict__ r2, int n2, const int* __restrict__ b2, int* __restrict__ c2, int E2,
    int* __restrict__ r3, int n3, const int* __restrict__ b3, int* __restrict__ c3, int E3,
    int g1, int g2)
{
    int blk = blockIdx.x;
    int* rp; int n; const int* bs; int* cur; int E;
    if (blk < g1)           { rp = r1; n = n1; bs = b1; cur = c1; E = E1; }
    else if (blk < g1 + g2) { rp = r2; n = n2; bs = b2; cur = c2; E = E2; blk -= g1; }
    else                    { rp = r3; n = n3; bs = b3; cur = c3; E = E3; blk -= g1 + g2; }
    int i = blk * 256 + threadIdx.x;
    if (i < n) {
        int v = rp[i] + bs[i >> 11];
        rp[i] = v;
        cur[i] = v;
    }
    if (i == 0) rp[n] = E;
}

// ---------------- CSR fill, XCD-partitioned dst windows ---------------------
// pass = blockIdx & 7 == XCD id: si window p and its cursors are written by
// XCD p only -> no cross-XCD partial-line writebacks.
__global__ __launch_bounds__(256) void fill3(
    const int* __restrict__ s1, const int* __restrict__ d1, int E1, int n1, int* __restrict__ c1, int* __restrict__ o1,
    const int* __restrict__ s2, const int* __restrict__ d2, int E2, int n2, int* __restrict__ c2, int* __restrict__ o2,
    const int* __restrict__ s3, const int* __restrict__ d3, int E3, int n3, int* __restrict__ c3, int* __restrict__ o3,
    int g1, int g2)
{
    int pass = blockIdx.x & 7;
    int b = blockIdx.x >> 3;
    const int *es, *ed; int *cur, *si; int E, n;
    if (b < g1)           { es = s1; ed = d1; cur = c1; si = o1; E = E1; n = n1; }
    else if (b < g1 + g2) { es = s2; ed = d2; cur = c2; si = o2; E = E2; n = n2; b -= g1; }
    else                  { es = s3; ed = d3; cur = c3; si = o3; E = E3; n = n3; b -= g1 + g2; }
    int e = b * 256 + threadIdx.x;
    if (e >= E) return;
    int dst = ed[e];
    int lo = pass * (n >> 3);
    if (dst >= lo && dst < lo + (n >> 3)) {
        int pos = atomicAdd(&cur[dst], 1);
        si[pos] = es[e];
    }
}

// ---------------- CSR aggregate: half-wave per dest, 4-deep unroll ----------
__global__ __launch_bounds__(256) void agg3(
    const ushort* __restrict__ dtab, const ushort* __restrict__ stab,
    const int* __restrict__ rpdd, const int* __restrict__ sidd, ushort* __restrict__ segdd,
    const int* __restrict__ rpsd, const int* __restrict__ sisd, ushort* __restrict__ segsd,
    const int* __restrict__ rpds, const int* __restrict__ sids, ushort* __restrict__ segds,
    int gA)
{
    int b = blockIdx.x;
    const ushort* src; const int* rp; const int* si; ushort* dst; int Ndst;
    if (b < gA)          { src = dtab; rp = rpdd; si = sidd; dst = segdd; Ndst = ND; }
    else if (b < 2 * gA) { src = stab; rp = rpsd; si = sisd; dst = segsd; Ndst = ND; b -= gA; }
    else                 { src = dtab; rp = rpds; si = sids; dst = segds; Ndst = NS; b -= 2 * gA; }
    int d = b * 8 + (threadIdx.x >> 5);   // 8 half-waves per block
    if (d >= Ndst) return;
    int c = threadIdx.x & 31;             // 8B per lane covers the 256B row
    int p0 = rp[d], p1 = rp[d + 1];
    float a0 = 0.f, a1 = 0.f, a2 = 0.f, a3 = 0.f;
    int p = p0;
    for (; p + 4 <= p1; p += 4) {
        int s0 = si[p], s1 = si[p + 1], s2 = si[p + 2], s3 = si[p + 3];
        uint2 v0 = *reinterpret_cast<const uint2*>(src + (size_t)s0 * H + c * 4);
        uint2 v1 = *reinterpret_cast<const uint2*>(src + (size_t)s1 * H + c * 4);
        uint2 v2 = *reinterpret_cast<const uint2*>(src + (size_t)s2 * H + c * 4);
        uint2 v3 = *reinterpret_cast<const uint2*>(src + (size_t)s3 * H + c * 4);
        a0 += h2f((ushort)(v0.x & 0xffff)) + h2f((ushort)(v1.x & 0xffff))
            + h2f((ushort)(v2.x & 0xffff)) + h2f((ushort)(v3.x & 0xffff));
        a1 += h2f((ushort)(v0.x >> 16))    + h2f((ushort)(v1.x >> 16))
            + h2f((ushort)(v2.x >> 16))    + h2f((ushort)(v3.x >> 16));
        a2 += h2f((ushort)(v0.y & 0xffff)) + h2f((ushort)(v1.y & 0xffff))
            + h2f((ushort)(v2.y & 0xffff)) + h2f((ushort)(v3.y & 0xffff));
        a3 += h2f((ushort)(v0.y >> 16))    + h2f((ushort)(v1.y >> 16))
            + h2f((ushort)(v2.y >> 16))    + h2f((ushort)(v3.y >> 16));
    }
    for (; p < p1; ++p) {
        int s0 = si[p];
        uint2 v0 = *reinterpret_cast<const uint2*>(src + (size_t)s0 * H + c * 4);
        a0 += h2f((ushort)(v0.x & 0xffff));
        a1 += h2f((ushort)(v0.x >> 16));
        a2 += h2f((ushort)(v0.y & 0xffff));
        a3 += h2f((ushort)(v0.y >> 16));
    }
    uint2 o;
    o.x = (uint)f2h(a0) | ((uint)f2h(a1) << 16);
    o.y = (uint)f2h(a2) | ((uint)f2h(a3) << 16);
    *reinterpret_cast<uint2*>(dst + (size_t)d * H + c * 4) = o;
}

// ---------------- fused GEMM layer: drug + SE in one dispatch, BM=64 --------
// sm copy layout (512 floats per copy, 8 copies):
//   [0:128) drug sum | [128:256) drug sumsq | [256:384) SE sum | [384:512) SE sumsq
template<bool OUTF32>
__global__ __launch_bounds__(256) void gemm_layer(
    const ushort* __restrict__ segdd, const ushort* __restrict__ segsd,
    const ushort* __restrict__ rootd, const ushort* __restrict__ Wd,
    const float* __restrict__ biasd, void* __restrict__ outd,
    const ushort* __restrict__ segds, const ushort* __restrict__ roots,
    const ushort* __restrict__ Ws, const float* __restrict__ biass,
    void* __restrict__ outs, float* __restrict__ sm, int GD)
{
    __shared__ union {
        struct { ushort Al[64][40]; ushort Bl[128][40]; } s;  // 15.4 KB
        float red[2][16][128];                                 // 16 KB
    } u;

    int b = blockIdx.x;
    const ushort *src0, *src1, *src2, *W; const float* bias; void* out;
    int M, nsrc, soff;
    if (b < GD) {
        src0 = segdd; src1 = segsd; src2 = rootd; W = Wd; bias = biasd;
        out = outd; M = ND; nsrc = 3; soff = 0;
    } else {
        b -= GD;
        src0 = segds; src1 = roots; src2 = nullptr; W = Ws; bias = biass;
        out = outs; M = NS; nsrc = 2; soff = 256;
    }

    const int t = threadIdx.x;
    const int wave = t >> 6;
    const int lane = t & 63;
    const int l15 = lane & 15;
    const int kreg = lane >> 4;
    const int block_row = b * 64;

    f32x4 acc[8] = {};

    for (int slot = 0; slot < nsrc; ++slot) {
        const ushort* sb = (slot == 0) ? src0 : (slot == 1) ? src1 : src2;
        #pragma unroll
        for (int kk = 0; kk < 4; ++kk) {
            const int kc = kk * 32;
            __syncthreads();
            {
                int row = t >> 2, part = t & 3;
                int grow = block_row + row;
                uint4 v = make_uint4(0, 0, 0, 0);
                if (grow < M)
                    v = *reinterpret_cast<const uint4*>(sb + (size_t)grow * H + kc + part * 8);
                *reinterpret_cast<uint4*>(&u.s.Al[row][part * 8]) = v;
            }
            #pragma unroll
            for (int it = 0; it < 2; ++it) {
                int c = t + it * 256;
                int row = c >> 2, part = c & 3;
                uint4 v = *reinterpret_cast<const uint4*>(W + slot * 16384 + row * 128 + kc + part * 8);
                *reinterpret_cast<uint4*>(&u.s.Bl[row][part * 8]) = v;
            }
            __syncthreads();

            f16x8 a = *reinterpret_cast<const f16x8*>(&u.s.Al[wave * 16 + l15][kreg * 8]);
            #pragma unroll
            for (int n = 0; n < 8; ++n) {
                f16x8 bb = *reinterpret_cast<const f16x8*>(&u.s.Bl[n * 16 + l15][kreg * 8]);
                acc[n] = __builtin_amdgcn_mfma_f32_16x16x32_f16(a, bb, acc[n], 0, 0, 0);
            }
        }
    }

    float psum[8], psq[8];
    const int rb = block_row + wave * 16 + kreg * 4;
    #pragma unroll
    for (int n = 0; n < 8; ++n) {
        int col = n * 16 + l15;
        float bv = bias[col];
        float s = 0.f, q = 0.f;
        #pragma unroll
        for (int r = 0; r < 4; ++r) {
            int row = rb + r;
            if (row < M) {
                float v = acc[n][r] + bv;
                v = (v > 0.f) ? v : 0.01f * v;
                if (OUTF32) ((float*)out)[(size_t)row * H + col] = v;
                else        ((ushort*)out)[(size_t)row * H + col] = f2h(v);
                s += v; q += v * v;
            }
        }
        psum[n] = s; psq[n] = q;
    }

    if (OUTF32) {
        __syncthreads();
        const int w4k = wave * 4 + kreg;
        #pragma unroll
        for (int n = 0; n < 8; ++n) {
            int col = n * 16 + l15;
            u.red[0][w4k][col] = psum[n];
            u.red[1][w4k][col] = psq[n];
        }
        __syncthreads();
        if (t < 128) {
            float a = 0.f, q = 0.f;
            #pragma unroll
            for (int k = 0; k < 16; ++k) { a += u.red[0][k][t]; q += u.red[1][k][t]; }
            float* dstp = sm + (blockIdx.x & 7) * 512 + soff;
            atomicAdd(&dstp[t], a);
            atomicAdd(&dstp[H + t], q);
        }
    }
}

// ---------------- fold 8 stats copies -> stats ------------------------------
__global__ void bn_fold(const float* __restrict__ sm, float* __restrict__ stats)
{
    int t = blockIdx.x * 256 + threadIdx.x;   // 0..511
    float s = 0.f;
    #pragma unroll
    for (int k = 0; k < 8; ++k) s += sm[k * 512 + t];
    stats[t] = s;
}

// ---------------- batchnorm apply: both tables in one launch ----------------
__global__ __launch_bounds__(256) void bn_apply_all(
    float* __restrict__ d2, float* __restrict__ s2,
    const float* __restrict__ stats,
    const float* __restrict__ gamma, const float* __restrict__ beta)
{
    size_t i = (size_t)blockIdx.x * 256 + threadIdx.x;
    const size_t totD = (size_t)ND * (H / 4);
    const size_t totAll = totD + (size_t)NS * (H / 4);
    if (i >= totAll) return;
    float* x;
    const float* st;
    float inv_m;
    size_t j;
    if (i < totD) { x = d2; st = stats;       inv_m = 1.0f / ND; j = i; }
    else          { x = s2; st = stats + 256; inv_m = 1.0f / NS; j = i - totD; }
    int c4 = (int)(j & (H / 4 - 1)) * 4;
    float4 v = reinterpret_cast<float4*>(x)[j];
    float* vp = &v.x;
    #pragma unroll
    for (int k = 0; k < 4; ++k) {
        int c = c4 + k;
        float mean = st[c] * inv_m;
        float var = st[H + c] * inv_m - mean * mean;
        float sc = gamma[c] * rsqrtf(fmaxf(var, 0.f) + 1e-5f);
        vp[k] = (vp[k] - mean) * sc + beta[c];
    }
    reinterpret_cast<float4*>(x)[j] = v;
}

// ---------------- launch ----------------------------------------------------
extern "C" void kernel_launch(void* const* d_in, const int* in_sizes, int n_in,
                              void* d_out, int out_size, void* d_ws, size_t ws_size,
                              hipStream_t stream)
{
    (void)n_in; (void)out_size; (void)ws_size;
    const float* x_drug = (const float*)d_in[0];
    const float* x_se   = (const float*)d_in[1];
    const int* ei_dd = (const int*)d_in[2];
    const int* ei_ds = (const int*)d_in[3];
    const int* ei_sd = (const int*)d_in[4];
    const int EDD = in_sizes[2] / 2;
    const int EDS = in_sizes[3] / 2;
    const int ESD = in_sizes[4] / 2;

    const float* w1_dd_rel  = (const float*)d_in[5];
    const float* b1_dd      = (const float*)d_in[6];
    const float* w1_dd_root = (const float*)d_in[7];
    const float* w1_ds_rel  = (const float*)d_in[8];
    const float* b1_ds      = (const float*)d_in[9];
    const float* w1_ds_root = (const float*)d_in[10];
    const float* w1_sd_rel  = (const float*)d_in[11];
    const float* b1_sd      = (const float*)d_in[12];
    const float* w1_sd_root = (const float*)d_in[13];
    const float* w2_dd_rel  = (const float*)d_in[14];
    const float* b2_dd      = (const float*)d_in[15];
    const float* w2_dd_root = (const float*)d_in[16];
    const float* w2_ds_rel  = (const float*)d_in[17];
    const float* b2_ds      = (const float*)d_in[18];
    const float* w2_ds_root = (const float*)d_in[19];
    const float* w2_sd_rel  = (const float*)d_in[20];
    const float* b2_sd      = (const float*)d_in[21];
    const float* w2_sd_root = (const float*)d_in[22];
    const float* gamma      = (const float*)d_in[23];
    const float* beta       = (const float*)d_in[24];

    // ---------------- workspace layout ----------------
    ushort* xd_h  = (ushort*)d_ws;                     // ND*H fp16 (becomes d1h in place)
    ushort* xs_h  = xd_h + (size_t)ND * H;             // NS*H fp16 (becomes s1h)
    ushort* segdd = xs_h + (size_t)NS * H;             // ND*H
    ushort* segsd = segdd + (size_t)ND * H;            // ND*H
    ushort* segds = segsd + (size_t)ND * H;            // NS*H
    ushort* Wd1 = segds + (size_t)NS * H;              // 3*16384
    ushort* Ws1 = Wd1 + 3 * 16384;                     // 2*16384
    ushort* Wd2 = Ws1 + 2 * 16384;                     // 3*16384
    ushort* Ws2 = Wd2 + 3 * 16384;                     // 2*16384
    float* bias  = (float*)(Ws2 + 2 * 16384);          // 512
    float* stats = bias + 512;                         // 512
    float* sm    = stats + 512;                        // 8*512 spread stats (memset start)
    int* cur_dd  = (int*)(sm + 8 * 512);               // ND (hist+cursor)
    int* cur_sd  = cur_dd + ND;                        // ND
    int* cur_ds  = cur_sd + ND;                        // NS (memset end)
    int* rp_dd = cur_ds + NS;                          // ND+1
    int* rp_sd = rp_dd + (ND + 1);                     // ND+1
    int* rp_ds = rp_sd + (ND + 1);                     // NS+1
    int* si_dd = rp_ds + (NS + 1);                     // EDD
    int* si_sd = si_dd + EDD;                          // ESD
    int* si_ds = si_sd + ESD;                          // EDS
    int* bs_dd = si_ds + EDS;                          // 64
    int* bs_sd = bs_dd + 64;                           // 64
    int* bs_ds = bs_sd + 64;                           // 64

    ushort* d1h = xd_h;
    ushort* s1h = xs_h;

    float* d2 = (float*)d_out;                // ND*H
    float* s2 = d2 + (size_t)ND * H;          // NS*H

    // zero sm + hist/cursor arrays (contiguous region)
    hipMemsetAsync(sm, 0, ((size_t)8 * 512 + (size_t)(2 * ND + NS)) * sizeof(int), stream);

    prep_weights<<<64, 256, 0, stream>>>(
        w1_dd_rel, w1_dd_root, w1_sd_rel, w1_sd_root, w1_ds_rel, w1_ds_root,
        w2_dd_rel, w2_dd_root, w2_sd_rel, w2_sd_root, w2_ds_rel, w2_ds_root,
        b1_dd, b1_sd, b1_ds, b2_dd, b2_sd, b2_ds,
        Wd1, Ws1, Wd2, Ws2, bias);

    f2h_all<<<((ND + NS) * H / 4 + 255) / 256, 256, 0, stream>>>(x_drug, x_se, xd_h, xs_h);

    // ---- CSR build (XCD-partitioned hist/fill) ----
    const int gDD = (EDD + 255) / 256, gSD = (ESD + 255) / 256, gDS = (EDS + 255) / 256;
    hist3<<<8 * (gDD + gSD + gDS), 256, 0, stream>>>(
        ei_dd + EDD, EDD, ND, cur_dd,
        ei_sd + ESD, ESD, ND, cur_sd,
        ei_ds + EDS, EDS, NS, cur_ds, gDD, gSD);

    const int nbDD = (ND + 2047) / 2048, nbDS = (NS + 2047) / 2048;
    scan1_3<<<2 * nbDD + nbDS, 256, 0, stream>>>(
        cur_dd, ND, rp_dd, bs_dd,
        cur_sd, ND, rp_sd, bs_sd,
        cur_ds, NS, rp_ds, bs_ds, nbDD, nbDD);
    scan2_3<<<3, 64, 0, stream>>>(bs_dd, nbDD, bs_sd, nbDD, bs_ds, nbDS);
    const int g3D = (ND + 255) / 256, g3S = (NS + 255) / 256;
    scan3_3<<<2 * g3D + g3S, 256, 0, stream>>>(
        rp_dd, ND, bs_dd, cur_dd, EDD,
        rp_sd, ND, bs_sd, cur_sd, ESD,
        rp_ds, NS, bs_ds, cur_ds, EDS, g3D, g3D);

    fill3<<<8 * (gDD + gSD + gDS), 256, 0, stream>>>(
        ei_dd, ei_dd + EDD, EDD, ND, cur_dd, si_dd,
        ei_sd, ei_sd + ESD, ESD, ND, cur_sd, si_sd,
        ei_ds, ei_ds + EDS, EDS, NS, cur_ds, si_ds, gDD, gSD);

    const int gA = (ND + 7) / 8, gB = (NS + 7) / 8;
    const int GD = (ND + 63) / 64, GS = (NS + 63) / 64;

    // ---- layer 1 ----
    agg3<<<2 * gA + gB, 256, 0, stream>>>(
        xd_h, xs_h,
        rp_dd, si_dd, segdd,
        rp_sd, si_sd, segsd,
        rp_ds, si_ds, segds, gA);
    gemm_layer<false><<<GD + GS, 256, 0, stream>>>(
        segdd, segsd, xd_h, Wd1, bias, d1h,
        segds, xs_h, Ws1, bias + H, s1h, sm, GD);

    // ---- layer 2 ----
    agg3<<<2 * gA + gB, 256, 0, stream>>>(
        d1h, s1h,
        rp_dd, si_dd, segdd,
        rp_sd, si_sd, segsd,
        rp_ds, si_ds, segds, gA);
    gemm_layer<true><<<GD + GS, 256, 0, stream>>>(
        segdd, segsd, d1h, Wd2, bias + 2 * H, d2,
        segds, s1h, Ws2, bias + 3 * H, s2, sm, GD);

    // ---- batchnorm: fold spread stats, then apply ----
    bn_fold<<<2, 256, 0, stream>>>(sm, stats);
    bn_apply_all<<<((ND + NS) * (H / 4) + 255) / 256, 256, 0, stream>>>(d2, s2, stats, gamma, beta);
}

// Round 10
// 489.376 us; speedup vs baseline: 12.9642x; 1.0631x over previous
//
#include <hip/hip_runtime.h>
#include <hip/hip_bf16.h>

#define H 128
#define ND 100000
#define NS 10000

typedef __attribute__((ext_vector_type(8))) _Float16 f16x8;
typedef __attribute__((ext_vector_type(4))) float f32x4;

__device__ inline ushort f2h(float f) {
    union { _Float16 h; ushort u; } c; c.h = (_Float16)f; return c.u;
}
__device__ inline float h2f(ushort u) {
    union { ushort u; _Float16 h; } c; c.u = u; return (float)c.h;
}

// ---------------- fp32 -> fp16 convert, both tables, one launch -------------
__global__ __launch_bounds__(256) void f2h_all(
    const float* __restrict__ xd, const float* __restrict__ xs,
    ushort* __restrict__ od, ushort* __restrict__ os)
{
    int i = blockIdx.x * 256 + threadIdx.x;
    const int nD = ND * H / 4;
    const int nT = (ND + NS) * H / 4;
    if (i >= nT) return;
    const float* in; ushort* out; int j;
    if (i < nD) { in = xd; out = od; j = i; }
    else        { in = xs; out = os; j = i - nD; }
    float4 v = reinterpret_cast<const float4*>(in)[j];
    ushort4 o;
    o.x = f2h(v.x); o.y = f2h(v.y); o.z = f2h(v.z); o.w = f2h(v.w);
    reinterpret_cast<ushort4*>(out)[j] = o;
}

// ---------------- weight prep: fp32 -> fp16, fold root weights & biases ----
__global__ void prep_weights(
    const float* w1ddr, const float* w1ddo, const float* w1sdr, const float* w1sdo,
    const float* w1dsr, const float* w1dso,
    const float* w2ddr, const float* w2ddo, const float* w2sdr, const float* w2sdo,
    const float* w2dsr, const float* w2dso,
    const float* b1dd, const float* b1sd, const float* b1ds,
    const float* b2dd, const float* b2sd, const float* b2ds,
    ushort* Wd1, ushort* Ws1, ushort* Wd2, ushort* Ws2, float* bias)
{
    int i = blockIdx.x * blockDim.x + threadIdx.x;
    if (i < 16384) {
        Wd1[i]           = f2h(w1ddr[i]);
        Wd1[16384 + i]   = f2h(w1sdr[i]);
        Wd1[32768 + i]   = f2h(w1ddo[i] + w1sdo[i]);
        Ws1[i]           = f2h(w1dsr[i]);
        Ws1[16384 + i]   = f2h(w1dso[i]);
        Wd2[i]           = f2h(w2ddr[i]);
        Wd2[16384 + i]   = f2h(w2sdr[i]);
        Wd2[32768 + i]   = f2h(w2ddo[i] + w2sdo[i]);
        Ws2[i]           = f2h(w2dsr[i]);
        Ws2[16384 + i]   = f2h(w2dso[i]);
    }
    if (i < H) {
        bias[i]         = b1dd[i] + b1sd[i];
        bias[H + i]     = b1ds[i];
        bias[2*H + i]   = b2dd[i] + b2sd[i];
        bias[3*H + i]   = b2ds[i];
    }
}

// ---------------- histogram, single-read, 3 rels ----------------------------
__global__ __launch_bounds__(256) void hist3(
    const int* __restrict__ e1, int E1, int* __restrict__ c1,
    const int* __restrict__ e2, int E2, int* __restrict__ c2,
    const int* __restrict__ e3, int E3, int* __restrict__ c3,
    int g1, int g2)
{
    int b = blockIdx.x;
    const int* ed; int* cnt; int E;
    if (b < g1)           { ed = e1; cnt = c1; E = E1; }
    else if (b < g1 + g2) { ed = e2; cnt = c2; E = E2; b -= g1; }
    else                  { ed = e3; cnt = c3; E = E3; b -= g1 + g2; }
    int e = b * 256 + threadIdx.x;
    if (e < E) atomicAdd(&cnt[ed[e]], 1);
}

// ---------------- scan stage 1 ----------------------------------------------
__global__ __launch_bounds__(256) void scan1_3(
    const int* __restrict__ c1, int n1, int* __restrict__ r1, int* __restrict__ b1,
    const int* __restrict__ c2, int n2, int* __restrict__ r2, int* __restrict__ b2,
    const int* __restrict__ c3, int n3, int* __restrict__ r3, int* __restrict__ b3,
    int g1, int g2)
{
    int blk = blockIdx.x;
    const int* cnt; int n; int* rp; int* bs;
    if (blk < g1)           { cnt = c1; n = n1; rp = r1; bs = b1; }
    else if (blk < g1 + g2) { cnt = c2; n = n2; rp = r2; bs = b2; blk -= g1; }
    else                    { cnt = c3; n = n3; rp = r3; bs = b3; blk -= g1 + g2; }
    __shared__ int sh[256];
    const int t = threadIdx.x;
    const int base = blk * 2048 + t * 8;
    int v[8]; int s = 0;
    #pragma unroll
    for (int j = 0; j < 8; ++j) { int i = base + j; v[j] = (i < n) ? cnt[i] : 0; s += v[j]; }
    sh[t] = s; __syncthreads();
    for (int off = 1; off < 256; off <<= 1) {
        int y = (t >= off) ? sh[t - off] : 0;
        __syncthreads();
        sh[t] += y;
        __syncthreads();
    }
    int excl = sh[t] - s;
    #pragma unroll
    for (int j = 0; j < 8; ++j) { int i = base + j; if (i < n) rp[i] = excl; excl += v[j]; }
    if (t == 255) bs[blk] = sh[255];
}

// ---------------- scan stage 2 ----------------------------------------------
__global__ void scan2_3(int* b1, int nb1, int* b2, int nb2, int* b3, int nb3)
{
    int* bs; int nb;
    if (blockIdx.x == 0)      { bs = b1; nb = nb1; }
    else if (blockIdx.x == 1) { bs = b2; nb = nb2; }
    else                      { bs = b3; nb = nb3; }
    int t = threadIdx.x;
    int v = (t < nb) ? bs[t] : 0;
    int x = v;
    for (int off = 1; off < 64; off <<= 1) {
        int y = __shfl_up(x, off);
        if (t >= off) x += y;
    }
    if (t < nb) bs[t] = x - v;
}

// ---------------- scan stage 3: add offsets, init cursors -------------------
__global__ __launch_bounds__(256) void scan3_3(
    int* __restrict__ r1, int n1, const int* __restrict__ b1, int* __restrict__ c1, int E1,
    int* __restrict__ r2, int n2, const int* __restrict__ b2, int* __restrict__ c2, int E2,
    int* __restrict__ r3, int n3, const int* __restrict__ b3, int* __restrict__ c3, int E3,
    int g1, int g2)
{
    int blk = blockIdx.x;
    int* rp; int n; const int* bs; int* cur; int E;
    if (blk < g1)           { rp = r1; n = n1; bs = b1; cur = c1; E = E1; }
    else if (blk < g1 + g2) { rp = r2; n = n2; bs = b2; cur = c2; E = E2; blk -= g1; }
    else                    { rp = r3; n = n3; bs = b3; cur = c3; E = E3; blk -= g1 + g2; }
    int i = blk * 256 + threadIdx.x;
    if (i < n) {
        int v = rp[i] + bs[i >> 11];
        rp[i] = v;
        cur[i] = v;
    }
    if (i == 0) rp[n] = E;
}

// ---------------- CSR fill, XCD-partitioned dst windows ---------------------
// pass = blockIdx & 7 == XCD id: si window p and its cursors are written by
// XCD p only -> no cross-XCD partial-line writebacks (proven round 9).
__global__ __launch_bounds__(256) void fill3(
    const int* __restrict__ s1, const int* __restrict__ d1, int E1, int n1, int* __restrict__ c1, int* __restrict__ o1,
    const int* __restrict__ s2, const int* __restrict__ d2, int E2, int n2, int* __restrict__ c2, int* __restrict__ o2,
    const int* __restrict__ s3, const int* __restrict__ d3, int E3, int n3, int* __restrict__ c3, int* __restrict__ o3,
    int g1, int g2)
{
    int pass = blockIdx.x & 7;
    int b = blockIdx.x >> 3;
    const int *es, *ed; int *cur, *si; int E, n;
    if (b < g1)           { es = s1; ed = d1; cur = c1; si = o1; E = E1; n = n1; }
    else if (b < g1 + g2) { es = s2; ed = d2; cur = c2; si = o2; E = E2; n = n2; b -= g1; }
    else                  { es = s3; ed = d3; cur = c3; si = o3; E = E3; n = n3; b -= g1 + g2; }
    int e = b * 256 + threadIdx.x;
    if (e >= E) return;
    int dst = ed[e];
    int lo = pass * (n >> 3);
    if (dst >= lo && dst < lo + (n >> 3)) {
        int pos = atomicAdd(&cur[dst], 1);
        si[pos] = es[e];
    }
}

// ---------------- CSR aggregate: quarter-wave per dest, uint4 loads ---------
// 16 lanes x 16B cover a 256B row; 16 dsts per block; 4-deep source unroll.
__global__ __launch_bounds__(256) void agg3(
    const ushort* __restrict__ dtab, const ushort* __restrict__ stab,
    const int* __restrict__ rpdd, const int* __restrict__ sidd, ushort* __restrict__ segdd,
    const int* __restrict__ rpsd, const int* __restrict__ sisd, ushort* __restrict__ segsd,
    const int* __restrict__ rpds, const int* __restrict__ sids, ushort* __restrict__ segds,
    int gA)
{
    int b = blockIdx.x;
    const ushort* src; const int* rp; const int* si; ushort* dst; int Ndst;
    if (b < gA)          { src = dtab; rp = rpdd; si = sidd; dst = segdd; Ndst = ND; }
    else if (b < 2 * gA) { src = stab; rp = rpsd; si = sisd; dst = segsd; Ndst = ND; b -= gA; }
    else                 { src = dtab; rp = rpds; si = sids; dst = segds; Ndst = NS; b -= 2 * gA; }
    int d = b * 16 + (threadIdx.x >> 4);
    if (d >= Ndst) return;
    int c = threadIdx.x & 15;             // 16B per lane covers the 256B row
    int p0 = rp[d], p1 = rp[d + 1];
    float a0 = 0.f, a1 = 0.f, a2 = 0.f, a3 = 0.f;
    float a4 = 0.f, a5 = 0.f, a6 = 0.f, a7 = 0.f;
    int p = p0;
    for (; p + 4 <= p1; p += 4) {
        int s0 = si[p], s1 = si[p + 1], s2 = si[p + 2], s3 = si[p + 3];
        uint4 v0 = *reinterpret_cast<const uint4*>(src + (size_t)s0 * H + c * 8);
        uint4 v1 = *reinterpret_cast<const uint4*>(src + (size_t)s1 * H + c * 8);
        uint4 v2 = *reinterpret_cast<const uint4*>(src + (size_t)s2 * H + c * 8);
        uint4 v3 = *reinterpret_cast<const uint4*>(src + (size_t)s3 * H + c * 8);
        a0 += h2f((ushort)(v0.x & 0xffff)) + h2f((ushort)(v1.x & 0xffff))
            + h2f((ushort)(v2.x & 0xffff)) + h2f((ushort)(v3.x & 0xffff));
        a1 += h2f((ushort)(v0.x >> 16))    + h2f((ushort)(v1.x >> 16))
            + h2f((ushort)(v2.x >> 16))    + h2f((ushort)(v3.x >> 16));
        a2 += h2f((ushort)(v0.y & 0xffff)) + h2f((ushort)(v1.y & 0xffff))
            + h2f((ushort)(v2.y & 0xffff)) + h2f((ushort)(v3.y & 0xffff));
        a3 += h2f((ushort)(v0.y >> 16))    + h2f((ushort)(v1.y >> 16))
            + h2f((ushort)(v2.y >> 16))    + h2f((ushort)(v3.y >> 16));
        a4 += h2f((ushort)(v0.z & 0xffff)) + h2f((ushort)(v1.z & 0xffff))
            + h2f((ushort)(v2.z & 0xffff)) + h2f((ushort)(v3.z & 0xffff));
        a5 += h2f((ushort)(v0.z >> 16))    + h2f((ushort)(v1.z >> 16))
            + h2f((ushort)(v2.z >> 16))    + h2f((ushort)(v3.z >> 16));
        a6 += h2f((ushort)(v0.w & 0xffff)) + h2f((ushort)(v1.w & 0xffff))
            + h2f((ushort)(v2.w & 0xffff)) + h2f((ushort)(v3.w & 0xffff));
        a7 += h2f((ushort)(v0.w >> 16))    + h2f((ushort)(v1.w >> 16))
            + h2f((ushort)(v2.w >> 16))    + h2f((ushort)(v3.w >> 16));
    }
    for (; p < p1; ++p) {
        int s0 = si[p];
        uint4 v0 = *reinterpret_cast<const uint4*>(src + (size_t)s0 * H + c * 8);
        a0 += h2f((ushort)(v0.x & 0xffff));
        a1 += h2f((ushort)(v0.x >> 16));
        a2 += h2f((ushort)(v0.y & 0xffff));
        a3 += h2f((ushort)(v0.y >> 16));
        a4 += h2f((ushort)(v0.z & 0xffff));
        a5 += h2f((ushort)(v0.z >> 16));
        a6 += h2f((ushort)(v0.w & 0xffff));
        a7 += h2f((ushort)(v0.w >> 16));
    }
    uint4 o;
    o.x = (uint)f2h(a0) | ((uint)f2h(a1) << 16);
    o.y = (uint)f2h(a2) | ((uint)f2h(a3) << 16);
    o.z = (uint)f2h(a4) | ((uint)f2h(a5) << 16);
    o.w = (uint)f2h(a6) | ((uint)f2h(a7) << 16);
    *reinterpret_cast<uint4*>(dst + (size_t)d * H + c * 8) = o;
}

// ---------------- fused GEMM layer: drug + SE, BM=64, BK=64 -----------------
// sm copy layout (512 floats per copy, 8 copies):
//   [0:128) drug sum | [128:256) drug sumsq | [256:384) SE sum | [384:512) SE sumsq
template<bool OUTF32>
__global__ __launch_bounds__(256) void gemm_layer(
    const ushort* __restrict__ segdd, const ushort* __restrict__ segsd,
    const ushort* __restrict__ rootd, const ushort* __restrict__ Wd,
    const float* __restrict__ biasd, void* __restrict__ outd,
    const ushort* __restrict__ segds, const ushort* __restrict__ roots,
    const ushort* __restrict__ Ws, const float* __restrict__ biass,
    void* __restrict__ outs, float* __restrict__ sm, int GD)
{
    __shared__ union {
        struct { ushort Al[64][72]; ushort Bl[128][72]; } s;  // 27.6 KB (pad 72: conflict-free)
        float red[2][16][128];                                 // 16 KB
    } u;

    int b = blockIdx.x;
    const ushort *src0, *src1, *src2, *W; const float* bias; void* out;
    int M, nsrc, soff;
    if (b < GD) {
        src0 = segdd; src1 = segsd; src2 = rootd; W = Wd; bias = biasd;
        out = outd; M = ND; nsrc = 3; soff = 0;
    } else {
        b -= GD;
        src0 = segds; src1 = roots; src2 = nullptr; W = Ws; bias = biass;
        out = outs; M = NS; nsrc = 2; soff = 256;
    }

    const int t = threadIdx.x;
    const int wave = t >> 6;
    const int lane = t & 63;
    const int l15 = lane & 15;
    const int kreg = lane >> 4;
    const int block_row = b * 64;

    f32x4 acc[8] = {};

    for (int slot = 0; slot < nsrc; ++slot) {
        const ushort* sb = (slot == 0) ? src0 : (slot == 1) ? src1 : src2;
        #pragma unroll
        for (int half = 0; half < 2; ++half) {
            const int kc = half * 64;
            __syncthreads();
            // stage A: 64 rows x 64 k fp16 (8KB), 2 uint4/thread
            #pragma unroll
            for (int it = 0; it < 2; ++it) {
                int c = t + it * 256;
                int row = c >> 3, part = c & 7;
                int grow = block_row + row;
                uint4 v = make_uint4(0, 0, 0, 0);
                if (grow < M)
                    v = *reinterpret_cast<const uint4*>(sb + (size_t)grow * H + kc + part * 8);
                *reinterpret_cast<uint4*>(&u.s.Al[row][part * 8]) = v;
            }
            // stage B: 128 n x 64 k fp16 (16KB), 4 uint4/thread (L2-hot)
            #pragma unroll
            for (int it = 0; it < 4; ++it) {
                int c = t + it * 256;
                int row = c >> 3, part = c & 7;
                uint4 v = *reinterpret_cast<const uint4*>(W + slot * 16384 + row * 128 + kc + part * 8);
                *reinterpret_cast<uint4*>(&u.s.Bl[row][part * 8]) = v;
            }
            __syncthreads();

            #pragma unroll
            for (int kk = 0; kk < 2; ++kk) {
                f16x8 a = *reinterpret_cast<const f16x8*>(&u.s.Al[wave * 16 + l15][kk * 32 + kreg * 8]);
                #pragma unroll
                for (int n = 0; n < 8; ++n) {
                    f16x8 bb = *reinterpret_cast<const f16x8*>(&u.s.Bl[n * 16 + l15][kk * 32 + kreg * 8]);
                    acc[n] = __builtin_amdgcn_mfma_f32_16x16x32_f16(a, bb, acc[n], 0, 0, 0);
                }
            }
        }
    }

    float psum[8], psq[8];
    const int rb = block_row + wave * 16 + kreg * 4;
    #pragma unroll
    for (int n = 0; n < 8; ++n) {
        int col = n * 16 + l15;
        float bv = bias[col];
        float s = 0.f, q = 0.f;
        #pragma unroll
        for (int r = 0; r < 4; ++r) {
            int row = rb + r;
            if (row < M) {
                float v = acc[n][r] + bv;
                v = (v > 0.f) ? v : 0.01f * v;
                if (OUTF32) ((float*)out)[(size_t)row * H + col] = v;
                else        ((ushort*)out)[(size_t)row * H + col] = f2h(v);
                s += v; q += v * v;
            }
        }
        psum[n] = s; psq[n] = q;
    }

    if (OUTF32) {
        __syncthreads();
        const int w4k = wave * 4 + kreg;
        #pragma unroll
        for (int n = 0; n < 8; ++n) {
            int col = n * 16 + l15;
            u.red[0][w4k][col] = psum[n];
            u.red[1][w4k][col] = psq[n];
        }
        __syncthreads();
        if (t < 128) {
            float a = 0.f, q = 0.f;
            #pragma unroll
            for (int k = 0; k < 16; ++k) { a += u.red[0][k][t]; q += u.red[1][k][t]; }
            float* dstp = sm + (blockIdx.x & 7) * 512 + soff;
            atomicAdd(&dstp[t], a);
            atomicAdd(&dstp[H + t], q);
        }
    }
}

// ---------------- fold 8 stats copies -> stats ------------------------------
__global__ void bn_fold(const float* __restrict__ sm, float* __restrict__ stats)
{
    int t = blockIdx.x * 256 + threadIdx.x;   // 0..511
    float s = 0.f;
    #pragma unroll
    for (int k = 0; k < 8; ++k) s += sm[k * 512 + t];
    stats[t] = s;
}

// ---------------- batchnorm apply: both tables in one launch ----------------
__global__ __launch_bounds__(256) void bn_apply_all(
    float* __restrict__ d2, float* __restrict__ s2,
    const float* __restrict__ stats,
    const float* __restrict__ gamma, const float* __restrict__ beta)
{
    size_t i = (size_t)blockIdx.x * 256 + threadIdx.x;
    const size_t totD = (size_t)ND * (H / 4);
    const size_t totAll = totD + (size_t)NS * (H / 4);
    if (i >= totAll) return;
    float* x;
    const float* st;
    float inv_m;
    size_t j;
    if (i < totD) { x = d2; st = stats;       inv_m = 1.0f / ND; j = i; }
    else          { x = s2; st = stats + 256; inv_m = 1.0f / NS; j = i - totD; }
    int c4 = (int)(j & (H / 4 - 1)) * 4;
    float4 v = reinterpret_cast<float4*>(x)[j];
    float* vp = &v.x;
    #pragma unroll
    for (int k = 0; k < 4; ++k) {
        int c = c4 + k;
        float mean = st[c] * inv_m;
        float var = st[H + c] * inv_m - mean * mean;
        float sc = gamma[c] * rsqrtf(fmaxf(var, 0.f) + 1e-5f);
        vp[k] = (vp[k] - mean) * sc + beta[c];
    }
    reinterpret_cast<float4*>(x)[j] = v;
}

// ---------------- launch ----------------------------------------------------
extern "C" void kernel_launch(void* const* d_in, const int* in_sizes, int n_in,
                              void* d_out, int out_size, void* d_ws, size_t ws_size,
                              hipStream_t stream)
{
    (void)n_in; (void)out_size; (void)ws_size;
    const float* x_drug = (const float*)d_in[0];
    const float* x_se   = (const float*)d_in[1];
    const int* ei_dd = (const int*)d_in[2];
    const int* ei_ds = (const int*)d_in[3];
    const int* ei_sd = (const int*)d_in[4];
    const int EDD = in_sizes[2] / 2;
    const int EDS = in_sizes[3] / 2;
    const int ESD = in_sizes[4] / 2;

    const float* w1_dd_rel  = (const float*)d_in[5];
    const float* b1_dd      = (const float*)d_in[6];
    const float* w1_dd_root = (const float*)d_in[7];
    const float* w1_ds_rel  = (const float*)d_in[8];
    const float* b1_ds      = (const float*)d_in[9];
    const float* w1_ds_root = (const float*)d_in[10];
    const float* w1_sd_rel  = (const float*)d_in[11];
    const float* b1_sd      = (const float*)d_in[12];
    const float* w1_sd_root = (const float*)d_in[13];
    const float* w2_dd_rel  = (const float*)d_in[14];
    const float* b2_dd      = (const float*)d_in[15];
    const float* w2_dd_root = (const float*)d_in[16];
    const float* w2_ds_rel  = (const float*)d_in[17];
    const float* b2_ds      = (const float*)d_in[18];
    const float* w2_ds_root = (const float*)d_in[19];
    const float* w2_sd_rel  = (const float*)d_in[20];
    const float* b2_sd      = (const float*)d_in[21];
    const float* w2_sd_root = (const float*)d_in[22];
    const float* gamma      = (const float*)d_in[23];
    const float* beta       = (const float*)d_in[24];

    // ---------------- workspace layout ----------------
    ushort* xd_h  = (ushort*)d_ws;                     // ND*H fp16 (becomes d1h in place)
    ushort* xs_h  = xd_h + (size_t)ND * H;             // NS*H fp16 (becomes s1h)
    ushort* segdd = xs_h + (size_t)NS * H;             // ND*H
    ushort* segsd = segdd + (size_t)ND * H;            // ND*H
    ushort* segds = segsd + (size_t)ND * H;            // NS*H
    ushort* Wd1 = segds + (size_t)NS * H;              // 3*16384
    ushort* Ws1 = Wd1 + 3 * 16384;                     // 2*16384
    ushort* Wd2 = Ws1 + 2 * 16384;                     // 3*16384
    ushort* Ws2 = Wd2 + 3 * 16384;                     // 2*16384
    float* bias  = (float*)(Ws2 + 2 * 16384);          // 512
    float* stats = bias + 512;                         // 512
    float* sm    = stats + 512;                        // 8*512 spread stats (memset start)
    int* cur_dd  = (int*)(sm + 8 * 512);               // ND (hist+cursor)
    int* cur_sd  = cur_dd + ND;                        // ND
    int* cur_ds  = cur_sd + ND;                        // NS (memset end)
    int* rp_dd = cur_ds + NS;                          // ND+1
    int* rp_sd = rp_dd + (ND + 1);                     // ND+1
    int* rp_ds = rp_sd + (ND + 1);                     // NS+1
    int* si_dd = rp_ds + (NS + 1);                     // EDD
    int* si_sd = si_dd + EDD;                          // ESD
    int* si_ds = si_sd + ESD;                          // EDS
    int* bs_dd = si_ds + EDS;                          // 64
    int* bs_sd = bs_dd + 64;                           // 64
    int* bs_ds = bs_sd + 64;                           // 64

    ushort* d1h = xd_h;
    ushort* s1h = xs_h;

    float* d2 = (float*)d_out;                // ND*H
    float* s2 = d2 + (size_t)ND * H;          // NS*H

    // zero sm + hist/cursor arrays (contiguous region)
    hipMemsetAsync(sm, 0, ((size_t)8 * 512 + (size_t)(2 * ND + NS)) * sizeof(int), stream);

    prep_weights<<<64, 256, 0, stream>>>(
        w1_dd_rel, w1_dd_root, w1_sd_rel, w1_sd_root, w1_ds_rel, w1_ds_root,
        w2_dd_rel, w2_dd_root, w2_sd_rel, w2_sd_root, w2_ds_rel, w2_ds_root,
        b1_dd, b1_sd, b1_ds, b2_dd, b2_sd, b2_ds,
        Wd1, Ws1, Wd2, Ws2, bias);

    f2h_all<<<((ND + NS) * H / 4 + 255) / 256, 256, 0, stream>>>(x_drug, x_se, xd_h, xs_h);

    // ---- CSR build ----
    const int gDD = (EDD + 255) / 256, gSD = (ESD + 255) / 256, gDS = (EDS + 255) / 256;
    hist3<<<gDD + gSD + gDS, 256, 0, stream>>>(
        ei_dd + EDD, EDD, cur_dd,
        ei_sd + ESD, ESD, cur_sd,
        ei_ds + EDS, EDS, cur_ds, gDD, gSD);

    const int nbDD = (ND + 2047) / 2048, nbDS = (NS + 2047) / 2048;
    scan1_3<<<2 * nbDD + nbDS, 256, 0, stream>>>(
        cur_dd, ND, rp_dd, bs_dd,
        cur_sd, ND, rp_sd, bs_sd,
        cur_ds, NS, rp_ds, bs_ds, nbDD, nbDD);
    scan2_3<<<3, 64, 0, stream>>>(bs_dd, nbDD, bs_sd, nbDD, bs_ds, nbDS);
    const int g3D = (ND + 255) / 256, g3S = (NS + 255) / 256;
    scan3_3<<<2 * g3D + g3S, 256, 0, stream>>>(
        rp_dd, ND, bs_dd, cur_dd, EDD,
        rp_sd, ND, bs_sd, cur_sd, ESD,
        rp_ds, NS, bs_ds, cur_ds, EDS, g3D, g3D);

    fill3<<<8 * (gDD + gSD + gDS), 256, 0, stream>>>(
        ei_dd, ei_dd + EDD, EDD, ND, cur_dd, si_dd,
        ei_sd, ei_sd + ESD, ESD, ND, cur_sd, si_sd,
        ei_ds, ei_ds + EDS, EDS, NS, cur_ds, si_ds, gDD, gSD);

    const int gA = (ND + 15) / 16, gB = (NS + 15) / 16;
    const int GD = (ND + 63) / 64, GS = (NS + 63) / 64;

    // ---- layer 1 ----
    agg3<<<2 * gA + gB, 256, 0, stream>>>(
        xd_h, xs_h,
        rp_dd, si_dd, segdd,
        rp_sd, si_sd, segsd,
        rp_ds, si_ds, segds, gA);
    gemm_layer<false><<<GD + GS, 256, 0, stream>>>(
        segdd, segsd, xd_h, Wd1, bias, d1h,
        segds, xs_h, Ws1, bias + H, s1h, sm, GD);

    // ---- layer 2 ----
    agg3<<<2 * gA + gB, 256, 0, stream>>>(
        d1h, s1h,
        rp_dd, si_dd, segdd,
        rp_sd, si_sd, segsd,
        rp_ds, si_ds, segds, gA);
    gemm_layer<true><<<GD + GS, 256, 0, stream>>>(
        segdd, segsd, d1h, Wd2, bias + 2 * H, d2,
        segds, s1h, Ws2, bias + 3 * H, s2, sm, GD);

    // ---- batchnorm: fold spread stats, then apply ----
    bn_fold<<<2, 256, 0, stream>>>(sm, stats);
    bn_apply_all<<<((ND + NS) * (H / 4) + 255) / 256, 256, 0, stream>>>(d2, s2, stats, gamma, beta);
}